// Round 14
// baseline (173.423 us; speedup 1.0000x reference)
//
#include <hip/hip_runtime.h>
#include <hip/hip_bf16.h>

typedef __attribute__((ext_vector_type(8))) short short8;
typedef __attribute__((ext_vector_type(4))) float float4v;

constexpr int B = 2, L = 1024, D = 256, K = 64;
constexpr int N = B * L;          // 2048 rows
constexpr int NC = L / 64;        // 16 chunks of 64 tokens

// WT arena (ushort units):
// big mats m in {w1_k, w1_q, wv, wo}: hi at m*131072, lo at +65536
// layer2 mats m in {w2_k, wa_k, w2_q, wa_q}: hi at WT2_OFF + m*32768, lo +16384
constexpr int WT2_OFF = 524288;

__device__ __forceinline__ ushort bf16_hi(float v) {
  return (ushort)(__float_as_uint(v) >> 16);
}
__device__ __forceinline__ float hi_f(float v) {
  return __uint_as_float(__float_as_uint(v) & 0xFFFF0000u);
}
__device__ __forceinline__ ushort bf16_rne(float v) {
  uint b = __float_as_uint(v);
  b += 0x7FFF + ((b >> 16) & 1);
  return (ushort)(b >> 16);
}
// convert 8 packed fp32 (two float4) to hi/lo bf16 fragments
__device__ __forceinline__ void cvt8(const float4 a, const float4 b,
                                     short8& h, short8& l) {
  const float v[8] = {a.x, a.y, a.z, a.w, b.x, b.y, b.z, b.w};
#pragma unroll
  for (int i = 0; i < 8; ++i) {
    h[i] = (short)bf16_hi(v[i]);
    l[i] = (short)bf16_rne(v[i] - hi_f(v[i]));
  }
}

// ---------------------------------------------------------------------------
// K0: transpose + hi/lo split weights into WT arena (vector writes only).
__global__ __launch_bounds__(256) void prep_kernel(
    const float* __restrict__ w1_k, const float* __restrict__ w1_q,
    const float* __restrict__ wv, const float* __restrict__ wo,
    const float* __restrict__ w2_k, const float* __restrict__ wa_k,
    const float* __restrict__ w2_q, const float* __restrict__ wa_q,
    ushort* __restrict__ WT) {
  __shared__ float Lt[64][65];
  const int bi = blockIdx.x, tid = threadIdx.x;
  const float* src;
  int ncols, k0, n0;
  ushort* dhi;
  int losz;
  if (bi < 64) {
    const int m = bi >> 4, t = bi & 15;
    src = (m == 0) ? w1_k : (m == 1) ? w1_q : (m == 2) ? wv : wo;
    ncols = 256; k0 = (t >> 2) * 64; n0 = (t & 3) * 64;
    dhi = WT + m * 131072; losz = 65536;
  } else {
    const int m = (bi - 64) >> 2, kt = (bi - 64) & 3;
    src = (m == 0) ? w2_k : (m == 1) ? wa_k : (m == 2) ? w2_q : wa_q;
    ncols = 64; k0 = kt * 64; n0 = 0;
    dhi = WT + WT2_OFF + m * 32768; losz = 16384;
  }
  ushort* dlo = dhi + losz;
  for (int p = 0; p < 16; ++p) {
    const int kr = p * 4 + (tid >> 6), nc = tid & 63;
    Lt[kr][nc] = src[(k0 + kr) * ncols + n0 + nc];
  }
  __syncthreads();
  const int n = tid >> 2, kq = tid & 3;
  uint uh[8], ul[8];
  for (int i = 0; i < 8; ++i) {
    const float v0 = Lt[kq * 16 + 2 * i][n];
    const float v1 = Lt[kq * 16 + 2 * i + 1][n];
    uh[i] = (uint)bf16_hi(v0) | ((uint)bf16_hi(v1) << 16);
    ul[i] = (uint)bf16_rne(v0 - hi_f(v0)) | ((uint)bf16_rne(v1 - hi_f(v1)) << 16);
  }
  const int oidx = (n0 + n) * 256 + k0 + kq * 16;
  *(uint4*)&dhi[oidx] = make_uint4(uh[0], uh[1], uh[2], uh[3]);
  *(uint4*)&dhi[oidx + 8] = make_uint4(uh[4], uh[5], uh[6], uh[7]);
  *(uint4*)&dlo[oidx] = make_uint4(ul[0], ul[1], ul[2], ul[3]);
  *(uint4*)&dlo[oidx + 8] = make_uint4(ul[4], ul[5], ul[6], ul[7]);
}

// ---------------------------------------------------------------------------
// K1: layer-1 as 3 GEMMs via MFMA bf16x3. 32x64 tiles, 768 blocks (3/CU).
__global__ __launch_bounds__(256) void enc1_kernel(
    const float* __restrict__ x, const float* __restrict__ pos_k,
    const float* __restrict__ pos_q,
    const float* __restrict__ b1_k, const float* __restrict__ b1_q,
    const float* __restrict__ bv, const ushort* __restrict__ WT,
    float* __restrict__ hk, float* __restrict__ hq, float* __restrict__ V) {
  __shared__ __align__(16) ushort Ah[32][40], Al[32][40];
  __shared__ __align__(16) ushort Bh[64][40], Bl[64][40];
  const int tid = threadIdx.x;
  const int g = blockIdx.x / 256;
  const int rem = blockIdx.x % 256;
  const int row0 = (rem >> 2) * 32, nb = (rem & 3) * 64;
  const float* pos = (g == 0) ? pos_k : (g == 1) ? pos_q : nullptr;
  const ushort* Wh = WT + g * 131072;
  const ushort* Wl = Wh + 65536;
  const int w = tid >> 6, lane = tid & 63;
  const int m16 = lane & 15, quad = lane >> 4;

  float4v acc[2] = {};

  for (int k0 = 0; k0 < 256; k0 += 32) {
    __syncthreads();
    {
      const int r = tid >> 3, kc = (tid & 7) * 4;
      const int row = row0 + r, l = row & (L - 1);
      float4 xv = *(const float4*)&x[row * D + k0 + kc];
      if (pos) {
        const float4 pv = *(const float4*)&pos[l * D + k0 + kc];
        xv.x += pv.x; xv.y += pv.y; xv.z += pv.z; xv.w += pv.w;
      }
      ushort4 h4, l4;
      h4.x = bf16_hi(xv.x); l4.x = bf16_rne(xv.x - hi_f(xv.x));
      h4.y = bf16_hi(xv.y); l4.y = bf16_rne(xv.y - hi_f(xv.y));
      h4.z = bf16_hi(xv.z); l4.z = bf16_rne(xv.z - hi_f(xv.z));
      h4.w = bf16_hi(xv.w); l4.w = bf16_rne(xv.w - hi_f(xv.w));
      *(ushort4*)&Ah[r][kc] = h4;
      *(ushort4*)&Al[r][kc] = l4;
    }
    {
      const int n = tid >> 2, chunk = tid & 3;
      const int ga = (nb + n) * 256 + k0 + chunk * 8;
      *(uint4*)&Bh[n][chunk * 8] = *(const uint4*)&Wh[ga];
      *(uint4*)&Bl[n][chunk * 8] = *(const uint4*)&Wl[ga];
    }
    __syncthreads();

    short8 afh[2], afl[2];
#pragma unroll
    for (int r = 0; r < 2; ++r) {
      afh[r] = *(const short8*)&Ah[r * 16 + m16][quad * 8];
      afl[r] = *(const short8*)&Al[r * 16 + m16][quad * 8];
    }
    const int col = w * 16 + m16;
    const short8 bfh = *(const short8*)&Bh[col][quad * 8];
    const short8 bfl = *(const short8*)&Bl[col][quad * 8];
#pragma unroll
    for (int r = 0; r < 2; ++r) {
      acc[r] = __builtin_amdgcn_mfma_f32_16x16x32_bf16(afh[r], bfh, acc[r], 0, 0, 0);
      acc[r] = __builtin_amdgcn_mfma_f32_16x16x32_bf16(afh[r], bfl, acc[r], 0, 0, 0);
      acc[r] = __builtin_amdgcn_mfma_f32_16x16x32_bf16(afl[r], bfh, acc[r], 0, 0, 0);
    }
  }

  float* outp = (g == 0) ? hk : (g == 1) ? hq : V;
  const float* bp = (g == 0) ? b1_k : (g == 1) ? b1_q : bv;
  const int colg = nb + w * 16 + m16;
  const float bias = bp[colg];
#pragma unroll
  for (int r = 0; r < 2; ++r)
#pragma unroll
    for (int j = 0; j < 4; ++j) {
      const int rowg = row0 + r * 16 + quad * 4 + j;
      float v = acc[r][j] + bias;
      if (g < 2) v = 0.5f * v * (1.0f + erff(v * 0.70710678f));
      outp[rowg * D + colg] = v;
    }
}

// ---------------------------------------------------------------------------
// K2: layer-2 (phase & amp GEMMs) + phasor epilogue. 256 blocks x 512 thr.
__global__ __launch_bounds__(512) void enc2_kernel(
    const float* __restrict__ x, const float* __restrict__ pos_k,
    const float* __restrict__ pos_q, const float* __restrict__ hk,
    const float* __restrict__ hq,
    const float* __restrict__ b2_k, const float* __restrict__ ba_k,
    const float* __restrict__ b2_q, const float* __restrict__ ba_q,
    const ushort* __restrict__ WT,
    float* __restrict__ kr, float* __restrict__ ki,
    float* __restrict__ qr, float* __restrict__ qi) {
  __shared__ __align__(16) ushort Ahh[16][40], Ahl[16][40], Axh[16][40], Axl[16][40];
  __shared__ __align__(16) ushort B2h[64][40], B2l[64][40], Bah[64][40], Bal[64][40];
  __shared__ float phL[16][68], amL[16][68];
  const int tid = threadIdx.x;
  const int e = blockIdx.x >> 7;
  const int r0g = (blockIdx.x & 127) * 16;
  const float* hsrc = e ? hq : hk;
  const float* pos = e ? pos_q : pos_k;
  const ushort* W2h = WT + WT2_OFF + (e ? 2 : 0) * 32768;
  const ushort* W2l = W2h + 16384;
  const ushort* Wah = WT + WT2_OFF + (e ? 3 : 1) * 32768;
  const ushort* Wal = Wah + 16384;
  const int w = tid >> 6, lane = tid & 63;
  const int m16 = lane & 15, quad = lane >> 4;
  const int mat = w & 1, ct = w >> 1;

  float4v acc = {};
  for (int k0 = 0; k0 < 256; k0 += 32) {
    __syncthreads();
    {
      const int half = tid >> 8;
      const int t2 = tid & 255;
      const int r = t2 >> 4, kc = (t2 & 15) * 2;
      const int row = r0g + r, l = row & (L - 1);
      if (half == 0) {
        const float2 hv = *(const float2*)&hsrc[row * D + k0 + kc];
        ushort2 h2, l2;
        h2.x = bf16_hi(hv.x); l2.x = bf16_rne(hv.x - hi_f(hv.x));
        h2.y = bf16_hi(hv.y); l2.y = bf16_rne(hv.y - hi_f(hv.y));
        *(ushort2*)&Ahh[r][kc] = h2;
        *(ushort2*)&Ahl[r][kc] = l2;
      } else {
        const float2 xv = *(const float2*)&x[row * D + k0 + kc];
        const float2 pv = *(const float2*)&pos[l * D + k0 + kc];
        const float a0 = xv.x + pv.x, a1 = xv.y + pv.y;
        ushort2 h2, l2;
        h2.x = bf16_hi(a0); l2.x = bf16_rne(a0 - hi_f(a0));
        h2.y = bf16_hi(a1); l2.y = bf16_rne(a1 - hi_f(a1));
        *(ushort2*)&Axh[r][kc] = h2;
        *(ushort2*)&Axl[r][kc] = l2;
      }
    }
    {
      const int sel = tid >> 7;
      const int idx = tid & 127;
      const int n = idx >> 1, ch = (idx & 1) * 2;
      const int ga = n * 256 + k0 + ch * 8;
      const ushort* s = (sel == 0) ? W2h : (sel == 1) ? W2l : (sel == 2) ? Wah : Wal;
      ushort* dst = (sel == 0) ? &B2h[n][ch * 8] : (sel == 1) ? &B2l[n][ch * 8]
                  : (sel == 2) ? &Bah[n][ch * 8] : &Bal[n][ch * 8];
      *(uint4*)dst = *(const uint4*)&s[ga];
      *(uint4*)(dst + 8) = *(const uint4*)&s[ga + 8];
    }
    __syncthreads();

    const short8 ah = mat ? *(const short8*)&Axh[m16][quad * 8]
                          : *(const short8*)&Ahh[m16][quad * 8];
    const short8 al = mat ? *(const short8*)&Axl[m16][quad * 8]
                          : *(const short8*)&Ahl[m16][quad * 8];
    const int col = ct * 16 + m16;
    const short8 bh = mat ? *(const short8*)&Bah[col][quad * 8]
                          : *(const short8*)&B2h[col][quad * 8];
    const short8 bl = mat ? *(const short8*)&Bal[col][quad * 8]
                          : *(const short8*)&B2l[col][quad * 8];
    acc = __builtin_amdgcn_mfma_f32_16x16x32_bf16(ah, bh, acc, 0, 0, 0);
    acc = __builtin_amdgcn_mfma_f32_16x16x32_bf16(ah, bl, acc, 0, 0, 0);
    acc = __builtin_amdgcn_mfma_f32_16x16x32_bf16(al, bh, acc, 0, 0, 0);
  }

  {
    const int colk = ct * 16 + m16;
    if (mat == 0) {
      const float b2v = (e ? b2_q : b2_k)[colk];
#pragma unroll
      for (int j = 0; j < 4; ++j)
        phL[quad * 4 + j][colk] = tanhf(acc[j] + b2v) * 3.14159265358979f;
    } else {
      const float bav = (e ? ba_q : ba_k)[colk];
#pragma unroll
      for (int j = 0; j < 4; ++j) {
        const float av = acc[j] + bav;
        amL[quad * 4 + j][colk] = fmaxf(av, 0.0f) + log1pf(expf(-fabsf(av))) + 0.1f;
      }
    }
  }
  __syncthreads();
  {
    float* pr = e ? qr : kr;
    float* pim = e ? qi : ki;
#pragma unroll
    for (int p = 0; p < 2; ++p) {
      const int idx = p * 512 + tid;
      const int r = idx >> 6, ccol = idx & 63;
      const int row = r0g + r;
      const float a = amL[r][ccol], pph = phL[r][ccol];
      pr[row * K + ccol] = a * cosf(pph);
      pim[row * K + ccol] = a * sinf(pph);
    }
  }
}

// ---------------------------------------------------------------------------
// K3: per-chunk T + V^T into TMt[b][c][d][192] = [T_re(64)|T_im(64)|Vt(64)].
__global__ __launch_bounds__(256) void tbuild_kernel(
    const float* __restrict__ kr, const float* __restrict__ ki,
    const float* __restrict__ V, float* __restrict__ TMt) {
  const int id = blockIdx.x;
  const int dc = id & 15, c = (id >> 4) & 15, b = id >> 8;
  const int tid = threadIdx.x;
  const int n0 = b * L + c * 64;
  const int dl = tid & 15;
  const int kb = tid >> 4;

  __shared__ float krL[64][68], kiL[64][68];
  __shared__ float VL[64][20];
  __shared__ float Tl[16][204];
  for (int e = tid; e < 1024; e += 256) {
    const int t = e >> 4, k4 = (e & 15) * 4;
    *(float4*)&krL[t][k4] = *(const float4*)&kr[(n0 + t) * K + k4];
    *(float4*)&kiL[t][k4] = *(const float4*)&ki[(n0 + t) * K + k4];
  }
  {
    const int t = tid >> 2, f = (tid & 3) * 4;
    *(float4*)&VL[t][f] = *(const float4*)&V[(n0 + t) * D + dc * 16 + f];
  }
  __syncthreads();

  {
    const int t0 = (tid >> 4) * 4;
#pragma unroll
    for (int i = 0; i < 4; ++i) Tl[dl][128 + t0 + i] = VL[t0 + i][dl];
  }

  float ar[4] = {0.f, 0.f, 0.f, 0.f}, ai[4] = {0.f, 0.f, 0.f, 0.f};
#pragma unroll 4
  for (int t = 0; t < 64; ++t) {
    const float vt = VL[t][dl];
    const float4 k4r = *(const float4*)&krL[t][kb * 4];
    const float4 k4i = *(const float4*)&kiL[t][kb * 4];
    ar[0] += k4r.x * vt; ar[1] += k4r.y * vt; ar[2] += k4r.z * vt; ar[3] += k4r.w * vt;
    ai[0] += k4i.x * vt; ai[1] += k4i.y * vt; ai[2] += k4i.z * vt; ai[3] += k4i.w * vt;
  }

#pragma unroll
  for (int i = 0; i < 4; ++i) {
    Tl[dl][kb * 4 + i] = ar[i];
    Tl[dl][64 + kb * 4 + i] = ai[i];
  }
  __syncthreads();

  float* dst = &TMt[(((size_t)(b * 16 + c)) * 256 + dc * 16) * 192];
#pragma unroll
  for (int p = 0; p < 3; ++p) {
    const int e = p * 256 + tid;
    const int row = e / 48, f4 = e % 48;
    *(float4*)&dst[(size_t)row * 192 + f4 * 4] = *(const float4*)&Tl[row][f4 * 4];
  }
}

// ---------------------------------------------------------------------------
// K4: ret slice, register-direct fragments. Only S lives in LDS (18.4 KB).
// Grid (b,c,dc8) = 256 blocks x 512 threads; waves: rt = w&3, ct = w>>2.
__global__ __launch_bounds__(512) void ret_kernel(
    const float* __restrict__ qr, const float* __restrict__ qi,
    const float* __restrict__ kr, const float* __restrict__ ki,
    const float* __restrict__ TMt, float* __restrict__ ret,
    float* __restrict__ LNred) {
  __shared__ __align__(16) ushort Sh[64][72], Sl[64][72];
  const int tid = threadIdx.x;
  const int dc = blockIdx.x & 7;
  const int c = (blockIdx.x >> 3) & 15;
  const int b = blockIdx.x >> 7;
  const int n0 = b * L + c * 64;
  const int cols0 = dc * 32;
  const int w = tid >> 6, lane = tid & 63;
  const int m16 = lane & 15, quad = lane >> 4;
  const int rt = w & 3, ct = w >> 2;   // rt: row tile, ct: 0..1 col half

  // M-prefix in registers, laid out exactly as phase-3 B-fragments need:
  // lane owns d-row n = cols0 + ct*16 + m16, k-segment quad*8 within each s*32.
  float m[4][8] = {};
  {
    const int n = cols0 + ct * 16 + m16;
    const float* base = TMt + (size_t)(b * 16) * 49152 + (size_t)n * 192 + quad * 8;
    for (int cp = 0; cp < c; ++cp) {
      const float* p = base + (size_t)cp * 49152;
#pragma unroll
      for (int s = 0; s < 4; ++s) {
        const float4 v0 = *(const float4*)(p + s * 32);
        const float4 v1 = *(const float4*)(p + s * 32 + 4);
        m[s][0] += v0.x; m[s][1] += v0.y; m[s][2] += v0.z; m[s][3] += v0.w;
        m[s][4] += v1.x; m[s][5] += v1.y; m[s][6] += v1.z; m[s][7] += v1.w;
      }
    }
  }

  // Phase 1: S = Q.K^T (inner 128), causal -> Sh/Sl. Wave (rt, ct):
  // rows rt*16.., cols ct*32..+31 (2 fragments).
  {
    float4v sc[2] = {};
#pragma unroll
    for (int kk = 0; kk < 4; ++kk) {
      const float* qsrc = (kk < 2) ? qr : qi;
      const int qoff = (kk & 1) * 32 + quad * 8;
      const float4 qa = *(const float4*)&qsrc[(n0 + rt * 16 + m16) * K + qoff];
      const float4 qb = *(const float4*)&qsrc[(n0 + rt * 16 + m16) * K + qoff + 4];
      short8 ah, al;
      cvt8(qa, qb, ah, al);
#pragma unroll
      for (int cf = 0; cf < 2; ++cf) {
        const int t = ct * 32 + cf * 16 + m16;
        const float* ksrc = (kk < 2) ? kr : ki;
        const float4 ka = *(const float4*)&ksrc[(n0 + t) * K + qoff];
        const float4 kb2 = *(const float4*)&ksrc[(n0 + t) * K + qoff + 4];
        short8 bh, bl;
        cvt8(ka, kb2, bh, bl);
        sc[cf] = __builtin_amdgcn_mfma_f32_16x16x32_bf16(ah, bh, sc[cf], 0, 0, 0);
        sc[cf] = __builtin_amdgcn_mfma_f32_16x16x32_bf16(ah, bl, sc[cf], 0, 0, 0);
        sc[cf] = __builtin_amdgcn_mfma_f32_16x16x32_bf16(al, bh, sc[cf], 0, 0, 0);
      }
    }
#pragma unroll
    for (int cf = 0; cf < 2; ++cf)
#pragma unroll
      for (int j = 0; j < 4; ++j) {
        const int row = rt * 16 + quad * 4 + j;
        const int t = ct * 32 + cf * 16 + m16;
        const float s = (t <= row) ? sc[cf][j] : 0.0f;
        Sh[row][t] = bf16_hi(s);
        Sl[row][t] = bf16_rne(s - hi_f(s));
      }
  }
  __syncthreads();

  // Phase 2: ret slice = [Q|S] . [M;Vt], inner 192. Wave (rt, ct):
  // rows rt*16.., cols cols0 + ct*16 + m16.
  {
    float4v racc = {};
#pragma unroll
    for (int s = 0; s < 4; ++s) {   // Q x M part
      const float* qsrc = (s < 2) ? qr : qi;
      const int qoff = (s & 1) * 32 + quad * 8;
      const float4 qa = *(const float4*)&qsrc[(n0 + rt * 16 + m16) * K + qoff];
      const float4 qb = *(const float4*)&qsrc[(n0 + rt * 16 + m16) * K + qoff + 4];
      short8 ah, al;
      cvt8(qa, qb, ah, al);
      short8 bh, bl;
#pragma unroll
      for (int i = 0; i < 8; ++i) {
        bh[i] = (short)bf16_hi(m[s][i]);
        bl[i] = (short)bf16_rne(m[s][i] - hi_f(m[s][i]));
      }
      racc = __builtin_amdgcn_mfma_f32_16x16x32_bf16(ah, bh, racc, 0, 0, 0);
      racc = __builtin_amdgcn_mfma_f32_16x16x32_bf16(ah, bl, racc, 0, 0, 0);
      racc = __builtin_amdgcn_mfma_f32_16x16x32_bf16(al, bh, racc, 0, 0, 0);
    }
#pragma unroll
    for (int s2 = 0; s2 < 2; ++s2) {  // S x Vt part
      const short8 ah = *(const short8*)&Sh[rt * 16 + m16][s2 * 32 + quad * 8];
      const short8 al = *(const short8*)&Sl[rt * 16 + m16][s2 * 32 + quad * 8];
      const int n = cols0 + ct * 16 + m16;
      const float* vp = &TMt[(size_t)(b * 16 + c) * 49152 + (size_t)n * 192 +
                             128 + s2 * 32 + quad * 8];
      const float4 va = *(const float4*)vp;
      const float4 vb = *(const float4*)(vp + 4);
      short8 bh, bl;
      cvt8(va, vb, bh, bl);
      racc = __builtin_amdgcn_mfma_f32_16x16x32_bf16(ah, bh, racc, 0, 0, 0);
      racc = __builtin_amdgcn_mfma_f32_16x16x32_bf16(ah, bl, racc, 0, 0, 0);
      racc = __builtin_amdgcn_mfma_f32_16x16x32_bf16(al, bh, racc, 0, 0, 0);
    }

#pragma unroll
    for (int j = 0; j < 4; ++j) {
      const int rowL = rt * 16 + quad * 4 + j;
      const float nrm = rsqrtf((float)(c * 64 + rowL + 1) * 64.0f);
      const float v = racc[j] * nrm;
      ret[(size_t)(n0 + rowL) * D + cols0 + ct * 16 + m16] = v;
      float sj = v, s2j = v * v;
      for (int off = 1; off < 16; off <<= 1) {
        sj += __shfl_xor(sj, off, 64);
        s2j += __shfl_xor(s2j, off, 64);
      }
      if (m16 == 0) {
        LNred[(size_t)(n0 + rowL) * 32 + (dc * 2 + ct) * 2 + 0] = sj;
        LNred[(size_t)(n0 + rowL) * 32 + (dc * 2 + ct) * 2 + 1] = s2j;
      }
    }
  }
}

// ---------------------------------------------------------------------------
// K5: out = x + LN(ret).wo + bo via MFMA bf16x3. 256 blocks x 512 threads.
__global__ __launch_bounds__(512) void out2_kernel(
    const float* __restrict__ ret, const float* __restrict__ LNred,
    const float* __restrict__ x, const float* __restrict__ ln_g,
    const float* __restrict__ ln_b, const ushort* __restrict__ WT,
    const float* __restrict__ bo, float* __restrict__ out) {
  __shared__ __align__(16) ushort Ah[32][40], Al[32][40];
  __shared__ __align__(16) ushort Bh[64][40], Bl[64][40];
  __shared__ float mu_s[32], rs_s[32];
  const int tid = threadIdx.x;
  const int row0 = (blockIdx.x >> 2) * 32, nb = (blockIdx.x & 3) * 64;
  const ushort* Wh = WT + 3 * 131072;
  const ushort* Wl = Wh + 65536;
  const int w = tid >> 6, lane = tid & 63;
  const int m16 = lane & 15, quad = lane >> 4;
  const int rt = w & 1, cq = w >> 1;

  if (tid < 32) {
    const int row = row0 + tid;
    float s = 0.f, s2 = 0.f;
#pragma unroll
    for (int i = 0; i < 16; ++i) {
      s += LNred[(size_t)row * 32 + i * 2 + 0];
      s2 += LNred[(size_t)row * 32 + i * 2 + 1];
    }
    const float mu = s * (1.0f / 256.0f);
    mu_s[tid] = mu;
    rs_s[tid] = rsqrtf(s2 * (1.0f / 256.0f) - mu * mu + 1e-5f);
  }

  float4v acc = {};
  for (int k0 = 0; k0 < 256; k0 += 32) {
    __syncthreads();
    {
      const int r = tid >> 4, kc = (tid & 15) * 2;
      const float2 v = *(const float2*)&ret[(size_t)(row0 + r) * D + k0 + kc];
      const float2 g2 = *(const float2*)&ln_g[k0 + kc];
      const float2 b2 = *(const float2*)&ln_b[k0 + kc];
      const float mu = mu_s[r], rs = rs_s[r];
      const float a0 = (v.x - mu) * rs * g2.x + b2.x;
      const float a1 = (v.y - mu) * rs * g2.y + b2.y;
      ushort2 h2, l2;
      h2.x = bf16_hi(a0); l2.x = bf16_rne(a0 - hi_f(a0));
      h2.y = bf16_hi(a1); l2.y = bf16_rne(a1 - hi_f(a1));
      *(ushort2*)&Ah[r][kc] = h2;
      *(ushort2*)&Al[r][kc] = l2;
    }
    {
      const int plane = tid >> 8;
      const int n = (tid >> 2) & 63, chunk = tid & 3;
      const int ga = (nb + n) * 256 + k0 + chunk * 8;
      if (plane == 0) *(uint4*)&Bh[n][chunk * 8] = *(const uint4*)&Wh[ga];
      else            *(uint4*)&Bl[n][chunk * 8] = *(const uint4*)&Wl[ga];
    }
    __syncthreads();

    const short8 afh = *(const short8*)&Ah[rt * 16 + m16][quad * 8];
    const short8 afl = *(const short8*)&Al[rt * 16 + m16][quad * 8];
    const int col = cq * 16 + m16;
    const short8 bfh = *(const short8*)&Bh[col][quad * 8];
    const short8 bfl = *(const short8*)&Bl[col][quad * 8];
    acc = __builtin_amdgcn_mfma_f32_16x16x32_bf16(afh, bfh, acc, 0, 0, 0);
    acc = __builtin_amdgcn_mfma_f32_16x16x32_bf16(afh, bfl, acc, 0, 0, 0);
    acc = __builtin_amdgcn_mfma_f32_16x16x32_bf16(afl, bfh, acc, 0, 0, 0);
  }

  const int colg = nb + cq * 16 + m16;
  const float bias = bo[colg];
#pragma unroll
  for (int j = 0; j < 4; ++j) {
    const int rowg = row0 + rt * 16 + quad * 4 + j;
    out[rowg * D + colg] = x[rowg * D + colg] + acc[j] + bias;
  }
}

// ---------------------------------------------------------------------------
extern "C" void kernel_launch(void* const* d_in, const int* in_sizes, int n_in,
                              void* d_out, int out_size, void* d_ws, size_t ws_size,
                              hipStream_t stream) {
  (void)in_sizes; (void)n_in; (void)out_size; (void)ws_size;
  const float* x    = (const float*)d_in[0];
  const float* pos_k= (const float*)d_in[1];
  const float* w1_k = (const float*)d_in[2];
  const float* b1_k = (const float*)d_in[3];
  const float* w2_k = (const float*)d_in[4];
  const float* b2_k = (const float*)d_in[5];
  const float* wa_k = (const float*)d_in[6];
  const float* ba_k = (const float*)d_in[7];
  const float* pos_q= (const float*)d_in[8];
  const float* w1_q = (const float*)d_in[9];
  const float* b1_q = (const float*)d_in[10];
  const float* w2_q = (const float*)d_in[11];
  const float* b2_q = (const float*)d_in[12];
  const float* wa_q = (const float*)d_in[13];
  const float* ba_q = (const float*)d_in[14];
  const float* wv   = (const float*)d_in[15];
  const float* bv   = (const float*)d_in[16];
  const float* ln_g = (const float*)d_in[17];
  const float* ln_b = (const float*)d_in[18];
  const float* wo   = (const float*)d_in[19];
  const float* bo   = (const float*)d_in[20];

  float* ws = (float*)d_ws;
  float* kr = ws;                          // N*K
  float* ki = kr + (size_t)N * K;
  float* qr = ki + (size_t)N * K;
  float* qi = qr + (size_t)N * K;
  float* V  = qi + (size_t)N * K;          // N*D
  float* TMt = V + (size_t)N * D;          // B*NC*256*192
  float* ret = TMt + (size_t)B * NC * 256 * 192;  // N*D
  float* LNred = ret + (size_t)N * D;      // N*32
  float* hk = LNred + (size_t)N * 32;      // N*D
  float* hq = hk + (size_t)N * D;          // N*D
  ushort* WT = (ushort*)(hq + (size_t)N * D);   // 655360 ushorts

  prep_kernel<<<80, 256, 0, stream>>>(w1_k, w1_q, wv, wo,
                                      w2_k, wa_k, w2_q, wa_q, WT);
  enc1_kernel<<<768, 256, 0, stream>>>(x, pos_k, pos_q, b1_k, b1_q, bv, WT,
                                       hk, hq, V);
  enc2_kernel<<<256, 512, 0, stream>>>(x, pos_k, pos_q, hk, hq,
                                       b2_k, ba_k, b2_q, ba_q, WT,
                                       kr, ki, qr, qi);
  tbuild_kernel<<<B * NC * 16, 256, 0, stream>>>(kr, ki, V, TMt);
  ret_kernel<<<B * NC * 8, 512, 0, stream>>>(qr, qi, kr, ki, TMt, ret, LNred);
  out2_kernel<<<256, 512, 0, stream>>>(ret, LNred, x, ln_g, ln_b, WT, bo,
                                       (float*)d_out);
}

// Round 15
// 148.260 us; speedup vs baseline: 1.1697x; 1.1697x over previous
//
#include <hip/hip_runtime.h>
#include <hip/hip_bf16.h>

typedef __attribute__((ext_vector_type(8))) short short8;
typedef __attribute__((ext_vector_type(4))) float float4v;

constexpr int B = 2, L = 1024, D = 256, K = 64;
constexpr int N = B * L;          // 2048 rows
constexpr int NC = L / 64;        // 16 chunks of 64 tokens

// WT arena (ushort units):
// big mats m in {w1_k, w1_q, wv, wo}: hi at m*131072, lo at +65536
// layer2 mats m in {w2_k, wa_k, w2_q, wa_q}: hi at WT2_OFF + m*32768, lo +16384
constexpr int WT2_OFF = 524288;

__device__ __forceinline__ ushort bf16_hi(float v) {
  return (ushort)(__float_as_uint(v) >> 16);
}
__device__ __forceinline__ float hi_f(float v) {
  return __uint_as_float(__float_as_uint(v) & 0xFFFF0000u);
}
__device__ __forceinline__ ushort bf16_rne(float v) {
  uint b = __float_as_uint(v);
  b += 0x7FFF + ((b >> 16) & 1);
  return (ushort)(b >> 16);
}

// ---------------------------------------------------------------------------
// K0: transpose + hi/lo split weights into WT arena (vector writes only).
__global__ __launch_bounds__(256) void prep_kernel(
    const float* __restrict__ w1_k, const float* __restrict__ w1_q,
    const float* __restrict__ wv, const float* __restrict__ wo,
    const float* __restrict__ w2_k, const float* __restrict__ wa_k,
    const float* __restrict__ w2_q, const float* __restrict__ wa_q,
    ushort* __restrict__ WT) {
  __shared__ float Lt[64][65];
  const int bi = blockIdx.x, tid = threadIdx.x;
  const float* src;
  int ncols, k0, n0;
  ushort* dhi;
  int losz;
  if (bi < 64) {
    const int m = bi >> 4, t = bi & 15;
    src = (m == 0) ? w1_k : (m == 1) ? w1_q : (m == 2) ? wv : wo;
    ncols = 256; k0 = (t >> 2) * 64; n0 = (t & 3) * 64;
    dhi = WT + m * 131072; losz = 65536;
  } else {
    const int m = (bi - 64) >> 2, kt = (bi - 64) & 3;
    src = (m == 0) ? w2_k : (m == 1) ? wa_k : (m == 2) ? w2_q : wa_q;
    ncols = 64; k0 = kt * 64; n0 = 0;
    dhi = WT + WT2_OFF + m * 32768; losz = 16384;
  }
  ushort* dlo = dhi + losz;
  for (int p = 0; p < 16; ++p) {
    const int kr = p * 4 + (tid >> 6), nc = tid & 63;
    Lt[kr][nc] = src[(k0 + kr) * ncols + n0 + nc];
  }
  __syncthreads();
  const int n = tid >> 2, kq = tid & 3;
  uint uh[8], ul[8];
  for (int i = 0; i < 8; ++i) {
    const float v0 = Lt[kq * 16 + 2 * i][n];
    const float v1 = Lt[kq * 16 + 2 * i + 1][n];
    uh[i] = (uint)bf16_hi(v0) | ((uint)bf16_hi(v1) << 16);
    ul[i] = (uint)bf16_rne(v0 - hi_f(v0)) | ((uint)bf16_rne(v1 - hi_f(v1)) << 16);
  }
  const int oidx = (n0 + n) * 256 + k0 + kq * 16;
  *(uint4*)&dhi[oidx] = make_uint4(uh[0], uh[1], uh[2], uh[3]);
  *(uint4*)&dhi[oidx + 8] = make_uint4(uh[4], uh[5], uh[6], uh[7]);
  *(uint4*)&dlo[oidx] = make_uint4(ul[0], ul[1], ul[2], ul[3]);
  *(uint4*)&dlo[oidx + 8] = make_uint4(ul[4], ul[5], ul[6], ul[7]);
}

// ---------------------------------------------------------------------------
// K1: layer-1 as 3 GEMMs via MFMA bf16x3. 32x64 tiles, 768 blocks (3/CU).
__global__ __launch_bounds__(256) void enc1_kernel(
    const float* __restrict__ x, const float* __restrict__ pos_k,
    const float* __restrict__ pos_q,
    const float* __restrict__ b1_k, const float* __restrict__ b1_q,
    const float* __restrict__ bv, const ushort* __restrict__ WT,
    float* __restrict__ hk, float* __restrict__ hq, float* __restrict__ V) {
  __shared__ __align__(16) ushort Ah[32][40], Al[32][40];
  __shared__ __align__(16) ushort Bh[64][40], Bl[64][40];
  const int tid = threadIdx.x;
  const int g = blockIdx.x / 256;
  const int rem = blockIdx.x % 256;
  const int row0 = (rem >> 2) * 32, nb = (rem & 3) * 64;
  const float* pos = (g == 0) ? pos_k : (g == 1) ? pos_q : nullptr;
  const ushort* Wh = WT + g * 131072;
  const ushort* Wl = Wh + 65536;
  const int w = tid >> 6, lane = tid & 63;
  const int m16 = lane & 15, quad = lane >> 4;

  float4v acc[2] = {};

  for (int k0 = 0; k0 < 256; k0 += 32) {
    __syncthreads();
    {
      const int r = tid >> 3, kc = (tid & 7) * 4;
      const int row = row0 + r, l = row & (L - 1);
      float4 xv = *(const float4*)&x[row * D + k0 + kc];
      if (pos) {
        const float4 pv = *(const float4*)&pos[l * D + k0 + kc];
        xv.x += pv.x; xv.y += pv.y; xv.z += pv.z; xv.w += pv.w;
      }
      ushort4 h4, l4;
      h4.x = bf16_hi(xv.x); l4.x = bf16_rne(xv.x - hi_f(xv.x));
      h4.y = bf16_hi(xv.y); l4.y = bf16_rne(xv.y - hi_f(xv.y));
      h4.z = bf16_hi(xv.z); l4.z = bf16_rne(xv.z - hi_f(xv.z));
      h4.w = bf16_hi(xv.w); l4.w = bf16_rne(xv.w - hi_f(xv.w));
      *(ushort4*)&Ah[r][kc] = h4;
      *(ushort4*)&Al[r][kc] = l4;
    }
    {
      const int n = tid >> 2, chunk = tid & 3;
      const int ga = (nb + n) * 256 + k0 + chunk * 8;
      *(uint4*)&Bh[n][chunk * 8] = *(const uint4*)&Wh[ga];
      *(uint4*)&Bl[n][chunk * 8] = *(const uint4*)&Wl[ga];
    }
    __syncthreads();

    short8 afh[2], afl[2];
#pragma unroll
    for (int r = 0; r < 2; ++r) {
      afh[r] = *(const short8*)&Ah[r * 16 + m16][quad * 8];
      afl[r] = *(const short8*)&Al[r * 16 + m16][quad * 8];
    }
    const int col = w * 16 + m16;
    const short8 bfh = *(const short8*)&Bh[col][quad * 8];
    const short8 bfl = *(const short8*)&Bl[col][quad * 8];
#pragma unroll
    for (int r = 0; r < 2; ++r) {
      acc[r] = __builtin_amdgcn_mfma_f32_16x16x32_bf16(afh[r], bfh, acc[r], 0, 0, 0);
      acc[r] = __builtin_amdgcn_mfma_f32_16x16x32_bf16(afh[r], bfl, acc[r], 0, 0, 0);
      acc[r] = __builtin_amdgcn_mfma_f32_16x16x32_bf16(afl[r], bfh, acc[r], 0, 0, 0);
    }
  }

  float* outp = (g == 0) ? hk : (g == 1) ? hq : V;
  const float* bp = (g == 0) ? b1_k : (g == 1) ? b1_q : bv;
  const int colg = nb + w * 16 + m16;
  const float bias = bp[colg];
#pragma unroll
  for (int r = 0; r < 2; ++r)
#pragma unroll
    for (int j = 0; j < 4; ++j) {
      const int rowg = row0 + r * 16 + quad * 4 + j;
      float v = acc[r][j] + bias;
      if (g < 2) v = 0.5f * v * (1.0f + erff(v * 0.70710678f));
      outp[rowg * D + colg] = v;
    }
}

// ---------------------------------------------------------------------------
// K2: layer-2 (phase & amp GEMMs) + phasor epilogue. 256 blocks x 512 thr.
__global__ __launch_bounds__(512) void enc2_kernel(
    const float* __restrict__ x, const float* __restrict__ pos_k,
    const float* __restrict__ pos_q, const float* __restrict__ hk,
    const float* __restrict__ hq,
    const float* __restrict__ b2_k, const float* __restrict__ ba_k,
    const float* __restrict__ b2_q, const float* __restrict__ ba_q,
    const ushort* __restrict__ WT,
    float* __restrict__ kr, float* __restrict__ ki,
    float* __restrict__ qr, float* __restrict__ qi) {
  __shared__ __align__(16) ushort Ahh[16][40], Ahl[16][40], Axh[16][40], Axl[16][40];
  __shared__ __align__(16) ushort B2h[64][40], B2l[64][40], Bah[64][40], Bal[64][40];
  __shared__ float phL[16][68], amL[16][68];
  const int tid = threadIdx.x;
  const int e = blockIdx.x >> 7;
  const int r0g = (blockIdx.x & 127) * 16;
  const float* hsrc = e ? hq : hk;
  const float* pos = e ? pos_q : pos_k;
  const ushort* W2h = WT + WT2_OFF + (e ? 2 : 0) * 32768;
  const ushort* W2l = W2h + 16384;
  const ushort* Wah = WT + WT2_OFF + (e ? 3 : 1) * 32768;
  const ushort* Wal = Wah + 16384;
  const int w = tid >> 6, lane = tid & 63;
  const int m16 = lane & 15, quad = lane >> 4;
  const int mat = w & 1, ct = w >> 1;

  float4v acc = {};
  for (int k0 = 0; k0 < 256; k0 += 32) {
    __syncthreads();
    {
      const int half = tid >> 8;
      const int t2 = tid & 255;
      const int r = t2 >> 4, kc = (t2 & 15) * 2;
      const int row = r0g + r, l = row & (L - 1);
      if (half == 0) {
        const float2 hv = *(const float2*)&hsrc[row * D + k0 + kc];
        ushort2 h2, l2;
        h2.x = bf16_hi(hv.x); l2.x = bf16_rne(hv.x - hi_f(hv.x));
        h2.y = bf16_hi(hv.y); l2.y = bf16_rne(hv.y - hi_f(hv.y));
        *(ushort2*)&Ahh[r][kc] = h2;
        *(ushort2*)&Ahl[r][kc] = l2;
      } else {
        const float2 xv = *(const float2*)&x[row * D + k0 + kc];
        const float2 pv = *(const float2*)&pos[l * D + k0 + kc];
        const float a0 = xv.x + pv.x, a1 = xv.y + pv.y;
        ushort2 h2, l2;
        h2.x = bf16_hi(a0); l2.x = bf16_rne(a0 - hi_f(a0));
        h2.y = bf16_hi(a1); l2.y = bf16_rne(a1 - hi_f(a1));
        *(ushort2*)&Axh[r][kc] = h2;
        *(ushort2*)&Axl[r][kc] = l2;
      }
    }
    {
      const int sel = tid >> 7;
      const int idx = tid & 127;
      const int n = idx >> 1, ch = (idx & 1) * 2;
      const int ga = n * 256 + k0 + ch * 8;
      const ushort* s = (sel == 0) ? W2h : (sel == 1) ? W2l : (sel == 2) ? Wah : Wal;
      ushort* dst = (sel == 0) ? &B2h[n][ch * 8] : (sel == 1) ? &B2l[n][ch * 8]
                  : (sel == 2) ? &Bah[n][ch * 8] : &Bal[n][ch * 8];
      *(uint4*)dst = *(const uint4*)&s[ga];
      *(uint4*)(dst + 8) = *(const uint4*)&s[ga + 8];
    }
    __syncthreads();

    const short8 ah = mat ? *(const short8*)&Axh[m16][quad * 8]
                          : *(const short8*)&Ahh[m16][quad * 8];
    const short8 al = mat ? *(const short8*)&Axl[m16][quad * 8]
                          : *(const short8*)&Ahl[m16][quad * 8];
    const int col = ct * 16 + m16;
    const short8 bh = mat ? *(const short8*)&Bah[col][quad * 8]
                          : *(const short8*)&B2h[col][quad * 8];
    const short8 bl = mat ? *(const short8*)&Bal[col][quad * 8]
                          : *(const short8*)&B2l[col][quad * 8];
    acc = __builtin_amdgcn_mfma_f32_16x16x32_bf16(ah, bh, acc, 0, 0, 0);
    acc = __builtin_amdgcn_mfma_f32_16x16x32_bf16(ah, bl, acc, 0, 0, 0);
    acc = __builtin_amdgcn_mfma_f32_16x16x32_bf16(al, bh, acc, 0, 0, 0);
  }

  {
    const int colk = ct * 16 + m16;
    if (mat == 0) {
      const float b2v = (e ? b2_q : b2_k)[colk];
#pragma unroll
      for (int j = 0; j < 4; ++j)
        phL[quad * 4 + j][colk] = tanhf(acc[j] + b2v) * 3.14159265358979f;
    } else {
      const float bav = (e ? ba_q : ba_k)[colk];
#pragma unroll
      for (int j = 0; j < 4; ++j) {
        const float av = acc[j] + bav;
        amL[quad * 4 + j][colk] = fmaxf(av, 0.0f) + log1pf(expf(-fabsf(av))) + 0.1f;
      }
    }
  }
  __syncthreads();
  {
    float* pr = e ? qr : kr;
    float* pim = e ? qi : ki;
#pragma unroll
    for (int p = 0; p < 2; ++p) {
      const int idx = p * 512 + tid;
      const int r = idx >> 6, ccol = idx & 63;
      const int row = r0g + r;
      const float a = amL[r][ccol], pph = phL[r][ccol];
      pr[row * K + ccol] = a * cosf(pph);
      pim[row * K + ccol] = a * sinf(pph);
    }
  }
}

// ---------------------------------------------------------------------------
// K3: per-chunk T + V^T into TMt[b][c][d][192] = [T_re(64)|T_im(64)|Vt(64)].
__global__ __launch_bounds__(256) void tbuild_kernel(
    const float* __restrict__ kr, const float* __restrict__ ki,
    const float* __restrict__ V, float* __restrict__ TMt) {
  const int id = blockIdx.x;
  const int dc = id & 15, c = (id >> 4) & 15, b = id >> 8;
  const int tid = threadIdx.x;
  const int n0 = b * L + c * 64;
  const int dl = tid & 15;
  const int kb = tid >> 4;

  __shared__ float krL[64][68], kiL[64][68];
  __shared__ float VL[64][20];
  __shared__ float Tl[16][204];
  for (int e = tid; e < 1024; e += 256) {
    const int t = e >> 4, k4 = (e & 15) * 4;
    *(float4*)&krL[t][k4] = *(const float4*)&kr[(n0 + t) * K + k4];
    *(float4*)&kiL[t][k4] = *(const float4*)&ki[(n0 + t) * K + k4];
  }
  {
    const int t = tid >> 2, f = (tid & 3) * 4;
    *(float4*)&VL[t][f] = *(const float4*)&V[(n0 + t) * D + dc * 16 + f];
  }
  __syncthreads();

  {
    const int t0 = (tid >> 4) * 4;
#pragma unroll
    for (int i = 0; i < 4; ++i) Tl[dl][128 + t0 + i] = VL[t0 + i][dl];
  }

  float ar[4] = {0.f, 0.f, 0.f, 0.f}, ai[4] = {0.f, 0.f, 0.f, 0.f};
#pragma unroll 4
  for (int t = 0; t < 64; ++t) {
    const float vt = VL[t][dl];
    const float4 k4r = *(const float4*)&krL[t][kb * 4];
    const float4 k4i = *(const float4*)&kiL[t][kb * 4];
    ar[0] += k4r.x * vt; ar[1] += k4r.y * vt; ar[2] += k4r.z * vt; ar[3] += k4r.w * vt;
    ai[0] += k4i.x * vt; ai[1] += k4i.y * vt; ai[2] += k4i.z * vt; ai[3] += k4i.w * vt;
  }

#pragma unroll
  for (int i = 0; i < 4; ++i) {
    Tl[dl][kb * 4 + i] = ar[i];
    Tl[dl][64 + kb * 4 + i] = ai[i];
  }
  __syncthreads();

  float* dst = &TMt[(((size_t)(b * 16 + c)) * 256 + dc * 16) * 192];
#pragma unroll
  for (int p = 0; p < 3; ++p) {
    const int e = p * 256 + tid;
    const int row = e / 48, f4 = e % 48;
    *(float4*)&dst[(size_t)row * 192 + f4 * 4] = *(const float4*)&Tl[row][f4 * 4];
  }
}

// ---------------------------------------------------------------------------
// K4: ret slice via MFMA, chunk prefix folded in (round-13 LDS-staged form).
// Grid (b,c,dc8) = 256 blocks x 512 threads (8 waves).
__global__ __launch_bounds__(512) void ret_kernel(
    const float* __restrict__ qr, const float* __restrict__ qi,
    const float* __restrict__ kr, const float* __restrict__ ki,
    const float* __restrict__ TMt, float* __restrict__ ret,
    float* __restrict__ LNred) {
  __shared__ __align__(16) ushort Ah[64][200], Al[64][200];   // [Q(128)|S(64)]
  __shared__ __align__(16) ushort Kh[64][136], Kl[64][136];
  __shared__ __align__(16) ushort Bh[32][200], Bl[32][200];
  const int tid = threadIdx.x;
  const int dc = blockIdx.x & 7;
  const int c = (blockIdx.x >> 3) & 15;
  const int b = blockIdx.x >> 7;
  const int n0 = b * L + c * 64;
  const int cols0 = dc * 32;
  const int w = tid >> 6, lane = tid & 63;
  const int m16 = lane & 15, quad = lane >> 4;

  // Phase 0: stage Q -> Ah[.,0:128], K -> Kh (hi/lo)
#pragma unroll
  for (int j = 0; j < 4; ++j) {
    const int e = j * 512 + tid;
    const int row = e >> 5, c4 = e & 31;
    const int col0 = (c4 & 15) * 4;
    const int acol = (c4 < 16 ? 0 : 64) + col0;
    {
      const float* src = (c4 < 16) ? qr : qi;
      const float4 v = *(const float4*)&src[(n0 + row) * K + col0];
      ushort4 h4, l4;
      h4.x = bf16_hi(v.x); l4.x = bf16_rne(v.x - hi_f(v.x));
      h4.y = bf16_hi(v.y); l4.y = bf16_rne(v.y - hi_f(v.y));
      h4.z = bf16_hi(v.z); l4.z = bf16_rne(v.z - hi_f(v.z));
      h4.w = bf16_hi(v.w); l4.w = bf16_rne(v.w - hi_f(v.w));
      *(ushort4*)&Ah[row][acol] = h4;
      *(ushort4*)&Al[row][acol] = l4;
    }
    {
      const float* src = (c4 < 16) ? kr : ki;
      const float4 v = *(const float4*)&src[(n0 + row) * K + col0];
      ushort4 h4, l4;
      h4.x = bf16_hi(v.x); l4.x = bf16_rne(v.x - hi_f(v.x));
      h4.y = bf16_hi(v.y); l4.y = bf16_rne(v.y - hi_f(v.y));
      h4.z = bf16_hi(v.z); l4.z = bf16_rne(v.z - hi_f(v.z));
      h4.w = bf16_hi(v.w); l4.w = bf16_rne(v.w - hi_f(v.w));
      *(ushort4*)&Kh[row][acol] = h4;
      *(ushort4*)&Kl[row][acol] = l4;
    }
  }

  // Prefix accumulation (registers; coalesced per-thread row segments):
  float4 mac0 = {}, mac1 = {};
  {
    const int prow = tid >> 4, in0 = (tid & 15) * 8;
    const float* base = &TMt[(size_t)(b * 16) * 49152 +
                             (size_t)(cols0 + prow) * 192 + in0];
    for (int cp = 0; cp < c; ++cp) {
      const float* p = base + (size_t)cp * 49152;
      const float4 v0 = *(const float4*)p;
      const float4 v1 = *(const float4*)(p + 4);
      mac0.x += v0.x; mac0.y += v0.y; mac0.z += v0.z; mac0.w += v0.w;
      mac1.x += v1.x; mac1.y += v1.y; mac1.z += v1.z; mac1.w += v1.w;
    }
  }
  __syncthreads();

  // Phase 1: S = Q.K^T (64x64, inner 128), causal -> Ah[.,128:192]
  {
    const int rt = w & 3;
    const int cp = (w >> 2) * 2;
    float4v sc[2] = {};
#pragma unroll
    for (int kk = 0; kk < 128; kk += 32) {
      const short8 ah = *(const short8*)&Ah[rt * 16 + m16][kk + quad * 8];
      const short8 al = *(const short8*)&Al[rt * 16 + m16][kk + quad * 8];
#pragma unroll
      for (int cc = 0; cc < 2; ++cc) {
        const int ct = cp + cc;
        const short8 bh = *(const short8*)&Kh[ct * 16 + m16][kk + quad * 8];
        const short8 bl = *(const short8*)&Kl[ct * 16 + m16][kk + quad * 8];
        sc[cc] = __builtin_amdgcn_mfma_f32_16x16x32_bf16(ah, bh, sc[cc], 0, 0, 0);
        sc[cc] = __builtin_amdgcn_mfma_f32_16x16x32_bf16(ah, bl, sc[cc], 0, 0, 0);
        sc[cc] = __builtin_amdgcn_mfma_f32_16x16x32_bf16(al, bh, sc[cc], 0, 0, 0);
      }
    }
#pragma unroll
    for (int cc = 0; cc < 2; ++cc)
#pragma unroll
      for (int j = 0; j < 4; ++j) {
        const int row = rt * 16 + quad * 4 + j;
        const int t = (cp + cc) * 16 + m16;
        const float s = (t <= row) ? sc[cc][j] : 0.0f;
        Ah[row][128 + t] = bf16_hi(s);
        Al[row][128 + t] = bf16_rne(s - hi_f(s));
      }
  }

  // Phase 2: stage B = [M_c (from regs) | Vt_c (from TMt)] hi/lo
  {
    const int prow = tid >> 4, in0 = (tid & 15) * 8;
    ushort4 h4, l4;
    h4.x = bf16_hi(mac0.x); l4.x = bf16_rne(mac0.x - hi_f(mac0.x));
    h4.y = bf16_hi(mac0.y); l4.y = bf16_rne(mac0.y - hi_f(mac0.y));
    h4.z = bf16_hi(mac0.z); l4.z = bf16_rne(mac0.z - hi_f(mac0.z));
    h4.w = bf16_hi(mac0.w); l4.w = bf16_rne(mac0.w - hi_f(mac0.w));
    *(ushort4*)&Bh[prow][in0] = h4;
    *(ushort4*)&Bl[prow][in0] = l4;
    h4.x = bf16_hi(mac1.x); l4.x = bf16_rne(mac1.x - hi_f(mac1.x));
    h4.y = bf16_hi(mac1.y); l4.y = bf16_rne(mac1.y - hi_f(mac1.y));
    h4.z = bf16_hi(mac1.z); l4.z = bf16_rne(mac1.z - hi_f(mac1.z));
    h4.w = bf16_hi(mac1.w); l4.w = bf16_rne(mac1.w - hi_f(mac1.w));
    *(ushort4*)&Bh[prow][in0 + 4] = h4;
    *(ushort4*)&Bl[prow][in0 + 4] = l4;

    const int vrow = tid >> 4, vin = 128 + (tid & 15) * 4;
    const float4 v = *(const float4*)&TMt[(size_t)(b * 16 + c) * 49152 +
                                          (size_t)(cols0 + vrow) * 192 + vin];
    ushort4 vh, vl;
    vh.x = bf16_hi(v.x); vl.x = bf16_rne(v.x - hi_f(v.x));
    vh.y = bf16_hi(v.y); vl.y = bf16_rne(v.y - hi_f(v.y));
    vh.z = bf16_hi(v.z); vl.z = bf16_rne(v.z - hi_f(v.z));
    vh.w = bf16_hi(v.w); vl.w = bf16_rne(v.w - hi_f(v.w));
    *(ushort4*)&Bh[vrow][vin] = vh;
    *(ushort4*)&Bl[vrow][vin] = vl;
  }
  __syncthreads();

  // Phase 3: ret slice = A[64x192] . B[32][192]; 8 waves = (rt=w&3) x (ct=w>>2)
  {
    const int rt = w & 3;
    const int ct = w >> 2;   // 0..1
    float4v r2 = {};
#pragma unroll
    for (int kk = 0; kk < 6; ++kk) {
      const short8 ah = *(const short8*)&Ah[rt * 16 + m16][kk * 32 + quad * 8];
      const short8 al = *(const short8*)&Al[rt * 16 + m16][kk * 32 + quad * 8];
      const short8 bh = *(const short8*)&Bh[ct * 16 + m16][kk * 32 + quad * 8];
      const short8 bl = *(const short8*)&Bl[ct * 16 + m16][kk * 32 + quad * 8];
      r2 = __builtin_amdgcn_mfma_f32_16x16x32_bf16(ah, bh, r2, 0, 0, 0);
      r2 = __builtin_amdgcn_mfma_f32_16x16x32_bf16(ah, bl, r2, 0, 0, 0);
      r2 = __builtin_amdgcn_mfma_f32_16x16x32_bf16(al, bh, r2, 0, 0, 0);
    }
#pragma unroll
    for (int j = 0; j < 4; ++j) {
      const int rowL = rt * 16 + quad * 4 + j;
      const float nrm = rsqrtf((float)(c * 64 + rowL + 1) * 64.0f);
      const float v = r2[j] * nrm;
      ret[(size_t)(n0 + rowL) * D + cols0 + ct * 16 + m16] = v;
      float sj = v, s2j = v * v;
      for (int off = 1; off < 16; off <<= 1) {
        sj += __shfl_xor(sj, off, 64);
        s2j += __shfl_xor(s2j, off, 64);
      }
      if (m16 == 0) {
        LNred[(size_t)(n0 + rowL) * 32 + (dc * 2 + ct) * 2 + 0] = sj;
        LNred[(size_t)(n0 + rowL) * 32 + (dc * 2 + ct) * 2 + 1] = s2j;
      }
    }
  }
}

// ---------------------------------------------------------------------------
// K5: out = x + LN(ret).wo + bo via MFMA bf16x3. 256 blocks x 512 threads.
__global__ __launch_bounds__(512) void out2_kernel(
    const float* __restrict__ ret, const float* __restrict__ LNred,
    const float* __restrict__ x, const float* __restrict__ ln_g,
    const float* __restrict__ ln_b, const ushort* __restrict__ WT,
    const float* __restrict__ bo, float* __restrict__ out) {
  __shared__ __align__(16) ushort Ah[32][40], Al[32][40];
  __shared__ __align__(16) ushort Bh[64][40], Bl[64][40];
  __shared__ float mu_s[32], rs_s[32];
  const int tid = threadIdx.x;
  const int row0 = (blockIdx.x >> 2) * 32, nb = (blockIdx.x & 3) * 64;
  const ushort* Wh = WT + 3 * 131072;
  const ushort* Wl = Wh + 65536;
  const int w = tid >> 6, lane = tid & 63;
  const int m16 = lane & 15, quad = lane >> 4;
  const int rt = w & 1, cq = w >> 1;

  if (tid < 32) {
    const int row = row0 + tid;
    float s = 0.f, s2 = 0.f;
#pragma unroll
    for (int i = 0; i < 16; ++i) {
      s += LNred[(size_t)row * 32 + i * 2 + 0];
      s2 += LNred[(size_t)row * 32 + i * 2 + 1];
    }
    const float mu = s * (1.0f / 256.0f);
    mu_s[tid] = mu;
    rs_s[tid] = rsqrtf(s2 * (1.0f / 256.0f) - mu * mu + 1e-5f);
  }

  float4v acc = {};
  for (int k0 = 0; k0 < 256; k0 += 32) {
    __syncthreads();
    {
      const int r = tid >> 4, kc = (tid & 15) * 2;
      const float2 v = *(const float2*)&ret[(size_t)(row0 + r) * D + k0 + kc];
      const float2 g2 = *(const float2*)&ln_g[k0 + kc];
      const float2 b2 = *(const float2*)&ln_b[k0 + kc];
      const float mu = mu_s[r], rs = rs_s[r];
      const float a0 = (v.x - mu) * rs * g2.x + b2.x;
      const float a1 = (v.y - mu) * rs * g2.y + b2.y;
      ushort2 h2, l2;
      h2.x = bf16_hi(a0); l2.x = bf16_rne(a0 - hi_f(a0));
      h2.y = bf16_hi(a1); l2.y = bf16_rne(a1 - hi_f(a1));
      *(ushort2*)&Ah[r][kc] = h2;
      *(ushort2*)&Al[r][kc] = l2;
    }
    {
      const int plane = tid >> 8;
      const int n = (tid >> 2) & 63, chunk = tid & 3;
      const int ga = (nb + n) * 256 + k0 + chunk * 8;
      if (plane == 0) *(uint4*)&Bh[n][chunk * 8] = *(const uint4*)&Wh[ga];
      else            *(uint4*)&Bl[n][chunk * 8] = *(const uint4*)&Wl[ga];
    }
    __syncthreads();

    const short8 afh = *(const short8*)&Ah[rt * 16 + m16][quad * 8];
    const short8 afl = *(const short8*)&Al[rt * 16 + m16][quad * 8];
    const int col = cq * 16 + m16;
    const short8 bfh = *(const short8*)&Bh[col][quad * 8];
    const short8 bfl = *(const short8*)&Bl[col][quad * 8];
    acc = __builtin_amdgcn_mfma_f32_16x16x32_bf16(afh, bfh, acc, 0, 0, 0);
    acc = __builtin_amdgcn_mfma_f32_16x16x32_bf16(afh, bfl, acc, 0, 0, 0);
    acc = __builtin_amdgcn_mfma_f32_16x16x32_bf16(afl, bfh, acc, 0, 0, 0);
  }

  const int colg = nb + cq * 16 + m16;
  const float bias = bo[colg];
#pragma unroll
  for (int j = 0; j < 4; ++j) {
    const int rowg = row0 + rt * 16 + quad * 4 + j;
    out[rowg * D + colg] = x[rowg * D + colg] + acc[j] + bias;
  }
}

// ---------------------------------------------------------------------------
extern "C" void kernel_launch(void* const* d_in, const int* in_sizes, int n_in,
                              void* d_out, int out_size, void* d_ws, size_t ws_size,
                              hipStream_t stream) {
  (void)in_sizes; (void)n_in; (void)out_size; (void)ws_size;
  const float* x    = (const float*)d_in[0];
  const float* pos_k= (const float*)d_in[1];
  const float* w1_k = (const float*)d_in[2];
  const float* b1_k = (const float*)d_in[3];
  const float* w2_k = (const float*)d_in[4];
  const float* b2_k = (const float*)d_in[5];
  const float* wa_k = (const float*)d_in[6];
  const float* ba_k = (const float*)d_in[7];
  const float* pos_q= (const float*)d_in[8];
  const float* w1_q = (const float*)d_in[9];
  const float* b1_q = (const float*)d_in[10];
  const float* w2_q = (const float*)d_in[11];
  const float* b2_q = (const float*)d_in[12];
  const float* wa_q = (const float*)d_in[13];
  const float* ba_q = (const float*)d_in[14];
  const float* wv   = (const float*)d_in[15];
  const float* bv   = (const float*)d_in[16];
  const float* ln_g = (const float*)d_in[17];
  const float* ln_b = (const float*)d_in[18];
  const float* wo   = (const float*)d_in[19];
  const float* bo   = (const float*)d_in[20];

  float* ws = (float*)d_ws;
  float* kr = ws;                          // N*K
  float* ki = kr + (size_t)N * K;
  float* qr = ki + (size_t)N * K;
  float* qi = qr + (size_t)N * K;
  float* V  = qi + (size_t)N * K;          // N*D
  float* TMt = V + (size_t)N * D;          // B*NC*256*192
  float* ret = TMt + (size_t)B * NC * 256 * 192;  // N*D
  float* LNred = ret + (size_t)N * D;      // N*32
  float* hk = LNred + (size_t)N * 32;      // N*D
  float* hq = hk + (size_t)N * D;          // N*D
  ushort* WT = (ushort*)(hq + (size_t)N * D);   // 655360 ushorts

  prep_kernel<<<80, 256, 0, stream>>>(w1_k, w1_q, wv, wo,
                                      w2_k, wa_k, w2_q, wa_q, WT);
  enc1_kernel<<<768, 256, 0, stream>>>(x, pos_k, pos_q, b1_k, b1_q, bv, WT,
                                       hk, hq, V);
  enc2_kernel<<<256, 512, 0, stream>>>(x, pos_k, pos_q, hk, hq,
                                       b2_k, ba_k, b2_q, ba_q, WT,
                                       kr, ki, qr, qi);
  tbuild_kernel<<<B * NC * 16, 256, 0, stream>>>(kr, ki, V, TMt);
  ret_kernel<<<B * NC * 8, 512, 0, stream>>>(qr, qi, kr, ki, TMt, ret, LNred);
  out2_kernel<<<256, 512, 0, stream>>>(ret, LNred, x, ln_g, ln_b, WT, bo,
                                       (float*)d_out);
}

// Round 16
// 145.810 us; speedup vs baseline: 1.1894x; 1.0168x over previous
//
#include <hip/hip_runtime.h>
#include <hip/hip_bf16.h>

typedef __attribute__((ext_vector_type(8))) short short8;
typedef __attribute__((ext_vector_type(4))) float float4v;

constexpr int B = 2, L = 1024, D = 256, K = 64;
constexpr int N = B * L;          // 2048 rows
constexpr int NC = L / 64;        // 16 chunks of 64 tokens

// WT arena (ushort units):
// big mats m in {w1_k, w1_q, wv, wo}: hi at m*131072, lo at +65536
// layer2 mats m in {w2_k, wa_k, w2_q, wa_q}: hi at WT2_OFF + m*32768, lo +16384
constexpr int WT2_OFF = 524288;

__device__ __forceinline__ ushort bf16_hi(float v) {
  return (ushort)(__float_as_uint(v) >> 16);
}
__device__ __forceinline__ float hi_f(float v) {
  return __uint_as_float(__float_as_uint(v) & 0xFFFF0000u);
}
__device__ __forceinline__ ushort bf16_rne(float v) {
  uint b = __float_as_uint(v);
  b += 0x7FFF + ((b >> 16) & 1);
  return (ushort)(b >> 16);
}

// ---------------------------------------------------------------------------
// K0: transpose + hi/lo split weights into WT arena (vector writes only).
__global__ __launch_bounds__(256) void prep_kernel(
    const float* __restrict__ w1_k, const float* __restrict__ w1_q,
    const float* __restrict__ wv, const float* __restrict__ wo,
    const float* __restrict__ w2_k, const float* __restrict__ wa_k,
    const float* __restrict__ w2_q, const float* __restrict__ wa_q,
    ushort* __restrict__ WT) {
  __shared__ float Lt[64][65];
  const int bi = blockIdx.x, tid = threadIdx.x;
  const float* src;
  int ncols, k0, n0;
  ushort* dhi;
  int losz;
  if (bi < 64) {
    const int m = bi >> 4, t = bi & 15;
    src = (m == 0) ? w1_k : (m == 1) ? w1_q : (m == 2) ? wv : wo;
    ncols = 256; k0 = (t >> 2) * 64; n0 = (t & 3) * 64;
    dhi = WT + m * 131072; losz = 65536;
  } else {
    const int m = (bi - 64) >> 2, kt = (bi - 64) & 3;
    src = (m == 0) ? w2_k : (m == 1) ? wa_k : (m == 2) ? w2_q : wa_q;
    ncols = 64; k0 = kt * 64; n0 = 0;
    dhi = WT + WT2_OFF + m * 32768; losz = 16384;
  }
  ushort* dlo = dhi + losz;
  for (int p = 0; p < 16; ++p) {
    const int kr = p * 4 + (tid >> 6), nc = tid & 63;
    Lt[kr][nc] = src[(k0 + kr) * ncols + n0 + nc];
  }
  __syncthreads();
  const int n = tid >> 2, kq = tid & 3;
  uint uh[8], ul[8];
  for (int i = 0; i < 8; ++i) {
    const float v0 = Lt[kq * 16 + 2 * i][n];
    const float v1 = Lt[kq * 16 + 2 * i + 1][n];
    uh[i] = (uint)bf16_hi(v0) | ((uint)bf16_hi(v1) << 16);
    ul[i] = (uint)bf16_rne(v0 - hi_f(v0)) | ((uint)bf16_rne(v1 - hi_f(v1)) << 16);
  }
  const int oidx = (n0 + n) * 256 + k0 + kq * 16;
  *(uint4*)&dhi[oidx] = make_uint4(uh[0], uh[1], uh[2], uh[3]);
  *(uint4*)&dhi[oidx + 8] = make_uint4(uh[4], uh[5], uh[6], uh[7]);
  *(uint4*)&dlo[oidx] = make_uint4(ul[0], ul[1], ul[2], ul[3]);
  *(uint4*)&dlo[oidx + 8] = make_uint4(ul[4], ul[5], ul[6], ul[7]);
}

// ---------------------------------------------------------------------------
// K1: layer-1 as 3 GEMMs via MFMA bf16x3. 32x64 tiles, 768 blocks (3/CU).
__global__ __launch_bounds__(256) void enc1_kernel(
    const float* __restrict__ x, const float* __restrict__ pos_k,
    const float* __restrict__ pos_q,
    const float* __restrict__ b1_k, const float* __restrict__ b1_q,
    const float* __restrict__ bv, const ushort* __restrict__ WT,
    float* __restrict__ hk, float* __restrict__ hq, float* __restrict__ V) {
  __shared__ __align__(16) ushort Ah[32][40], Al[32][40];
  __shared__ __align__(16) ushort Bh[64][40], Bl[64][40];
  const int tid = threadIdx.x;
  const int g = blockIdx.x / 256;
  const int rem = blockIdx.x % 256;
  const int row0 = (rem >> 2) * 32, nb = (rem & 3) * 64;
  const float* pos = (g == 0) ? pos_k : (g == 1) ? pos_q : nullptr;
  const ushort* Wh = WT + g * 131072;
  const ushort* Wl = Wh + 65536;
  const int w = tid >> 6, lane = tid & 63;
  const int m16 = lane & 15, quad = lane >> 4;

  float4v acc[2] = {};

  for (int k0 = 0; k0 < 256; k0 += 32) {
    __syncthreads();
    {
      const int r = tid >> 3, kc = (tid & 7) * 4;
      const int row = row0 + r, l = row & (L - 1);
      float4 xv = *(const float4*)&x[row * D + k0 + kc];
      if (pos) {
        const float4 pv = *(const float4*)&pos[l * D + k0 + kc];
        xv.x += pv.x; xv.y += pv.y; xv.z += pv.z; xv.w += pv.w;
      }
      ushort4 h4, l4;
      h4.x = bf16_hi(xv.x); l4.x = bf16_rne(xv.x - hi_f(xv.x));
      h4.y = bf16_hi(xv.y); l4.y = bf16_rne(xv.y - hi_f(xv.y));
      h4.z = bf16_hi(xv.z); l4.z = bf16_rne(xv.z - hi_f(xv.z));
      h4.w = bf16_hi(xv.w); l4.w = bf16_rne(xv.w - hi_f(xv.w));
      *(ushort4*)&Ah[r][kc] = h4;
      *(ushort4*)&Al[r][kc] = l4;
    }
    {
      const int n = tid >> 2, chunk = tid & 3;
      const int ga = (nb + n) * 256 + k0 + chunk * 8;
      *(uint4*)&Bh[n][chunk * 8] = *(const uint4*)&Wh[ga];
      *(uint4*)&Bl[n][chunk * 8] = *(const uint4*)&Wl[ga];
    }
    __syncthreads();

    short8 afh[2], afl[2];
#pragma unroll
    for (int r = 0; r < 2; ++r) {
      afh[r] = *(const short8*)&Ah[r * 16 + m16][quad * 8];
      afl[r] = *(const short8*)&Al[r * 16 + m16][quad * 8];
    }
    const int col = w * 16 + m16;
    const short8 bfh = *(const short8*)&Bh[col][quad * 8];
    const short8 bfl = *(const short8*)&Bl[col][quad * 8];
#pragma unroll
    for (int r = 0; r < 2; ++r) {
      acc[r] = __builtin_amdgcn_mfma_f32_16x16x32_bf16(afh[r], bfh, acc[r], 0, 0, 0);
      acc[r] = __builtin_amdgcn_mfma_f32_16x16x32_bf16(afh[r], bfl, acc[r], 0, 0, 0);
      acc[r] = __builtin_amdgcn_mfma_f32_16x16x32_bf16(afl[r], bfh, acc[r], 0, 0, 0);
    }
  }

  float* outp = (g == 0) ? hk : (g == 1) ? hq : V;
  const float* bp = (g == 0) ? b1_k : (g == 1) ? b1_q : bv;
  const int colg = nb + w * 16 + m16;
  const float bias = bp[colg];
#pragma unroll
  for (int r = 0; r < 2; ++r)
#pragma unroll
    for (int j = 0; j < 4; ++j) {
      const int rowg = row0 + r * 16 + quad * 4 + j;
      float v = acc[r][j] + bias;
      if (g < 2) v = 0.5f * v * (1.0f + erff(v * 0.70710678f));
      outp[rowg * D + colg] = v;
    }
}

// ---------------------------------------------------------------------------
// K2: layer-2 (phase & amp GEMMs) + phasor epilogue. 256 blocks x 512 thr.
__global__ __launch_bounds__(512) void enc2_kernel(
    const float* __restrict__ x, const float* __restrict__ pos_k,
    const float* __restrict__ pos_q, const float* __restrict__ hk,
    const float* __restrict__ hq,
    const float* __restrict__ b2_k, const float* __restrict__ ba_k,
    const float* __restrict__ b2_q, const float* __restrict__ ba_q,
    const ushort* __restrict__ WT,
    float* __restrict__ kr, float* __restrict__ ki,
    float* __restrict__ qr, float* __restrict__ qi) {
  __shared__ __align__(16) ushort Ahh[16][40], Ahl[16][40], Axh[16][40], Axl[16][40];
  __shared__ __align__(16) ushort B2h[64][40], B2l[64][40], Bah[64][40], Bal[64][40];
  __shared__ float phL[16][68], amL[16][68];
  const int tid = threadIdx.x;
  const int e = blockIdx.x >> 7;
  const int r0g = (blockIdx.x & 127) * 16;
  const float* hsrc = e ? hq : hk;
  const float* pos = e ? pos_q : pos_k;
  const ushort* W2h = WT + WT2_OFF + (e ? 2 : 0) * 32768;
  const ushort* W2l = W2h + 16384;
  const ushort* Wah = WT + WT2_OFF + (e ? 3 : 1) * 32768;
  const ushort* Wal = Wah + 16384;
  const int w = tid >> 6, lane = tid & 63;
  const int m16 = lane & 15, quad = lane >> 4;
  const int mat = w & 1, ct = w >> 1;

  float4v acc = {};
  for (int k0 = 0; k0 < 256; k0 += 32) {
    __syncthreads();
    {
      const int half = tid >> 8;
      const int t2 = tid & 255;
      const int r = t2 >> 4, kc = (t2 & 15) * 2;
      const int row = r0g + r, l = row & (L - 1);
      if (half == 0) {
        const float2 hv = *(const float2*)&hsrc[row * D + k0 + kc];
        ushort2 h2, l2;
        h2.x = bf16_hi(hv.x); l2.x = bf16_rne(hv.x - hi_f(hv.x));
        h2.y = bf16_hi(hv.y); l2.y = bf16_rne(hv.y - hi_f(hv.y));
        *(ushort2*)&Ahh[r][kc] = h2;
        *(ushort2*)&Ahl[r][kc] = l2;
      } else {
        const float2 xv = *(const float2*)&x[row * D + k0 + kc];
        const float2 pv = *(const float2*)&pos[l * D + k0 + kc];
        const float a0 = xv.x + pv.x, a1 = xv.y + pv.y;
        ushort2 h2, l2;
        h2.x = bf16_hi(a0); l2.x = bf16_rne(a0 - hi_f(a0));
        h2.y = bf16_hi(a1); l2.y = bf16_rne(a1 - hi_f(a1));
        *(ushort2*)&Axh[r][kc] = h2;
        *(ushort2*)&Axl[r][kc] = l2;
      }
    }
    {
      const int sel = tid >> 7;
      const int idx = tid & 127;
      const int n = idx >> 1, ch = (idx & 1) * 2;
      const int ga = n * 256 + k0 + ch * 8;
      const ushort* s = (sel == 0) ? W2h : (sel == 1) ? W2l : (sel == 2) ? Wah : Wal;
      ushort* dst = (sel == 0) ? &B2h[n][ch * 8] : (sel == 1) ? &B2l[n][ch * 8]
                  : (sel == 2) ? &Bah[n][ch * 8] : &Bal[n][ch * 8];
      *(uint4*)dst = *(const uint4*)&s[ga];
      *(uint4*)(dst + 8) = *(const uint4*)&s[ga + 8];
    }
    __syncthreads();

    const short8 ah = mat ? *(const short8*)&Axh[m16][quad * 8]
                          : *(const short8*)&Ahh[m16][quad * 8];
    const short8 al = mat ? *(const short8*)&Axl[m16][quad * 8]
                          : *(const short8*)&Ahl[m16][quad * 8];
    const int col = ct * 16 + m16;
    const short8 bh = mat ? *(const short8*)&Bah[col][quad * 8]
                          : *(const short8*)&B2h[col][quad * 8];
    const short8 bl = mat ? *(const short8*)&Bal[col][quad * 8]
                          : *(const short8*)&B2l[col][quad * 8];
    acc = __builtin_amdgcn_mfma_f32_16x16x32_bf16(ah, bh, acc, 0, 0, 0);
    acc = __builtin_amdgcn_mfma_f32_16x16x32_bf16(ah, bl, acc, 0, 0, 0);
    acc = __builtin_amdgcn_mfma_f32_16x16x32_bf16(al, bh, acc, 0, 0, 0);
  }

  {
    const int colk = ct * 16 + m16;
    if (mat == 0) {
      const float b2v = (e ? b2_q : b2_k)[colk];
#pragma unroll
      for (int j = 0; j < 4; ++j)
        phL[quad * 4 + j][colk] = tanhf(acc[j] + b2v) * 3.14159265358979f;
    } else {
      const float bav = (e ? ba_q : ba_k)[colk];
#pragma unroll
      for (int j = 0; j < 4; ++j) {
        const float av = acc[j] + bav;
        amL[quad * 4 + j][colk] = fmaxf(av, 0.0f) + log1pf(expf(-fabsf(av))) + 0.1f;
      }
    }
  }
  __syncthreads();
  {
    float* pr = e ? qr : kr;
    float* pim = e ? qi : ki;
#pragma unroll
    for (int p = 0; p < 2; ++p) {
      const int idx = p * 512 + tid;
      const int r = idx >> 6, ccol = idx & 63;
      const int row = r0g + r;
      const float a = amL[r][ccol], pph = phL[r][ccol];
      pr[row * K + ccol] = a * cosf(pph);
      pim[row * K + ccol] = a * sinf(pph);
    }
  }
}

// ---------------------------------------------------------------------------
// K3: per-chunk T + V^T into TMt[b][c][d][192] = [T_re(64)|T_im(64)|Vt(64)].
__global__ __launch_bounds__(256) void tbuild_kernel(
    const float* __restrict__ kr, const float* __restrict__ ki,
    const float* __restrict__ V, float* __restrict__ TMt) {
  const int id = blockIdx.x;
  const int dc = id & 15, c = (id >> 4) & 15, b = id >> 8;
  const int tid = threadIdx.x;
  const int n0 = b * L + c * 64;
  const int dl = tid & 15;
  const int kb = tid >> 4;

  __shared__ float krL[64][68], kiL[64][68];
  __shared__ float VL[64][20];
  __shared__ float Tl[16][204];
  for (int e = tid; e < 1024; e += 256) {
    const int t = e >> 4, k4 = (e & 15) * 4;
    *(float4*)&krL[t][k4] = *(const float4*)&kr[(n0 + t) * K + k4];
    *(float4*)&kiL[t][k4] = *(const float4*)&ki[(n0 + t) * K + k4];
  }
  {
    const int t = tid >> 2, f = (tid & 3) * 4;
    *(float4*)&VL[t][f] = *(const float4*)&V[(n0 + t) * D + dc * 16 + f];
  }
  __syncthreads();

  {
    const int t0 = (tid >> 4) * 4;
#pragma unroll
    for (int i = 0; i < 4; ++i) Tl[dl][128 + t0 + i] = VL[t0 + i][dl];
  }

  float ar[4] = {0.f, 0.f, 0.f, 0.f}, ai[4] = {0.f, 0.f, 0.f, 0.f};
#pragma unroll 4
  for (int t = 0; t < 64; ++t) {
    const float vt = VL[t][dl];
    const float4 k4r = *(const float4*)&krL[t][kb * 4];
    const float4 k4i = *(const float4*)&kiL[t][kb * 4];
    ar[0] += k4r.x * vt; ar[1] += k4r.y * vt; ar[2] += k4r.z * vt; ar[3] += k4r.w * vt;
    ai[0] += k4i.x * vt; ai[1] += k4i.y * vt; ai[2] += k4i.z * vt; ai[3] += k4i.w * vt;
  }

#pragma unroll
  for (int i = 0; i < 4; ++i) {
    Tl[dl][kb * 4 + i] = ar[i];
    Tl[dl][64 + kb * 4 + i] = ai[i];
  }
  __syncthreads();

  float* dst = &TMt[(((size_t)(b * 16 + c)) * 256 + dc * 16) * 192];
#pragma unroll
  for (int p = 0; p < 3; ++p) {
    const int e = p * 256 + tid;
    const int row = e / 48, f4 = e % 48;
    *(float4*)&dst[(size_t)row * 192 + f4 * 4] = *(const float4*)&Tl[row][f4 * 4];
  }
}

// ---------------------------------------------------------------------------
// K4: ret slice via MFMA, prefix folded in. 512 blocks (dc16) x 256 threads,
// 77 KB LDS -> 2 blocks/CU. S stored bf16-hi only; K region reused for B.
__global__ __launch_bounds__(256) void ret_kernel(
    const float* __restrict__ qr, const float* __restrict__ qi,
    const float* __restrict__ kr, const float* __restrict__ ki,
    const float* __restrict__ TMt, float* __restrict__ ret,
    float* __restrict__ LNred) {
  __shared__ __align__(16) ushort Qh[64][136], Ql[64][136];   // 34 KB
  __shared__ __align__(16) ushort Sh[64][72];                 // 9 KB (hi only)
  __shared__ __align__(16) char KB[34816];                    // K planes / B planes
  ushort* Kh = (ushort*)KB;              // [64][136]
  ushort* Kl = Kh + 64 * 136;
  ushort* Bh = (ushort*)KB;              // [16][200]
  ushort* Bl = Bh + 16 * 200;

  const int tid = threadIdx.x;
  const int dc = blockIdx.x & 15;
  const int c = (blockIdx.x >> 4) & 15;
  const int b = blockIdx.x >> 8;
  const int n0 = b * L + c * 64;
  const int cols0 = dc * 16;
  const int w = tid >> 6, lane = tid & 63;
  const int m16 = lane & 15, quad = lane >> 4;

  // Phase 0: stage Q, K (hi/lo)
#pragma unroll
  for (int j = 0; j < 8; ++j) {
    const int e = j * 256 + tid;
    const int row = e >> 5, c4 = e & 31;
    const int col0 = (c4 & 15) * 4;
    const int acol = (c4 < 16 ? 0 : 64) + col0;
    {
      const float* src = (c4 < 16) ? qr : qi;
      const float4 v = *(const float4*)&src[(n0 + row) * K + col0];
      ushort4 h4, l4;
      h4.x = bf16_hi(v.x); l4.x = bf16_rne(v.x - hi_f(v.x));
      h4.y = bf16_hi(v.y); l4.y = bf16_rne(v.y - hi_f(v.y));
      h4.z = bf16_hi(v.z); l4.z = bf16_rne(v.z - hi_f(v.z));
      h4.w = bf16_hi(v.w); l4.w = bf16_rne(v.w - hi_f(v.w));
      *(ushort4*)&Qh[row][acol] = h4;
      *(ushort4*)&Ql[row][acol] = l4;
    }
    {
      const float* src = (c4 < 16) ? kr : ki;
      const float4 v = *(const float4*)&src[(n0 + row) * K + col0];
      ushort4 h4, l4;
      h4.x = bf16_hi(v.x); l4.x = bf16_rne(v.x - hi_f(v.x));
      h4.y = bf16_hi(v.y); l4.y = bf16_rne(v.y - hi_f(v.y));
      h4.z = bf16_hi(v.z); l4.z = bf16_rne(v.z - hi_f(v.z));
      h4.w = bf16_hi(v.w); l4.w = bf16_rne(v.w - hi_f(v.w));
      *(ushort4*)&Kh[row * 136 + acol] = h4;
      *(ushort4*)&Kl[row * 136 + acol] = l4;
    }
  }

  // Prefix accumulation (registers; coalesced 8-float row segments)
  float4 mac0 = {}, mac1 = {};
  {
    const int prow = tid >> 4, in0 = (tid & 15) * 8;
    const float* base = &TMt[(size_t)(b * 16) * 49152 +
                             (size_t)(cols0 + prow) * 192 + in0];
    for (int cp = 0; cp < c; ++cp) {
      const float* p = base + (size_t)cp * 49152;
      const float4 v0 = *(const float4*)p;
      const float4 v1 = *(const float4*)(p + 4);
      mac0.x += v0.x; mac0.y += v0.y; mac0.z += v0.z; mac0.w += v0.w;
      mac1.x += v1.x; mac1.y += v1.y; mac1.z += v1.z; mac1.w += v1.w;
    }
  }
  __syncthreads();

  // Phase 1: S = Q.K^T (64x64, inner 128), causal. Wave w: rows w*16..,
  // all 64 t-cols (4 fragments).
  {
    float4v sc[4] = {};
#pragma unroll
    for (int kk = 0; kk < 128; kk += 32) {
      const short8 ah = *(const short8*)&Qh[w * 16 + m16][kk + quad * 8];
      const short8 al = *(const short8*)&Ql[w * 16 + m16][kk + quad * 8];
#pragma unroll
      for (int ct = 0; ct < 4; ++ct) {
        const short8 bh = *(const short8*)&Kh[(ct * 16 + m16) * 136 + kk + quad * 8];
        const short8 bl = *(const short8*)&Kl[(ct * 16 + m16) * 136 + kk + quad * 8];
        sc[ct] = __builtin_amdgcn_mfma_f32_16x16x32_bf16(ah, bh, sc[ct], 0, 0, 0);
        sc[ct] = __builtin_amdgcn_mfma_f32_16x16x32_bf16(ah, bl, sc[ct], 0, 0, 0);
        sc[ct] = __builtin_amdgcn_mfma_f32_16x16x32_bf16(al, bh, sc[ct], 0, 0, 0);
      }
    }
#pragma unroll
    for (int ct = 0; ct < 4; ++ct)
#pragma unroll
      for (int j = 0; j < 4; ++j) {
        const int row = w * 16 + quad * 4 + j;
        const int t = ct * 16 + m16;
        Sh[row][t] = (t <= row) ? bf16_hi(sc[ct][j]) : (ushort)0;
      }
  }
  __syncthreads();   // K reads done; Sh written

  // Phase 2: stage B = [M_c (regs) | Vt_c (TMt)] hi/lo into KB region
  {
    const int prow = tid >> 4, in0 = (tid & 15) * 8;
    ushort4 h4, l4;
    h4.x = bf16_hi(mac0.x); l4.x = bf16_rne(mac0.x - hi_f(mac0.x));
    h4.y = bf16_hi(mac0.y); l4.y = bf16_rne(mac0.y - hi_f(mac0.y));
    h4.z = bf16_hi(mac0.z); l4.z = bf16_rne(mac0.z - hi_f(mac0.z));
    h4.w = bf16_hi(mac0.w); l4.w = bf16_rne(mac0.w - hi_f(mac0.w));
    *(ushort4*)&Bh[prow * 200 + in0] = h4;
    *(ushort4*)&Bl[prow * 200 + in0] = l4;
    h4.x = bf16_hi(mac1.x); l4.x = bf16_rne(mac1.x - hi_f(mac1.x));
    h4.y = bf16_hi(mac1.y); l4.y = bf16_rne(mac1.y - hi_f(mac1.y));
    h4.z = bf16_hi(mac1.z); l4.z = bf16_rne(mac1.z - hi_f(mac1.z));
    h4.w = bf16_hi(mac1.w); l4.w = bf16_rne(mac1.w - hi_f(mac1.w));
    *(ushort4*)&Bh[prow * 200 + in0 + 4] = h4;
    *(ushort4*)&Bl[prow * 200 + in0 + 4] = l4;

    const int vrow = tid >> 4, vin = 128 + (tid & 15) * 4;
    const float4 v = *(const float4*)&TMt[(size_t)(b * 16 + c) * 49152 +
                                          (size_t)(cols0 + vrow) * 192 + vin];
    ushort4 vh, vl;
    vh.x = bf16_hi(v.x); vl.x = bf16_rne(v.x - hi_f(v.x));
    vh.y = bf16_hi(v.y); vl.y = bf16_rne(v.y - hi_f(v.y));
    vh.z = bf16_hi(v.z); vl.z = bf16_rne(v.z - hi_f(v.z));
    vh.w = bf16_hi(v.w); vl.w = bf16_rne(v.w - hi_f(v.w));
    *(ushort4*)&Bh[vrow * 200 + vin] = vh;
    *(ushort4*)&Bl[vrow * 200 + vin] = vl;
  }
  __syncthreads();

  // Phase 3: ret slice = [Q|S].[M;Vt], inner 192. Wave w: rows w*16..,
  // cols cols0 + m16 (one 16-col fragment).
  {
    float4v r2 = {};
#pragma unroll
    for (int kk = 0; kk < 4; ++kk) {     // Q x M
      const short8 ah = *(const short8*)&Qh[w * 16 + m16][kk * 32 + quad * 8];
      const short8 al = *(const short8*)&Ql[w * 16 + m16][kk * 32 + quad * 8];
      const short8 bh = *(const short8*)&Bh[m16 * 200 + kk * 32 + quad * 8];
      const short8 bl = *(const short8*)&Bl[m16 * 200 + kk * 32 + quad * 8];
      r2 = __builtin_amdgcn_mfma_f32_16x16x32_bf16(ah, bh, r2, 0, 0, 0);
      r2 = __builtin_amdgcn_mfma_f32_16x16x32_bf16(ah, bl, r2, 0, 0, 0);
      r2 = __builtin_amdgcn_mfma_f32_16x16x32_bf16(al, bh, r2, 0, 0, 0);
    }
#pragma unroll
    for (int s2 = 0; s2 < 2; ++s2) {     // S x Vt (S hi-only)
      const short8 ah = *(const short8*)&Sh[w * 16 + m16][s2 * 32 + quad * 8];
      const short8 bh = *(const short8*)&Bh[m16 * 200 + 128 + s2 * 32 + quad * 8];
      const short8 bl = *(const short8*)&Bl[m16 * 200 + 128 + s2 * 32 + quad * 8];
      r2 = __builtin_amdgcn_mfma_f32_16x16x32_bf16(ah, bh, r2, 0, 0, 0);
      r2 = __builtin_amdgcn_mfma_f32_16x16x32_bf16(ah, bl, r2, 0, 0, 0);
    }
#pragma unroll
    for (int j = 0; j < 4; ++j) {
      const int rowL = w * 16 + quad * 4 + j;
      const float nrm = rsqrtf((float)(c * 64 + rowL + 1) * 64.0f);
      const float v = r2[j] * nrm;
      ret[(size_t)(n0 + rowL) * D + cols0 + m16] = v;
      float sj = v, s2j = v * v;
      for (int off = 1; off < 16; off <<= 1) {
        sj += __shfl_xor(sj, off, 64);
        s2j += __shfl_xor(s2j, off, 64);
      }
      if (m16 == 0) {
        LNred[(size_t)(n0 + rowL) * 32 + dc * 2 + 0] = sj;
        LNred[(size_t)(n0 + rowL) * 32 + dc * 2 + 1] = s2j;
      }
    }
  }
}

// ---------------------------------------------------------------------------
// K5: out = x + LN(ret).wo + bo via MFMA bf16x3. 512 blocks x 256 threads
// (32-row x 32-col tiles, 20 KB LDS -> 2 blocks/CU).
__global__ __launch_bounds__(256) void out2_kernel(
    const float* __restrict__ ret, const float* __restrict__ LNred,
    const float* __restrict__ x, const float* __restrict__ ln_g,
    const float* __restrict__ ln_b, const ushort* __restrict__ WT,
    const float* __restrict__ bo, float* __restrict__ out) {
  __shared__ __align__(16) ushort Ah[32][40], Al[32][40];
  __shared__ __align__(16) ushort Bh[32][40], Bl[32][40];
  __shared__ float mu_s[32], rs_s[32];
  const int tid = threadIdx.x;
  const int row0 = (blockIdx.x >> 3) * 32, nb = (blockIdx.x & 7) * 32;
  const ushort* Wh = WT + 3 * 131072;
  const ushort* Wl = Wh + 65536;
  const int w = tid >> 6, lane = tid & 63;
  const int m16 = lane & 15, quad = lane >> 4;
  const int rt = w & 1, cq = w >> 1;

  if (tid < 32) {
    const int row = row0 + tid;
    float s = 0.f, s2 = 0.f;
#pragma unroll
    for (int i = 0; i < 16; ++i) {
      s += LNred[(size_t)row * 32 + i * 2 + 0];
      s2 += LNred[(size_t)row * 32 + i * 2 + 1];
    }
    const float mu = s * (1.0f / 256.0f);
    mu_s[tid] = mu;
    rs_s[tid] = rsqrtf(s2 * (1.0f / 256.0f) - mu * mu + 1e-5f);
  }

  float4v acc = {};
  for (int k0 = 0; k0 < 256; k0 += 32) {
    __syncthreads();
    {  // stage A: rn = (ret - mu)*rs*g + b, hi/lo (float4 per thread)
      const int r = tid >> 3, kc = (tid & 7) * 4;
      const float4 v = *(const float4*)&ret[(size_t)(row0 + r) * D + k0 + kc];
      const float4 g4 = *(const float4*)&ln_g[k0 + kc];
      const float4 b4 = *(const float4*)&ln_b[k0 + kc];
      const float mu = mu_s[r], rs = rs_s[r];
      float a0 = (v.x - mu) * rs * g4.x + b4.x;
      float a1 = (v.y - mu) * rs * g4.y + b4.y;
      float a2 = (v.z - mu) * rs * g4.z + b4.z;
      float a3 = (v.w - mu) * rs * g4.w + b4.w;
      ushort4 h4, l4;
      h4.x = bf16_hi(a0); l4.x = bf16_rne(a0 - hi_f(a0));
      h4.y = bf16_hi(a1); l4.y = bf16_rne(a1 - hi_f(a1));
      h4.z = bf16_hi(a2); l4.z = bf16_rne(a2 - hi_f(a2));
      h4.w = bf16_hi(a3); l4.w = bf16_rne(a3 - hi_f(a3));
      *(ushort4*)&Ah[r][kc] = h4;
      *(ushort4*)&Al[r][kc] = l4;
    }
    {  // stage B: 32 cols x 32 k, hi plane threads 0..127, lo 128..255
      const int plane = tid >> 7;
      const int idx = tid & 127;
      const int n = idx >> 2, chunk = idx & 3;
      const int ga = (nb + n) * 256 + k0 + chunk * 8;
      if (plane == 0) *(uint4*)&Bh[n][chunk * 8] = *(const uint4*)&Wh[ga];
      else            *(uint4*)&Bl[n][chunk * 8] = *(const uint4*)&Wl[ga];
    }
    __syncthreads();

    const short8 afh = *(const short8*)&Ah[rt * 16 + m16][quad * 8];
    const short8 afl = *(const short8*)&Al[rt * 16 + m16][quad * 8];
    const int col = cq * 16 + m16;
    const short8 bfh = *(const short8*)&Bh[col][quad * 8];
    const short8 bfl = *(const short8*)&Bl[col][quad * 8];
    acc = __builtin_amdgcn_mfma_f32_16x16x32_bf16(afh, bfh, acc, 0, 0, 0);
    acc = __builtin_amdgcn_mfma_f32_16x16x32_bf16(afh, bfl, acc, 0, 0, 0);
    acc = __builtin_amdgcn_mfma_f32_16x16x32_bf16(afl, bfh, acc, 0, 0, 0);
  }

  const int colg = nb + cq * 16 + m16;
  const float bias = bo[colg];
#pragma unroll
  for (int j = 0; j < 4; ++j) {
    const int rowg = row0 + rt * 16 + quad * 4 + j;
    out[rowg * D + colg] = x[rowg * D + colg] + acc[j] + bias;
  }
}

// ---------------------------------------------------------------------------
extern "C" void kernel_launch(void* const* d_in, const int* in_sizes, int n_in,
                              void* d_out, int out_size, void* d_ws, size_t ws_size,
                              hipStream_t stream) {
  (void)in_sizes; (void)n_in; (void)out_size; (void)ws_size;
  const float* x    = (const float*)d_in[0];
  const float* pos_k= (const float*)d_in[1];
  const float* w1_k = (const float*)d_in[2];
  const float* b1_k = (const float*)d_in[3];
  const float* w2_k = (const float*)d_in[4];
  const float* b2_k = (const float*)d_in[5];
  const float* wa_k = (const float*)d_in[6];
  const float* ba_k = (const float*)d_in[7];
  const float* pos_q= (const float*)d_in[8];
  const float* w1_q = (const float*)d_in[9];
  const float* b1_q = (const float*)d_in[10];
  const float* w2_q = (const float*)d_in[11];
  const float* b2_q = (const float*)d_in[12];
  const float* wa_q = (const float*)d_in[13];
  const float* ba_q = (const float*)d_in[14];
  const float* wv   = (const float*)d_in[15];
  const float* bv   = (const float*)d_in[16];
  const float* ln_g = (const float*)d_in[17];
  const float* ln_b = (const float*)d_in[18];
  const float* wo   = (const float*)d_in[19];
  const float* bo   = (const float*)d_in[20];

  float* ws = (float*)d_ws;
  float* kr = ws;                          // N*K
  float* ki = kr + (size_t)N * K;
  float* qr = ki + (size_t)N * K;
  float* qi = qr + (size_t)N * K;
  float* V  = qi + (size_t)N * K;          // N*D
  float* TMt = V + (size_t)N * D;          // B*NC*256*192
  float* ret = TMt + (size_t)B * NC * 256 * 192;  // N*D
  float* LNred = ret + (size_t)N * D;      // N*32
  float* hk = LNred + (size_t)N * 32;      // N*D
  float* hq = hk + (size_t)N * D;          // N*D
  ushort* WT = (ushort*)(hq + (size_t)N * D);   // 655360 ushorts

  prep_kernel<<<80, 256, 0, stream>>>(w1_k, w1_q, wv, wo,
                                      w2_k, wa_k, w2_q, wa_q, WT);
  enc1_kernel<<<768, 256, 0, stream>>>(x, pos_k, pos_q, b1_k, b1_q, bv, WT,
                                       hk, hq, V);
  enc2_kernel<<<256, 512, 0, stream>>>(x, pos_k, pos_q, hk, hq,
                                       b2_k, ba_k, b2_q, ba_q, WT,
                                       kr, ki, qr, qi);
  tbuild_kernel<<<B * NC * 16, 256, 0, stream>>>(kr, ki, V, TMt);
  ret_kernel<<<B * NC * 16, 256, 0, stream>>>(qr, qi, kr, ki, TMt, ret, LNred);
  out2_kernel<<<512, 256, 0, stream>>>(ret, LNred, x, ln_g, ln_b, WT, bo,
                                       (float*)d_out);
}

// Round 17
// 144.865 us; speedup vs baseline: 1.1971x; 1.0065x over previous
//
#include <hip/hip_runtime.h>
#include <hip/hip_bf16.h>

typedef __attribute__((ext_vector_type(8))) short short8;
typedef __attribute__((ext_vector_type(4))) float float4v;

constexpr int B = 2, L = 1024, D = 256, K = 64;
constexpr int N = B * L;          // 2048 rows
constexpr int NC = L / 64;        // 16 chunks of 64 tokens

// WT arena (ushort units):
// big mats m in {w1_k, w1_q, wv, wo}: hi at m*131072, lo at +65536
// layer2 mats m in {w2_k, wa_k, w2_q, wa_q}: hi at WT2_OFF + m*32768, lo +16384
constexpr int WT2_OFF = 524288;

__device__ __forceinline__ ushort bf16_hi(float v) {
  return (ushort)(__float_as_uint(v) >> 16);
}
__device__ __forceinline__ float hi_f(float v) {
  return __uint_as_float(__float_as_uint(v) & 0xFFFF0000u);
}
__device__ __forceinline__ ushort bf16_rne(float v) {
  uint b = __float_as_uint(v);
  b += 0x7FFF + ((b >> 16) & 1);
  return (ushort)(b >> 16);
}

// ---------------------------------------------------------------------------
// K0: transpose + hi/lo split weights into WT arena (vector writes only).
__global__ __launch_bounds__(256) void prep_kernel(
    const float* __restrict__ w1_k, const float* __restrict__ w1_q,
    const float* __restrict__ wv, const float* __restrict__ wo,
    const float* __restrict__ w2_k, const float* __restrict__ wa_k,
    const float* __restrict__ w2_q, const float* __restrict__ wa_q,
    ushort* __restrict__ WT) {
  __shared__ float Lt[64][65];
  const int bi = blockIdx.x, tid = threadIdx.x;
  const float* src;
  int ncols, k0, n0;
  ushort* dhi;
  int losz;
  if (bi < 64) {
    const int m = bi >> 4, t = bi & 15;
    src = (m == 0) ? w1_k : (m == 1) ? w1_q : (m == 2) ? wv : wo;
    ncols = 256; k0 = (t >> 2) * 64; n0 = (t & 3) * 64;
    dhi = WT + m * 131072; losz = 65536;
  } else {
    const int m = (bi - 64) >> 2, kt = (bi - 64) & 3;
    src = (m == 0) ? w2_k : (m == 1) ? wa_k : (m == 2) ? w2_q : wa_q;
    ncols = 64; k0 = kt * 64; n0 = 0;
    dhi = WT + WT2_OFF + m * 32768; losz = 16384;
  }
  ushort* dlo = dhi + losz;
  for (int p = 0; p < 16; ++p) {
    const int kr = p * 4 + (tid >> 6), nc = tid & 63;
    Lt[kr][nc] = src[(k0 + kr) * ncols + n0 + nc];
  }
  __syncthreads();
  const int n = tid >> 2, kq = tid & 3;
  uint uh[8], ul[8];
  for (int i = 0; i < 8; ++i) {
    const float v0 = Lt[kq * 16 + 2 * i][n];
    const float v1 = Lt[kq * 16 + 2 * i + 1][n];
    uh[i] = (uint)bf16_hi(v0) | ((uint)bf16_hi(v1) << 16);
    ul[i] = (uint)bf16_rne(v0 - hi_f(v0)) | ((uint)bf16_rne(v1 - hi_f(v1)) << 16);
  }
  const int oidx = (n0 + n) * 256 + k0 + kq * 16;
  *(uint4*)&dhi[oidx] = make_uint4(uh[0], uh[1], uh[2], uh[3]);
  *(uint4*)&dhi[oidx + 8] = make_uint4(uh[4], uh[5], uh[6], uh[7]);
  *(uint4*)&dlo[oidx] = make_uint4(ul[0], ul[1], ul[2], ul[3]);
  *(uint4*)&dlo[oidx + 8] = make_uint4(ul[4], ul[5], ul[6], ul[7]);
}

// ---------------------------------------------------------------------------
// K1: layer-1 as 3 GEMMs via MFMA bf16x3. 32x64 tiles, 768 blocks (3/CU).
__global__ __launch_bounds__(256) void enc1_kernel(
    const float* __restrict__ x, const float* __restrict__ pos_k,
    const float* __restrict__ pos_q,
    const float* __restrict__ b1_k, const float* __restrict__ b1_q,
    const float* __restrict__ bv, const ushort* __restrict__ WT,
    float* __restrict__ hk, float* __restrict__ hq, float* __restrict__ V) {
  __shared__ __align__(16) ushort Ah[32][40], Al[32][40];
  __shared__ __align__(16) ushort Bh[64][40], Bl[64][40];
  const int tid = threadIdx.x;
  const int g = blockIdx.x / 256;
  const int rem = blockIdx.x % 256;
  const int row0 = (rem >> 2) * 32, nb = (rem & 3) * 64;
  const float* pos = (g == 0) ? pos_k : (g == 1) ? pos_q : nullptr;
  const ushort* Wh = WT + g * 131072;
  const ushort* Wl = Wh + 65536;
  const int w = tid >> 6, lane = tid & 63;
  const int m16 = lane & 15, quad = lane >> 4;

  float4v acc[2] = {};

  for (int k0 = 0; k0 < 256; k0 += 32) {
    __syncthreads();
    {
      const int r = tid >> 3, kc = (tid & 7) * 4;
      const int row = row0 + r, l = row & (L - 1);
      float4 xv = *(const float4*)&x[row * D + k0 + kc];
      if (pos) {
        const float4 pv = *(const float4*)&pos[l * D + k0 + kc];
        xv.x += pv.x; xv.y += pv.y; xv.z += pv.z; xv.w += pv.w;
      }
      ushort4 h4, l4;
      h4.x = bf16_hi(xv.x); l4.x = bf16_rne(xv.x - hi_f(xv.x));
      h4.y = bf16_hi(xv.y); l4.y = bf16_rne(xv.y - hi_f(xv.y));
      h4.z = bf16_hi(xv.z); l4.z = bf16_rne(xv.z - hi_f(xv.z));
      h4.w = bf16_hi(xv.w); l4.w = bf16_rne(xv.w - hi_f(xv.w));
      *(ushort4*)&Ah[r][kc] = h4;
      *(ushort4*)&Al[r][kc] = l4;
    }
    {
      const int n = tid >> 2, chunk = tid & 3;
      const int ga = (nb + n) * 256 + k0 + chunk * 8;
      *(uint4*)&Bh[n][chunk * 8] = *(const uint4*)&Wh[ga];
      *(uint4*)&Bl[n][chunk * 8] = *(const uint4*)&Wl[ga];
    }
    __syncthreads();

    short8 afh[2], afl[2];
#pragma unroll
    for (int r = 0; r < 2; ++r) {
      afh[r] = *(const short8*)&Ah[r * 16 + m16][quad * 8];
      afl[r] = *(const short8*)&Al[r * 16 + m16][quad * 8];
    }
    const int col = w * 16 + m16;
    const short8 bfh = *(const short8*)&Bh[col][quad * 8];
    const short8 bfl = *(const short8*)&Bl[col][quad * 8];
#pragma unroll
    for (int r = 0; r < 2; ++r) {
      acc[r] = __builtin_amdgcn_mfma_f32_16x16x32_bf16(afh[r], bfh, acc[r], 0, 0, 0);
      acc[r] = __builtin_amdgcn_mfma_f32_16x16x32_bf16(afh[r], bfl, acc[r], 0, 0, 0);
      acc[r] = __builtin_amdgcn_mfma_f32_16x16x32_bf16(afl[r], bfh, acc[r], 0, 0, 0);
    }
  }

  float* outp = (g == 0) ? hk : (g == 1) ? hq : V;
  const float* bp = (g == 0) ? b1_k : (g == 1) ? b1_q : bv;
  const int colg = nb + w * 16 + m16;
  const float bias = bp[colg];
#pragma unroll
  for (int r = 0; r < 2; ++r)
#pragma unroll
    for (int j = 0; j < 4; ++j) {
      const int rowg = row0 + r * 16 + quad * 4 + j;
      float v = acc[r][j] + bias;
      if (g < 2) v = 0.5f * v * (1.0f + erff(v * 0.70710678f));
      outp[rowg * D + colg] = v;
    }
}

// ---------------------------------------------------------------------------
// K2: layer-2 (phase & amp GEMMs) + phasor epilogue.
// 512 blocks x 256 threads: (e, 16-row tile, 32-col half). 4 waves:
// mat = w&1 (phase|amp), ct = w>>1 (two 16-col fragments of the half).
__global__ __launch_bounds__(256) void enc2_kernel(
    const float* __restrict__ x, const float* __restrict__ pos_k,
    const float* __restrict__ pos_q, const float* __restrict__ hk,
    const float* __restrict__ hq,
    const float* __restrict__ b2_k, const float* __restrict__ ba_k,
    const float* __restrict__ b2_q, const float* __restrict__ ba_q,
    const ushort* __restrict__ WT,
    float* __restrict__ kr, float* __restrict__ ki,
    float* __restrict__ qr, float* __restrict__ qi) {
  __shared__ __align__(16) ushort Ahh[16][40], Ahl[16][40], Axh[16][40], Axl[16][40];
  __shared__ __align__(16) ushort B2h[32][40], B2l[32][40], Bah[32][40], Bal[32][40];
  __shared__ float phL[16][36], amL[16][36];
  const int tid = threadIdx.x;
  const int e = blockIdx.x >> 8;
  const int rem = blockIdx.x & 255;
  const int r0g = (rem >> 1) * 16;
  const int colbase = (rem & 1) * 32;
  const float* hsrc = e ? hq : hk;
  const float* pos = e ? pos_q : pos_k;
  const ushort* W2h = WT + WT2_OFF + (e ? 2 : 0) * 32768;
  const ushort* W2l = W2h + 16384;
  const ushort* Wah = WT + WT2_OFF + (e ? 3 : 1) * 32768;
  const ushort* Wal = Wah + 16384;
  const int w = tid >> 6, lane = tid & 63;
  const int m16 = lane & 15, quad = lane >> 4;
  const int mat = w & 1, ct = w >> 1;

  float4v acc = {};
  for (int k0 = 0; k0 < 256; k0 += 32) {
    __syncthreads();
    {  // stage A: half 0 stages h, half 1 stages xa = x+pos (hi/lo, float4)
      const int half = tid >> 7;
      const int t2 = tid & 127;
      const int r = t2 >> 3, kc = (t2 & 7) * 4;
      const int row = r0g + r, l = row & (L - 1);
      if (half == 0) {
        const float4 hv = *(const float4*)&hsrc[row * D + k0 + kc];
        ushort4 h4, l4;
        h4.x = bf16_hi(hv.x); l4.x = bf16_rne(hv.x - hi_f(hv.x));
        h4.y = bf16_hi(hv.y); l4.y = bf16_rne(hv.y - hi_f(hv.y));
        h4.z = bf16_hi(hv.z); l4.z = bf16_rne(hv.z - hi_f(hv.z));
        h4.w = bf16_hi(hv.w); l4.w = bf16_rne(hv.w - hi_f(hv.w));
        *(ushort4*)&Ahh[r][kc] = h4;
        *(ushort4*)&Ahl[r][kc] = l4;
      } else {
        const float4 xv = *(const float4*)&x[row * D + k0 + kc];
        const float4 pv = *(const float4*)&pos[l * D + k0 + kc];
        const float a0 = xv.x + pv.x, a1 = xv.y + pv.y;
        const float a2 = xv.z + pv.z, a3 = xv.w + pv.w;
        ushort4 h4, l4;
        h4.x = bf16_hi(a0); l4.x = bf16_rne(a0 - hi_f(a0));
        h4.y = bf16_hi(a1); l4.y = bf16_rne(a1 - hi_f(a1));
        h4.z = bf16_hi(a2); l4.z = bf16_rne(a2 - hi_f(a2));
        h4.w = bf16_hi(a3); l4.w = bf16_rne(a3 - hi_f(a3));
        *(ushort4*)&Axh[r][kc] = h4;
        *(ushort4*)&Axl[r][kc] = l4;
      }
    }
    {  // stage B: 4 planes x 32 rows x 32 k; 2 uint4 per thread
      const int sel = tid >> 6;         // 0: B2h, 1: B2l, 2: Bah, 3: Bal
      const int idx = tid & 63;
      const int n = idx >> 1, ch = (idx & 1) * 2;
      const int ga = (colbase + n) * 256 + k0 + ch * 8;
      const ushort* s = (sel == 0) ? W2h : (sel == 1) ? W2l : (sel == 2) ? Wah : Wal;
      ushort* dst = (sel == 0) ? &B2h[n][ch * 8] : (sel == 1) ? &B2l[n][ch * 8]
                  : (sel == 2) ? &Bah[n][ch * 8] : &Bal[n][ch * 8];
      *(uint4*)dst = *(const uint4*)&s[ga];
      *(uint4*)(dst + 8) = *(const uint4*)&s[ga + 8];
    }
    __syncthreads();

    const short8 ah = mat ? *(const short8*)&Axh[m16][quad * 8]
                          : *(const short8*)&Ahh[m16][quad * 8];
    const short8 al = mat ? *(const short8*)&Axl[m16][quad * 8]
                          : *(const short8*)&Ahl[m16][quad * 8];
    const int col = ct * 16 + m16;
    const short8 bh = mat ? *(const short8*)&Bah[col][quad * 8]
                          : *(const short8*)&B2h[col][quad * 8];
    const short8 bl = mat ? *(const short8*)&Bal[col][quad * 8]
                          : *(const short8*)&B2l[col][quad * 8];
    acc = __builtin_amdgcn_mfma_f32_16x16x32_bf16(ah, bh, acc, 0, 0, 0);
    acc = __builtin_amdgcn_mfma_f32_16x16x32_bf16(ah, bl, acc, 0, 0, 0);
    acc = __builtin_amdgcn_mfma_f32_16x16x32_bf16(al, bh, acc, 0, 0, 0);
  }

  {
    const int lcol = ct * 16 + m16;
    const int colk = colbase + lcol;
    if (mat == 0) {
      const float b2v = (e ? b2_q : b2_k)[colk];
#pragma unroll
      for (int j = 0; j < 4; ++j)
        phL[quad * 4 + j][lcol] = tanhf(acc[j] + b2v) * 3.14159265358979f;
    } else {
      const float bav = (e ? ba_q : ba_k)[colk];
#pragma unroll
      for (int j = 0; j < 4; ++j) {
        const float av = acc[j] + bav;
        amL[quad * 4 + j][lcol] = fmaxf(av, 0.0f) + log1pf(expf(-fabsf(av))) + 0.1f;
      }
    }
  }
  __syncthreads();
  {
    float* pr = e ? qr : kr;
    float* pim = e ? qi : ki;
#pragma unroll
    for (int p = 0; p < 2; ++p) {
      const int idx = p * 256 + tid;    // 512 = 16 rows x 32 cols
      const int r = idx >> 5, lcol = idx & 31;
      const int row = r0g + r;
      const float a = amL[r][lcol], pph = phL[r][lcol];
      pr[row * K + colbase + lcol] = a * cosf(pph);
      pim[row * K + colbase + lcol] = a * sinf(pph);
    }
  }
}

// ---------------------------------------------------------------------------
// K3: per-chunk T + V^T into TMt[b][c][d][192] = [T_re(64)|T_im(64)|Vt(64)].
__global__ __launch_bounds__(256) void tbuild_kernel(
    const float* __restrict__ kr, const float* __restrict__ ki,
    const float* __restrict__ V, float* __restrict__ TMt) {
  const int id = blockIdx.x;
  const int dc = id & 15, c = (id >> 4) & 15, b = id >> 8;
  const int tid = threadIdx.x;
  const int n0 = b * L + c * 64;
  const int dl = tid & 15;
  const int kb = tid >> 4;

  __shared__ float krL[64][68], kiL[64][68];
  __shared__ float VL[64][20];
  __shared__ float Tl[16][204];
  for (int e = tid; e < 1024; e += 256) {
    const int t = e >> 4, k4 = (e & 15) * 4;
    *(float4*)&krL[t][k4] = *(const float4*)&kr[(n0 + t) * K + k4];
    *(float4*)&kiL[t][k4] = *(const float4*)&ki[(n0 + t) * K + k4];
  }
  {
    const int t = tid >> 2, f = (tid & 3) * 4;
    *(float4*)&VL[t][f] = *(const float4*)&V[(n0 + t) * D + dc * 16 + f];
  }
  __syncthreads();

  {
    const int t0 = (tid >> 4) * 4;
#pragma unroll
    for (int i = 0; i < 4; ++i) Tl[dl][128 + t0 + i] = VL[t0 + i][dl];
  }

  float ar[4] = {0.f, 0.f, 0.f, 0.f}, ai[4] = {0.f, 0.f, 0.f, 0.f};
#pragma unroll 4
  for (int t = 0; t < 64; ++t) {
    const float vt = VL[t][dl];
    const float4 k4r = *(const float4*)&krL[t][kb * 4];
    const float4 k4i = *(const float4*)&kiL[t][kb * 4];
    ar[0] += k4r.x * vt; ar[1] += k4r.y * vt; ar[2] += k4r.z * vt; ar[3] += k4r.w * vt;
    ai[0] += k4i.x * vt; ai[1] += k4i.y * vt; ai[2] += k4i.z * vt; ai[3] += k4i.w * vt;
  }

#pragma unroll
  for (int i = 0; i < 4; ++i) {
    Tl[dl][kb * 4 + i] = ar[i];
    Tl[dl][64 + kb * 4 + i] = ai[i];
  }
  __syncthreads();

  float* dst = &TMt[(((size_t)(b * 16 + c)) * 256 + dc * 16) * 192];
#pragma unroll
  for (int p = 0; p < 3; ++p) {
    const int e = p * 256 + tid;
    const int row = e / 48, f4 = e % 48;
    *(float4*)&dst[(size_t)row * 192 + f4 * 4] = *(const float4*)&Tl[row][f4 * 4];
  }
}

// ---------------------------------------------------------------------------
// K4: ret slice via MFMA, prefix folded in. 512 blocks (dc16) x 256 threads,
// 77 KB LDS -> 2 blocks/CU. S stored bf16-hi only; K region reused for B.
__global__ __launch_bounds__(256) void ret_kernel(
    const float* __restrict__ qr, const float* __restrict__ qi,
    const float* __restrict__ kr, const float* __restrict__ ki,
    const float* __restrict__ TMt, float* __restrict__ ret,
    float* __restrict__ LNred) {
  __shared__ __align__(16) ushort Qh[64][136], Ql[64][136];
  __shared__ __align__(16) ushort Sh[64][72];
  __shared__ __align__(16) char KB[34816];
  ushort* Kh = (ushort*)KB;
  ushort* Kl = Kh + 64 * 136;
  ushort* Bh = (ushort*)KB;
  ushort* Bl = Bh + 16 * 200;

  const int tid = threadIdx.x;
  const int dc = blockIdx.x & 15;
  const int c = (blockIdx.x >> 4) & 15;
  const int b = blockIdx.x >> 8;
  const int n0 = b * L + c * 64;
  const int cols0 = dc * 16;
  const int w = tid >> 6, lane = tid & 63;
  const int m16 = lane & 15, quad = lane >> 4;

  // Phase 0: stage Q, K (hi/lo)
#pragma unroll
  for (int j = 0; j < 8; ++j) {
    const int e = j * 256 + tid;
    const int row = e >> 5, c4 = e & 31;
    const int col0 = (c4 & 15) * 4;
    const int acol = (c4 < 16 ? 0 : 64) + col0;
    {
      const float* src = (c4 < 16) ? qr : qi;
      const float4 v = *(const float4*)&src[(n0 + row) * K + col0];
      ushort4 h4, l4;
      h4.x = bf16_hi(v.x); l4.x = bf16_rne(v.x - hi_f(v.x));
      h4.y = bf16_hi(v.y); l4.y = bf16_rne(v.y - hi_f(v.y));
      h4.z = bf16_hi(v.z); l4.z = bf16_rne(v.z - hi_f(v.z));
      h4.w = bf16_hi(v.w); l4.w = bf16_rne(v.w - hi_f(v.w));
      *(ushort4*)&Qh[row][acol] = h4;
      *(ushort4*)&Ql[row][acol] = l4;
    }
    {
      const float* src = (c4 < 16) ? kr : ki;
      const float4 v = *(const float4*)&src[(n0 + row) * K + col0];
      ushort4 h4, l4;
      h4.x = bf16_hi(v.x); l4.x = bf16_rne(v.x - hi_f(v.x));
      h4.y = bf16_hi(v.y); l4.y = bf16_rne(v.y - hi_f(v.y));
      h4.z = bf16_hi(v.z); l4.z = bf16_rne(v.z - hi_f(v.z));
      h4.w = bf16_hi(v.w); l4.w = bf16_rne(v.w - hi_f(v.w));
      *(ushort4*)&Kh[row * 136 + acol] = h4;
      *(ushort4*)&Kl[row * 136 + acol] = l4;
    }
  }

  // Prefix accumulation (registers)
  float4 mac0 = {}, mac1 = {};
  {
    const int prow = tid >> 4, in0 = (tid & 15) * 8;
    const float* base = &TMt[(size_t)(b * 16) * 49152 +
                             (size_t)(cols0 + prow) * 192 + in0];
    for (int cp = 0; cp < c; ++cp) {
      const float* p = base + (size_t)cp * 49152;
      const float4 v0 = *(const float4*)p;
      const float4 v1 = *(const float4*)(p + 4);
      mac0.x += v0.x; mac0.y += v0.y; mac0.z += v0.z; mac0.w += v0.w;
      mac1.x += v1.x; mac1.y += v1.y; mac1.z += v1.z; mac1.w += v1.w;
    }
  }
  __syncthreads();

  // Phase 1: S = Q.K^T, causal
  {
    float4v sc[4] = {};
#pragma unroll
    for (int kk = 0; kk < 128; kk += 32) {
      const short8 ah = *(const short8*)&Qh[w * 16 + m16][kk + quad * 8];
      const short8 al = *(const short8*)&Ql[w * 16 + m16][kk + quad * 8];
#pragma unroll
      for (int ct = 0; ct < 4; ++ct) {
        const short8 bh = *(const short8*)&Kh[(ct * 16 + m16) * 136 + kk + quad * 8];
        const short8 bl = *(const short8*)&Kl[(ct * 16 + m16) * 136 + kk + quad * 8];
        sc[ct] = __builtin_amdgcn_mfma_f32_16x16x32_bf16(ah, bh, sc[ct], 0, 0, 0);
        sc[ct] = __builtin_amdgcn_mfma_f32_16x16x32_bf16(ah, bl, sc[ct], 0, 0, 0);
        sc[ct] = __builtin_amdgcn_mfma_f32_16x16x32_bf16(al, bh, sc[ct], 0, 0, 0);
      }
    }
#pragma unroll
    for (int ct = 0; ct < 4; ++ct)
#pragma unroll
      for (int j = 0; j < 4; ++j) {
        const int row = w * 16 + quad * 4 + j;
        const int t = ct * 16 + m16;
        Sh[row][t] = (t <= row) ? bf16_hi(sc[ct][j]) : (ushort)0;
      }
  }
  __syncthreads();

  // Phase 2: stage B = [M_c | Vt_c] hi/lo into KB region
  {
    const int prow = tid >> 4, in0 = (tid & 15) * 8;
    ushort4 h4, l4;
    h4.x = bf16_hi(mac0.x); l4.x = bf16_rne(mac0.x - hi_f(mac0.x));
    h4.y = bf16_hi(mac0.y); l4.y = bf16_rne(mac0.y - hi_f(mac0.y));
    h4.z = bf16_hi(mac0.z); l4.z = bf16_rne(mac0.z - hi_f(mac0.z));
    h4.w = bf16_hi(mac0.w); l4.w = bf16_rne(mac0.w - hi_f(mac0.w));
    *(ushort4*)&Bh[prow * 200 + in0] = h4;
    *(ushort4*)&Bl[prow * 200 + in0] = l4;
    h4.x = bf16_hi(mac1.x); l4.x = bf16_rne(mac1.x - hi_f(mac1.x));
    h4.y = bf16_hi(mac1.y); l4.y = bf16_rne(mac1.y - hi_f(mac1.y));
    h4.z = bf16_hi(mac1.z); l4.z = bf16_rne(mac1.z - hi_f(mac1.z));
    h4.w = bf16_hi(mac1.w); l4.w = bf16_rne(mac1.w - hi_f(mac1.w));
    *(ushort4*)&Bh[prow * 200 + in0 + 4] = h4;
    *(ushort4*)&Bl[prow * 200 + in0 + 4] = l4;

    const int vrow = tid >> 4, vin = 128 + (tid & 15) * 4;
    const float4 v = *(const float4*)&TMt[(size_t)(b * 16 + c) * 49152 +
                                          (size_t)(cols0 + vrow) * 192 + vin];
    ushort4 vh, vl;
    vh.x = bf16_hi(v.x); vl.x = bf16_rne(v.x - hi_f(v.x));
    vh.y = bf16_hi(v.y); vl.y = bf16_rne(v.y - hi_f(v.y));
    vh.z = bf16_hi(v.z); vl.z = bf16_rne(v.z - hi_f(v.z));
    vh.w = bf16_hi(v.w); vl.w = bf16_rne(v.w - hi_f(v.w));
    *(ushort4*)&Bh[vrow * 200 + vin] = vh;
    *(ushort4*)&Bl[vrow * 200 + vin] = vl;
  }
  __syncthreads();

  // Phase 3: ret slice = [Q|S].[M;Vt]
  {
    float4v r2 = {};
#pragma unroll
    for (int kk = 0; kk < 4; ++kk) {
      const short8 ah = *(const short8*)&Qh[w * 16 + m16][kk * 32 + quad * 8];
      const short8 al = *(const short8*)&Ql[w * 16 + m16][kk * 32 + quad * 8];
      const short8 bh = *(const short8*)&Bh[m16 * 200 + kk * 32 + quad * 8];
      const short8 bl = *(const short8*)&Bl[m16 * 200 + kk * 32 + quad * 8];
      r2 = __builtin_amdgcn_mfma_f32_16x16x32_bf16(ah, bh, r2, 0, 0, 0);
      r2 = __builtin_amdgcn_mfma_f32_16x16x32_bf16(ah, bl, r2, 0, 0, 0);
      r2 = __builtin_amdgcn_mfma_f32_16x16x32_bf16(al, bh, r2, 0, 0, 0);
    }
#pragma unroll
    for (int s2 = 0; s2 < 2; ++s2) {
      const short8 ah = *(const short8*)&Sh[w * 16 + m16][s2 * 32 + quad * 8];
      const short8 bh = *(const short8*)&Bh[m16 * 200 + 128 + s2 * 32 + quad * 8];
      const short8 bl = *(const short8*)&Bl[m16 * 200 + 128 + s2 * 32 + quad * 8];
      r2 = __builtin_amdgcn_mfma_f32_16x16x32_bf16(ah, bh, r2, 0, 0, 0);
      r2 = __builtin_amdgcn_mfma_f32_16x16x32_bf16(ah, bl, r2, 0, 0, 0);
    }
#pragma unroll
    for (int j = 0; j < 4; ++j) {
      const int rowL = w * 16 + quad * 4 + j;
      const float nrm = rsqrtf((float)(c * 64 + rowL + 1) * 64.0f);
      const float v = r2[j] * nrm;
      ret[(size_t)(n0 + rowL) * D + cols0 + m16] = v;
      float sj = v, s2j = v * v;
      for (int off = 1; off < 16; off <<= 1) {
        sj += __shfl_xor(sj, off, 64);
        s2j += __shfl_xor(s2j, off, 64);
      }
      if (m16 == 0) {
        LNred[(size_t)(n0 + rowL) * 32 + dc * 2 + 0] = sj;
        LNred[(size_t)(n0 + rowL) * 32 + dc * 2 + 1] = s2j;
      }
    }
  }
}

// ---------------------------------------------------------------------------
// K5: out = x + LN(ret).wo + bo via MFMA bf16x3. 512 blocks x 256 threads.
__global__ __launch_bounds__(256) void out2_kernel(
    const float* __restrict__ ret, const float* __restrict__ LNred,
    const float* __restrict__ x, const float* __restrict__ ln_g,
    const float* __restrict__ ln_b, const ushort* __restrict__ WT,
    const float* __restrict__ bo, float* __restrict__ out) {
  __shared__ __align__(16) ushort Ah[32][40], Al[32][40];
  __shared__ __align__(16) ushort Bh[32][40], Bl[32][40];
  __shared__ float mu_s[32], rs_s[32];
  const int tid = threadIdx.x;
  const int row0 = (blockIdx.x >> 3) * 32, nb = (blockIdx.x & 7) * 32;
  const ushort* Wh = WT + 3 * 131072;
  const ushort* Wl = Wh + 65536;
  const int w = tid >> 6, lane = tid & 63;
  const int m16 = lane & 15, quad = lane >> 4;
  const int rt = w & 1, cq = w >> 1;

  if (tid < 32) {
    const int row = row0 + tid;
    float s = 0.f, s2 = 0.f;
#pragma unroll
    for (int i = 0; i < 16; ++i) {
      s += LNred[(size_t)row * 32 + i * 2 + 0];
      s2 += LNred[(size_t)row * 32 + i * 2 + 1];
    }
    const float mu = s * (1.0f / 256.0f);
    mu_s[tid] = mu;
    rs_s[tid] = rsqrtf(s2 * (1.0f / 256.0f) - mu * mu + 1e-5f);
  }

  float4v acc = {};
  for (int k0 = 0; k0 < 256; k0 += 32) {
    __syncthreads();
    {
      const int r = tid >> 3, kc = (tid & 7) * 4;
      const float4 v = *(const float4*)&ret[(size_t)(row0 + r) * D + k0 + kc];
      const float4 g4 = *(const float4*)&ln_g[k0 + kc];
      const float4 b4 = *(const float4*)&ln_b[k0 + kc];
      const float mu = mu_s[r], rs = rs_s[r];
      float a0 = (v.x - mu) * rs * g4.x + b4.x;
      float a1 = (v.y - mu) * rs * g4.y + b4.y;
      float a2 = (v.z - mu) * rs * g4.z + b4.z;
      float a3 = (v.w - mu) * rs * g4.w + b4.w;
      ushort4 h4, l4;
      h4.x = bf16_hi(a0); l4.x = bf16_rne(a0 - hi_f(a0));
      h4.y = bf16_hi(a1); l4.y = bf16_rne(a1 - hi_f(a1));
      h4.z = bf16_hi(a2); l4.z = bf16_rne(a2 - hi_f(a2));
      h4.w = bf16_hi(a3); l4.w = bf16_rne(a3 - hi_f(a3));
      *(ushort4*)&Ah[r][kc] = h4;
      *(ushort4*)&Al[r][kc] = l4;
    }
    {
      const int plane = tid >> 7;
      const int idx = tid & 127;
      const int n = idx >> 2, chunk = idx & 3;
      const int ga = (nb + n) * 256 + k0 + chunk * 8;
      if (plane == 0) *(uint4*)&Bh[n][chunk * 8] = *(const uint4*)&Wh[ga];
      else            *(uint4*)&Bl[n][chunk * 8] = *(const uint4*)&Wl[ga];
    }
    __syncthreads();

    const short8 afh = *(const short8*)&Ah[rt * 16 + m16][quad * 8];
    const short8 afl = *(const short8*)&Al[rt * 16 + m16][quad * 8];
    const int col = cq * 16 + m16;
    const short8 bfh = *(const short8*)&Bh[col][quad * 8];
    const short8 bfl = *(const short8*)&Bl[col][quad * 8];
    acc = __builtin_amdgcn_mfma_f32_16x16x32_bf16(afh, bfh, acc, 0, 0, 0);
    acc = __builtin_amdgcn_mfma_f32_16x16x32_bf16(afh, bfl, acc, 0, 0, 0);
    acc = __builtin_amdgcn_mfma_f32_16x16x32_bf16(afl, bfh, acc, 0, 0, 0);
  }

  const int colg = nb + cq * 16 + m16;
  const float bias = bo[colg];
#pragma unroll
  for (int j = 0; j < 4; ++j) {
    const int rowg = row0 + rt * 16 + quad * 4 + j;
    out[rowg * D + colg] = x[rowg * D + colg] + acc[j] + bias;
  }
}

// ---------------------------------------------------------------------------
extern "C" void kernel_launch(void* const* d_in, const int* in_sizes, int n_in,
                              void* d_out, int out_size, void* d_ws, size_t ws_size,
                              hipStream_t stream) {
  (void)in_sizes; (void)n_in; (void)out_size; (void)ws_size;
  const float* x    = (const float*)d_in[0];
  const float* pos_k= (const float*)d_in[1];
  const float* w1_k = (const float*)d_in[2];
  const float* b1_k = (const float*)d_in[3];
  const float* w2_k = (const float*)d_in[4];
  const float* b2_k = (const float*)d_in[5];
  const float* wa_k = (const float*)d_in[6];
  const float* ba_k = (const float*)d_in[7];
  const float* pos_q= (const float*)d_in[8];
  const float* w1_q = (const float*)d_in[9];
  const float* b1_q = (const float*)d_in[10];
  const float* w2_q = (const float*)d_in[11];
  const float* b2_q = (const float*)d_in[12];
  const float* wa_q = (const float*)d_in[13];
  const float* ba_q = (const float*)d_in[14];
  const float* wv   = (const float*)d_in[15];
  const float* bv   = (const float*)d_in[16];
  const float* ln_g = (const float*)d_in[17];
  const float* ln_b = (const float*)d_in[18];
  const float* wo   = (const float*)d_in[19];
  const float* bo   = (const float*)d_in[20];

  float* ws = (float*)d_ws;
  float* kr = ws;                          // N*K
  float* ki = kr + (size_t)N * K;
  float* qr = ki + (size_t)N * K;
  float* qi = qr + (size_t)N * K;
  float* V  = qi + (size_t)N * K;          // N*D
  float* TMt = V + (size_t)N * D;          // B*NC*256*192
  float* ret = TMt + (size_t)B * NC * 256 * 192;  // N*D
  float* LNred = ret + (size_t)N * D;      // N*32
  float* hk = LNred + (size_t)N * 32;      // N*D
  float* hq = hk + (size_t)N * D;          // N*D
  ushort* WT = (ushort*)(hq + (size_t)N * D);   // 655360 ushorts

  prep_kernel<<<80, 256, 0, stream>>>(w1_k, w1_q, wv, wo,
                                      w2_k, wa_k, w2_q, wa_q, WT);
  enc1_kernel<<<768, 256, 0, stream>>>(x, pos_k, pos_q, b1_k, b1_q, bv, WT,
                                       hk, hq, V);
  enc2_kernel<<<512, 256, 0, stream>>>(x, pos_k, pos_q, hk, hq,
                                       b2_k, ba_k, b2_q, ba_q, WT,
                                       kr, ki, qr, qi);
  tbuild_kernel<<<B * NC * 16, 256, 0, stream>>>(kr, ki, V, TMt);
  ret_kernel<<<B * NC * 16, 256, 0, stream>>>(qr, qi, kr, ki, TMt, ret, LNred);
  out2_kernel<<<512, 256, 0, stream>>>(ret, LNred, x, ln_g, ln_b, WT, bo,
                                       (float*)d_out);
}

// Round 18
// 142.915 us; speedup vs baseline: 1.2135x; 1.0136x over previous
//
#include <hip/hip_runtime.h>
#include <hip/hip_bf16.h>

typedef __attribute__((ext_vector_type(8))) short short8;
typedef __attribute__((ext_vector_type(4))) float float4v;

constexpr int B = 2, L = 1024, D = 256, K = 64;
constexpr int N = B * L;          // 2048 rows
constexpr int NC = L / 64;        // 16 chunks of 64 tokens

// WT arena (ushort units):
// big mats m in {w1_k, w1_q, wv, wo}: hi at m*131072, lo at +65536
// layer2 mats m in {w2_k, wa_k, w2_q, wa_q}: hi at WT2_OFF + m*32768, lo +16384
constexpr int WT2_OFF = 524288;

__device__ __forceinline__ ushort bf16_hi(float v) {
  return (ushort)(__float_as_uint(v) >> 16);
}
__device__ __forceinline__ float hi_f(float v) {
  return __uint_as_float(__float_as_uint(v) & 0xFFFF0000u);
}
__device__ __forceinline__ ushort bf16_rne(float v) {
  uint b = __float_as_uint(v);
  b += 0x7FFF + ((b >> 16) & 1);
  return (ushort)(b >> 16);
}

// ---------------------------------------------------------------------------
// K0: transpose + hi/lo split weights into WT arena (vector writes only).
__global__ __launch_bounds__(256) void prep_kernel(
    const float* __restrict__ w1_k, const float* __restrict__ w1_q,
    const float* __restrict__ wv, const float* __restrict__ wo,
    const float* __restrict__ w2_k, const float* __restrict__ wa_k,
    const float* __restrict__ w2_q, const float* __restrict__ wa_q,
    ushort* __restrict__ WT) {
  __shared__ float Lt[64][65];
  const int bi = blockIdx.x, tid = threadIdx.x;
  const float* src;
  int ncols, k0, n0;
  ushort* dhi;
  int losz;
  if (bi < 64) {
    const int m = bi >> 4, t = bi & 15;
    src = (m == 0) ? w1_k : (m == 1) ? w1_q : (m == 2) ? wv : wo;
    ncols = 256; k0 = (t >> 2) * 64; n0 = (t & 3) * 64;
    dhi = WT + m * 131072; losz = 65536;
  } else {
    const int m = (bi - 64) >> 2, kt = (bi - 64) & 3;
    src = (m == 0) ? w2_k : (m == 1) ? wa_k : (m == 2) ? w2_q : wa_q;
    ncols = 64; k0 = kt * 64; n0 = 0;
    dhi = WT + WT2_OFF + m * 32768; losz = 16384;
  }
  ushort* dlo = dhi + losz;
  for (int p = 0; p < 16; ++p) {
    const int kr = p * 4 + (tid >> 6), nc = tid & 63;
    Lt[kr][nc] = src[(k0 + kr) * ncols + n0 + nc];
  }
  __syncthreads();
  const int n = tid >> 2, kq = tid & 3;
  uint uh[8], ul[8];
  for (int i = 0; i < 8; ++i) {
    const float v0 = Lt[kq * 16 + 2 * i][n];
    const float v1 = Lt[kq * 16 + 2 * i + 1][n];
    uh[i] = (uint)bf16_hi(v0) | ((uint)bf16_hi(v1) << 16);
    ul[i] = (uint)bf16_rne(v0 - hi_f(v0)) | ((uint)bf16_rne(v1 - hi_f(v1)) << 16);
  }
  const int oidx = (n0 + n) * 256 + k0 + kq * 16;
  *(uint4*)&dhi[oidx] = make_uint4(uh[0], uh[1], uh[2], uh[3]);
  *(uint4*)&dhi[oidx + 8] = make_uint4(uh[4], uh[5], uh[6], uh[7]);
  *(uint4*)&dlo[oidx] = make_uint4(ul[0], ul[1], ul[2], ul[3]);
  *(uint4*)&dlo[oidx + 8] = make_uint4(ul[4], ul[5], ul[6], ul[7]);
}

// ---------------------------------------------------------------------------
// K1: layer-1 as 3 GEMMs via MFMA bf16x3. 32x64 tiles, 768 blocks (3/CU).
// Register prefetch of next k-tile overlapped with MFMA phase.
__global__ __launch_bounds__(256) void enc1_kernel(
    const float* __restrict__ x, const float* __restrict__ pos_k,
    const float* __restrict__ pos_q,
    const float* __restrict__ b1_k, const float* __restrict__ b1_q,
    const float* __restrict__ bv, const ushort* __restrict__ WT,
    float* __restrict__ hk, float* __restrict__ hq, float* __restrict__ V) {
  __shared__ __align__(16) ushort Ah[32][40], Al[32][40];
  __shared__ __align__(16) ushort Bh[64][40], Bl[64][40];
  const int tid = threadIdx.x;
  const int g = blockIdx.x / 256;
  const int rem = blockIdx.x % 256;
  const int row0 = (rem >> 2) * 32, nb = (rem & 3) * 64;
  const float* pos = (g == 0) ? pos_k : (g == 1) ? pos_q : nullptr;
  const ushort* Wh = WT + g * 131072;
  const ushort* Wl = Wh + 65536;
  const int w = tid >> 6, lane = tid & 63;
  const int m16 = lane & 15, quad = lane >> 4;

  // staging-role constants
  const int sr = tid >> 3, skc = (tid & 7) * 4;
  const int srow = row0 + sr, sl = srow & (L - 1);
  const int sn = tid >> 2, schunk = tid & 3;

  float4 pxv;
  uint4 pbh, pbl;
  auto loadTile = [&](int k0) {
    float4 xv = *(const float4*)&x[srow * D + k0 + skc];
    if (pos) {
      const float4 pv = *(const float4*)&pos[sl * D + k0 + skc];
      xv.x += pv.x; xv.y += pv.y; xv.z += pv.z; xv.w += pv.w;
    }
    pxv = xv;
    const int ga = (nb + sn) * 256 + k0 + schunk * 8;
    pbh = *(const uint4*)&Wh[ga];
    pbl = *(const uint4*)&Wl[ga];
  };

  float4v acc[2] = {};
  loadTile(0);

  for (int k0 = 0; k0 < 256; k0 += 32) {
    __syncthreads();
    {  // store prefetched tile to LDS
      ushort4 h4, l4;
      h4.x = bf16_hi(pxv.x); l4.x = bf16_rne(pxv.x - hi_f(pxv.x));
      h4.y = bf16_hi(pxv.y); l4.y = bf16_rne(pxv.y - hi_f(pxv.y));
      h4.z = bf16_hi(pxv.z); l4.z = bf16_rne(pxv.z - hi_f(pxv.z));
      h4.w = bf16_hi(pxv.w); l4.w = bf16_rne(pxv.w - hi_f(pxv.w));
      *(ushort4*)&Ah[sr][skc] = h4;
      *(ushort4*)&Al[sr][skc] = l4;
      *(uint4*)&Bh[sn][schunk * 8] = pbh;
      *(uint4*)&Bl[sn][schunk * 8] = pbl;
    }
    __syncthreads();
    if (k0 + 32 < 256) loadTile(k0 + 32);   // overlapped with MFMA below

    short8 afh[2], afl[2];
#pragma unroll
    for (int r = 0; r < 2; ++r) {
      afh[r] = *(const short8*)&Ah[r * 16 + m16][quad * 8];
      afl[r] = *(const short8*)&Al[r * 16 + m16][quad * 8];
    }
    const int col = w * 16 + m16;
    const short8 bfh = *(const short8*)&Bh[col][quad * 8];
    const short8 bfl = *(const short8*)&Bl[col][quad * 8];
#pragma unroll
    for (int r = 0; r < 2; ++r) {
      acc[r] = __builtin_amdgcn_mfma_f32_16x16x32_bf16(afh[r], bfh, acc[r], 0, 0, 0);
      acc[r] = __builtin_amdgcn_mfma_f32_16x16x32_bf16(afh[r], bfl, acc[r], 0, 0, 0);
      acc[r] = __builtin_amdgcn_mfma_f32_16x16x32_bf16(afl[r], bfh, acc[r], 0, 0, 0);
    }
  }

  float* outp = (g == 0) ? hk : (g == 1) ? hq : V;
  const float* bp = (g == 0) ? b1_k : (g == 1) ? b1_q : bv;
  const int colg = nb + w * 16 + m16;
  const float bias = bp[colg];
#pragma unroll
  for (int r = 0; r < 2; ++r)
#pragma unroll
    for (int j = 0; j < 4; ++j) {
      const int rowg = row0 + r * 16 + quad * 4 + j;
      float v = acc[r][j] + bias;
      if (g < 2) v = 0.5f * v * (1.0f + erff(v * 0.70710678f));
      outp[rowg * D + colg] = v;
    }
}

// ---------------------------------------------------------------------------
// K2: layer-2 (phase & amp GEMMs) + phasor epilogue.
// 512 blocks x 256 threads; register prefetch in the k-loop.
__global__ __launch_bounds__(256) void enc2_kernel(
    const float* __restrict__ x, const float* __restrict__ pos_k,
    const float* __restrict__ pos_q, const float* __restrict__ hk,
    const float* __restrict__ hq,
    const float* __restrict__ b2_k, const float* __restrict__ ba_k,
    const float* __restrict__ b2_q, const float* __restrict__ ba_q,
    const ushort* __restrict__ WT,
    float* __restrict__ kr, float* __restrict__ ki,
    float* __restrict__ qr, float* __restrict__ qi) {
  __shared__ __align__(16) ushort Ahh[16][40], Ahl[16][40], Axh[16][40], Axl[16][40];
  __shared__ __align__(16) ushort B2h[32][40], B2l[32][40], Bah[32][40], Bal[32][40];
  __shared__ float phL[16][36], amL[16][36];
  const int tid = threadIdx.x;
  const int e = blockIdx.x >> 8;
  const int rem = blockIdx.x & 255;
  const int r0g = (rem >> 1) * 16;
  const int colbase = (rem & 1) * 32;
  const float* hsrc = e ? hq : hk;
  const float* pos = e ? pos_q : pos_k;
  const ushort* W2h = WT + WT2_OFF + (e ? 2 : 0) * 32768;
  const ushort* W2l = W2h + 16384;
  const ushort* Wah = WT + WT2_OFF + (e ? 3 : 1) * 32768;
  const ushort* Wal = Wah + 16384;
  const int w = tid >> 6, lane = tid & 63;
  const int m16 = lane & 15, quad = lane >> 4;
  const int mat = w & 1, ct = w >> 1;

  // staging-role constants
  const int ahalf = tid >> 7;
  const int at = tid & 127;
  const int ar_ = at >> 3, akc = (at & 7) * 4;
  const int arow = r0g + ar_, al_ = arow & (L - 1);
  const int bsel = tid >> 6;
  const int bidx = tid & 63;
  const int bn = bidx >> 1, bch = (bidx & 1) * 2;
  const ushort* bs = (bsel == 0) ? W2h : (bsel == 1) ? W2l : (bsel == 2) ? Wah : Wal;
  ushort* bdst = (bsel == 0) ? &B2h[bn][bch * 8] : (bsel == 1) ? &B2l[bn][bch * 8]
               : (bsel == 2) ? &Bah[bn][bch * 8] : &Bal[bn][bch * 8];

  float4 pav;
  uint4 pb0, pb1;
  auto loadTile = [&](int k0) {
    if (ahalf == 0) {
      pav = *(const float4*)&hsrc[arow * D + k0 + akc];
    } else {
      const float4 xv = *(const float4*)&x[arow * D + k0 + akc];
      const float4 pv = *(const float4*)&pos[al_ * D + k0 + akc];
      pav.x = xv.x + pv.x; pav.y = xv.y + pv.y;
      pav.z = xv.z + pv.z; pav.w = xv.w + pv.w;
    }
    const int ga = (colbase + bn) * 256 + k0 + bch * 8;
    pb0 = *(const uint4*)&bs[ga];
    pb1 = *(const uint4*)&bs[ga + 8];
  };

  float4v acc = {};
  loadTile(0);

  for (int k0 = 0; k0 < 256; k0 += 32) {
    __syncthreads();
    {  // store prefetched tile
      ushort4 h4, l4;
      h4.x = bf16_hi(pav.x); l4.x = bf16_rne(pav.x - hi_f(pav.x));
      h4.y = bf16_hi(pav.y); l4.y = bf16_rne(pav.y - hi_f(pav.y));
      h4.z = bf16_hi(pav.z); l4.z = bf16_rne(pav.z - hi_f(pav.z));
      h4.w = bf16_hi(pav.w); l4.w = bf16_rne(pav.w - hi_f(pav.w));
      if (ahalf == 0) {
        *(ushort4*)&Ahh[ar_][akc] = h4;
        *(ushort4*)&Ahl[ar_][akc] = l4;
      } else {
        *(ushort4*)&Axh[ar_][akc] = h4;
        *(ushort4*)&Axl[ar_][akc] = l4;
      }
      *(uint4*)bdst = pb0;
      *(uint4*)(bdst + 8) = pb1;
    }
    __syncthreads();
    if (k0 + 32 < 256) loadTile(k0 + 32);

    const short8 ah = mat ? *(const short8*)&Axh[m16][quad * 8]
                          : *(const short8*)&Ahh[m16][quad * 8];
    const short8 al = mat ? *(const short8*)&Axl[m16][quad * 8]
                          : *(const short8*)&Ahl[m16][quad * 8];
    const int col = ct * 16 + m16;
    const short8 bh = mat ? *(const short8*)&Bah[col][quad * 8]
                          : *(const short8*)&B2h[col][quad * 8];
    const short8 bl = mat ? *(const short8*)&Bal[col][quad * 8]
                          : *(const short8*)&B2l[col][quad * 8];
    acc = __builtin_amdgcn_mfma_f32_16x16x32_bf16(ah, bh, acc, 0, 0, 0);
    acc = __builtin_amdgcn_mfma_f32_16x16x32_bf16(ah, bl, acc, 0, 0, 0);
    acc = __builtin_amdgcn_mfma_f32_16x16x32_bf16(al, bh, acc, 0, 0, 0);
  }

  {
    const int lcol = ct * 16 + m16;
    const int colk = colbase + lcol;
    if (mat == 0) {
      const float b2v = (e ? b2_q : b2_k)[colk];
#pragma unroll
      for (int j = 0; j < 4; ++j)
        phL[quad * 4 + j][lcol] = tanhf(acc[j] + b2v) * 3.14159265358979f;
    } else {
      const float bav = (e ? ba_q : ba_k)[colk];
#pragma unroll
      for (int j = 0; j < 4; ++j) {
        const float av = acc[j] + bav;
        amL[quad * 4 + j][lcol] = fmaxf(av, 0.0f) + log1pf(expf(-fabsf(av))) + 0.1f;
      }
    }
  }
  __syncthreads();
  {
    float* pr = e ? qr : kr;
    float* pim = e ? qi : ki;
#pragma unroll
    for (int p = 0; p < 2; ++p) {
      const int idx = p * 256 + tid;
      const int r = idx >> 5, lcol = idx & 31;
      const int row = r0g + r;
      const float a = amL[r][lcol], pph = phL[r][lcol];
      pr[row * K + colbase + lcol] = a * cosf(pph);
      pim[row * K + colbase + lcol] = a * sinf(pph);
    }
  }
}

// ---------------------------------------------------------------------------
// K3: per-chunk T + V^T into TMt[b][c][d][192] = [T_re(64)|T_im(64)|Vt(64)].
__global__ __launch_bounds__(256) void tbuild_kernel(
    const float* __restrict__ kr, const float* __restrict__ ki,
    const float* __restrict__ V, float* __restrict__ TMt) {
  const int id = blockIdx.x;
  const int dc = id & 15, c = (id >> 4) & 15, b = id >> 8;
  const int tid = threadIdx.x;
  const int n0 = b * L + c * 64;
  const int dl = tid & 15;
  const int kb = tid >> 4;

  __shared__ float krL[64][68], kiL[64][68];
  __shared__ float VL[64][20];
  __shared__ float Tl[16][204];
  for (int e = tid; e < 1024; e += 256) {
    const int t = e >> 4, k4 = (e & 15) * 4;
    *(float4*)&krL[t][k4] = *(const float4*)&kr[(n0 + t) * K + k4];
    *(float4*)&kiL[t][k4] = *(const float4*)&ki[(n0 + t) * K + k4];
  }
  {
    const int t = tid >> 2, f = (tid & 3) * 4;
    *(float4*)&VL[t][f] = *(const float4*)&V[(n0 + t) * D + dc * 16 + f];
  }
  __syncthreads();

  {
    const int t0 = (tid >> 4) * 4;
#pragma unroll
    for (int i = 0; i < 4; ++i) Tl[dl][128 + t0 + i] = VL[t0 + i][dl];
  }

  float ar[4] = {0.f, 0.f, 0.f, 0.f}, ai[4] = {0.f, 0.f, 0.f, 0.f};
#pragma unroll 4
  for (int t = 0; t < 64; ++t) {
    const float vt = VL[t][dl];
    const float4 k4r = *(const float4*)&krL[t][kb * 4];
    const float4 k4i = *(const float4*)&kiL[t][kb * 4];
    ar[0] += k4r.x * vt; ar[1] += k4r.y * vt; ar[2] += k4r.z * vt; ar[3] += k4r.w * vt;
    ai[0] += k4i.x * vt; ai[1] += k4i.y * vt; ai[2] += k4i.z * vt; ai[3] += k4i.w * vt;
  }

#pragma unroll
  for (int i = 0; i < 4; ++i) {
    Tl[dl][kb * 4 + i] = ar[i];
    Tl[dl][64 + kb * 4 + i] = ai[i];
  }
  __syncthreads();

  float* dst = &TMt[(((size_t)(b * 16 + c)) * 256 + dc * 16) * 192];
#pragma unroll
  for (int p = 0; p < 3; ++p) {
    const int e = p * 256 + tid;
    const int row = e / 48, f4 = e % 48;
    *(float4*)&dst[(size_t)row * 192 + f4 * 4] = *(const float4*)&Tl[row][f4 * 4];
  }
}

// ---------------------------------------------------------------------------
// K4: ret slice via MFMA, prefix folded in. 512 blocks (dc16) x 256 threads,
// 77 KB LDS -> 2 blocks/CU. S stored bf16-hi only; K region reused for B.
__global__ __launch_bounds__(256) void ret_kernel(
    const float* __restrict__ qr, const float* __restrict__ qi,
    const float* __restrict__ kr, const float* __restrict__ ki,
    const float* __restrict__ TMt, float* __restrict__ ret,
    float* __restrict__ LNred) {
  __shared__ __align__(16) ushort Qh[64][136], Ql[64][136];
  __shared__ __align__(16) ushort Sh[64][72];
  __shared__ __align__(16) char KB[34816];
  ushort* Kh = (ushort*)KB;
  ushort* Kl = Kh + 64 * 136;
  ushort* Bh = (ushort*)KB;
  ushort* Bl = Bh + 16 * 200;

  const int tid = threadIdx.x;
  const int dc = blockIdx.x & 15;
  const int c = (blockIdx.x >> 4) & 15;
  const int b = blockIdx.x >> 8;
  const int n0 = b * L + c * 64;
  const int cols0 = dc * 16;
  const int w = tid >> 6, lane = tid & 63;
  const int m16 = lane & 15, quad = lane >> 4;

  // Phase 0: stage Q, K (hi/lo)
#pragma unroll
  for (int j = 0; j < 8; ++j) {
    const int e = j * 256 + tid;
    const int row = e >> 5, c4 = e & 31;
    const int col0 = (c4 & 15) * 4;
    const int acol = (c4 < 16 ? 0 : 64) + col0;
    {
      const float* src = (c4 < 16) ? qr : qi;
      const float4 v = *(const float4*)&src[(n0 + row) * K + col0];
      ushort4 h4, l4;
      h4.x = bf16_hi(v.x); l4.x = bf16_rne(v.x - hi_f(v.x));
      h4.y = bf16_hi(v.y); l4.y = bf16_rne(v.y - hi_f(v.y));
      h4.z = bf16_hi(v.z); l4.z = bf16_rne(v.z - hi_f(v.z));
      h4.w = bf16_hi(v.w); l4.w = bf16_rne(v.w - hi_f(v.w));
      *(ushort4*)&Qh[row][acol] = h4;
      *(ushort4*)&Ql[row][acol] = l4;
    }
    {
      const float* src = (c4 < 16) ? kr : ki;
      const float4 v = *(const float4*)&src[(n0 + row) * K + col0];
      ushort4 h4, l4;
      h4.x = bf16_hi(v.x); l4.x = bf16_rne(v.x - hi_f(v.x));
      h4.y = bf16_hi(v.y); l4.y = bf16_rne(v.y - hi_f(v.y));
      h4.z = bf16_hi(v.z); l4.z = bf16_rne(v.z - hi_f(v.z));
      h4.w = bf16_hi(v.w); l4.w = bf16_rne(v.w - hi_f(v.w));
      *(ushort4*)&Kh[row * 136 + acol] = h4;
      *(ushort4*)&Kl[row * 136 + acol] = l4;
    }
  }

  // Prefix accumulation (registers)
  float4 mac0 = {}, mac1 = {};
  {
    const int prow = tid >> 4, in0 = (tid & 15) * 8;
    const float* base = &TMt[(size_t)(b * 16) * 49152 +
                             (size_t)(cols0 + prow) * 192 + in0];
    for (int cp = 0; cp < c; ++cp) {
      const float* p = base + (size_t)cp * 49152;
      const float4 v0 = *(const float4*)p;
      const float4 v1 = *(const float4*)(p + 4);
      mac0.x += v0.x; mac0.y += v0.y; mac0.z += v0.z; mac0.w += v0.w;
      mac1.x += v1.x; mac1.y += v1.y; mac1.z += v1.z; mac1.w += v1.w;
    }
  }
  __syncthreads();

  // Phase 1: S = Q.K^T, causal
  {
    float4v sc[4] = {};
#pragma unroll
    for (int kk = 0; kk < 128; kk += 32) {
      const short8 ah = *(const short8*)&Qh[w * 16 + m16][kk + quad * 8];
      const short8 al = *(const short8*)&Ql[w * 16 + m16][kk + quad * 8];
#pragma unroll
      for (int ct = 0; ct < 4; ++ct) {
        const short8 bh = *(const short8*)&Kh[(ct * 16 + m16) * 136 + kk + quad * 8];
        const short8 bl = *(const short8*)&Kl[(ct * 16 + m16) * 136 + kk + quad * 8];
        sc[ct] = __builtin_amdgcn_mfma_f32_16x16x32_bf16(ah, bh, sc[ct], 0, 0, 0);
        sc[ct] = __builtin_amdgcn_mfma_f32_16x16x32_bf16(ah, bl, sc[ct], 0, 0, 0);
        sc[ct] = __builtin_amdgcn_mfma_f32_16x16x32_bf16(al, bh, sc[ct], 0, 0, 0);
      }
    }
#pragma unroll
    for (int ct = 0; ct < 4; ++ct)
#pragma unroll
      for (int j = 0; j < 4; ++j) {
        const int row = w * 16 + quad * 4 + j;
        const int t = ct * 16 + m16;
        Sh[row][t] = (t <= row) ? bf16_hi(sc[ct][j]) : (ushort)0;
      }
  }
  __syncthreads();

  // Phase 2: stage B = [M_c | Vt_c] hi/lo into KB region
  {
    const int prow = tid >> 4, in0 = (tid & 15) * 8;
    ushort4 h4, l4;
    h4.x = bf16_hi(mac0.x); l4.x = bf16_rne(mac0.x - hi_f(mac0.x));
    h4.y = bf16_hi(mac0.y); l4.y = bf16_rne(mac0.y - hi_f(mac0.y));
    h4.z = bf16_hi(mac0.z); l4.z = bf16_rne(mac0.z - hi_f(mac0.z));
    h4.w = bf16_hi(mac0.w); l4.w = bf16_rne(mac0.w - hi_f(mac0.w));
    *(ushort4*)&Bh[prow * 200 + in0] = h4;
    *(ushort4*)&Bl[prow * 200 + in0] = l4;
    h4.x = bf16_hi(mac1.x); l4.x = bf16_rne(mac1.x - hi_f(mac1.x));
    h4.y = bf16_hi(mac1.y); l4.y = bf16_rne(mac1.y - hi_f(mac1.y));
    h4.z = bf16_hi(mac1.z); l4.z = bf16_rne(mac1.z - hi_f(mac1.z));
    h4.w = bf16_hi(mac1.w); l4.w = bf16_rne(mac1.w - hi_f(mac1.w));
    *(ushort4*)&Bh[prow * 200 + in0 + 4] = h4;
    *(ushort4*)&Bl[prow * 200 + in0 + 4] = l4;

    const int vrow = tid >> 4, vin = 128 + (tid & 15) * 4;
    const float4 v = *(const float4*)&TMt[(size_t)(b * 16 + c) * 49152 +
                                          (size_t)(cols0 + vrow) * 192 + vin];
    ushort4 vh, vl;
    vh.x = bf16_hi(v.x); vl.x = bf16_rne(v.x - hi_f(v.x));
    vh.y = bf16_hi(v.y); vl.y = bf16_rne(v.y - hi_f(v.y));
    vh.z = bf16_hi(v.z); vl.z = bf16_rne(v.z - hi_f(v.z));
    vh.w = bf16_hi(v.w); vl.w = bf16_rne(v.w - hi_f(v.w));
    *(ushort4*)&Bh[vrow * 200 + vin] = vh;
    *(ushort4*)&Bl[vrow * 200 + vin] = vl;
  }
  __syncthreads();

  // Phase 3: ret slice = [Q|S].[M;Vt]
  {
    float4v r2 = {};
#pragma unroll
    for (int kk = 0; kk < 4; ++kk) {
      const short8 ah = *(const short8*)&Qh[w * 16 + m16][kk * 32 + quad * 8];
      const short8 al = *(const short8*)&Ql[w * 16 + m16][kk * 32 + quad * 8];
      const short8 bh = *(const short8*)&Bh[m16 * 200 + kk * 32 + quad * 8];
      const short8 bl = *(const short8*)&Bl[m16 * 200 + kk * 32 + quad * 8];
      r2 = __builtin_amdgcn_mfma_f32_16x16x32_bf16(ah, bh, r2, 0, 0, 0);
      r2 = __builtin_amdgcn_mfma_f32_16x16x32_bf16(ah, bl, r2, 0, 0, 0);
      r2 = __builtin_amdgcn_mfma_f32_16x16x32_bf16(al, bh, r2, 0, 0, 0);
    }
#pragma unroll
    for (int s2 = 0; s2 < 2; ++s2) {
      const short8 ah = *(const short8*)&Sh[w * 16 + m16][s2 * 32 + quad * 8];
      const short8 bh = *(const short8*)&Bh[m16 * 200 + 128 + s2 * 32 + quad * 8];
      const short8 bl = *(const short8*)&Bl[m16 * 200 + 128 + s2 * 32 + quad * 8];
      r2 = __builtin_amdgcn_mfma_f32_16x16x32_bf16(ah, bh, r2, 0, 0, 0);
      r2 = __builtin_amdgcn_mfma_f32_16x16x32_bf16(ah, bl, r2, 0, 0, 0);
    }
#pragma unroll
    for (int j = 0; j < 4; ++j) {
      const int rowL = w * 16 + quad * 4 + j;
      const float nrm = rsqrtf((float)(c * 64 + rowL + 1) * 64.0f);
      const float v = r2[j] * nrm;
      ret[(size_t)(n0 + rowL) * D + cols0 + m16] = v;
      float sj = v, s2j = v * v;
      for (int off = 1; off < 16; off <<= 1) {
        sj += __shfl_xor(sj, off, 64);
        s2j += __shfl_xor(s2j, off, 64);
      }
      if (m16 == 0) {
        LNred[(size_t)(n0 + rowL) * 32 + dc * 2 + 0] = sj;
        LNred[(size_t)(n0 + rowL) * 32 + dc * 2 + 1] = s2j;
      }
    }
  }
}

// ---------------------------------------------------------------------------
// K5: out = x + LN(ret).wo + bo via MFMA bf16x3. 512 blocks x 256 threads,
// register prefetch in the k-loop.
__global__ __launch_bounds__(256) void out2_kernel(
    const float* __restrict__ ret, const float* __restrict__ LNred,
    const float* __restrict__ x, const float* __restrict__ ln_g,
    const float* __restrict__ ln_b, const ushort* __restrict__ WT,
    const float* __restrict__ bo, float* __restrict__ out) {
  __shared__ __align__(16) ushort Ah[32][40], Al[32][40];
  __shared__ __align__(16) ushort Bh[32][40], Bl[32][40];
  __shared__ float mu_s[32], rs_s[32];
  const int tid = threadIdx.x;
  const int row0 = (blockIdx.x >> 3) * 32, nb = (blockIdx.x & 7) * 32;
  const ushort* Wh = WT + 3 * 131072;
  const ushort* Wl = Wh + 65536;
  const int w = tid >> 6, lane = tid & 63;
  const int m16 = lane & 15, quad = lane >> 4;
  const int rt = w & 1, cq = w >> 1;

  // staging-role constants
  const int ar_ = tid >> 3, akc = (tid & 7) * 4;
  const int bplane = tid >> 7;
  const int bidx = tid & 127;
  const int bn = bidx >> 2, bchunk = bidx & 3;

  if (tid < 32) {
    const int row = row0 + tid;
    float s = 0.f, s2 = 0.f;
#pragma unroll
    for (int i = 0; i < 16; ++i) {
      s += LNred[(size_t)row * 32 + i * 2 + 0];
      s2 += LNred[(size_t)row * 32 + i * 2 + 1];
    }
    const float mu = s * (1.0f / 256.0f);
    mu_s[tid] = mu;
    rs_s[tid] = rsqrtf(s2 * (1.0f / 256.0f) - mu * mu + 1e-5f);
  }

  float4 prv, pg4, pb4;
  uint4 pbw;
  auto loadTile = [&](int k0) {
    prv = *(const float4*)&ret[(size_t)(row0 + ar_) * D + k0 + akc];
    pg4 = *(const float4*)&ln_g[k0 + akc];
    pb4 = *(const float4*)&ln_b[k0 + akc];
    const int ga = (nb + bn) * 256 + k0 + bchunk * 8;
    pbw = (bplane == 0) ? *(const uint4*)&Wh[ga] : *(const uint4*)&Wl[ga];
  };

  float4v acc = {};
  loadTile(0);

  for (int k0 = 0; k0 < 256; k0 += 32) {
    __syncthreads();
    {  // store prefetched tile (LN folded into A-staging)
      const float mu = mu_s[ar_], rs = rs_s[ar_];
      const float a0 = (prv.x - mu) * rs * pg4.x + pb4.x;
      const float a1 = (prv.y - mu) * rs * pg4.y + pb4.y;
      const float a2 = (prv.z - mu) * rs * pg4.z + pb4.z;
      const float a3 = (prv.w - mu) * rs * pg4.w + pb4.w;
      ushort4 h4, l4;
      h4.x = bf16_hi(a0); l4.x = bf16_rne(a0 - hi_f(a0));
      h4.y = bf16_hi(a1); l4.y = bf16_rne(a1 - hi_f(a1));
      h4.z = bf16_hi(a2); l4.z = bf16_rne(a2 - hi_f(a2));
      h4.w = bf16_hi(a3); l4.w = bf16_rne(a3 - hi_f(a3));
      *(ushort4*)&Ah[ar_][akc] = h4;
      *(ushort4*)&Al[ar_][akc] = l4;
      if (bplane == 0) *(uint4*)&Bh[bn][bchunk * 8] = pbw;
      else             *(uint4*)&Bl[bn][bchunk * 8] = pbw;
    }
    __syncthreads();
    if (k0 + 32 < 256) loadTile(k0 + 32);

    const short8 afh = *(const short8*)&Ah[rt * 16 + m16][quad * 8];
    const short8 afl = *(const short8*)&Al[rt * 16 + m16][quad * 8];
    const int col = cq * 16 + m16;
    const short8 bfh = *(const short8*)&Bh[col][quad * 8];
    const short8 bfl = *(const short8*)&Bl[col][quad * 8];
    acc = __builtin_amdgcn_mfma_f32_16x16x32_bf16(afh, bfh, acc, 0, 0, 0);
    acc = __builtin_amdgcn_mfma_f32_16x16x32_bf16(afh, bfl, acc, 0, 0, 0);
    acc = __builtin_amdgcn_mfma_f32_16x16x32_bf16(afl, bfh, acc, 0, 0, 0);
  }

  const int colg = nb + cq * 16 + m16;
  const float bias = bo[colg];
#pragma unroll
  for (int j = 0; j < 4; ++j) {
    const int rowg = row0 + rt * 16 + quad * 4 + j;
    out[rowg * D + colg] = x[rowg * D + colg] + acc[j] + bias;
  }
}

// ---------------------------------------------------------------------------
extern "C" void kernel_launch(void* const* d_in, const int* in_sizes, int n_in,
                              void* d_out, int out_size, void* d_ws, size_t ws_size,
                              hipStream_t stream) {
  (void)in_sizes; (void)n_in; (void)out_size; (void)ws_size;
  const float* x    = (const float*)d_in[0];
  const float* pos_k= (const float*)d_in[1];
  const float* w1_k = (const float*)d_in[2];
  const float* b1_k = (const float*)d_in[3];
  const float* w2_k = (const float*)d_in[4];
  const float* b2_k = (const float*)d_in[5];
  const float* wa_k = (const float*)d_in[6];
  const float* ba_k = (const float*)d_in[7];
  const float* pos_q= (const float*)d_in[8];
  const float* w1_q = (const float*)d_in[9];
  const float* b1_q = (const float*)d_in[10];
  const float* w2_q = (const float*)d_in[11];
  const float* b2_q = (const float*)d_in[12];
  const float* wa_q = (const float*)d_in[13];
  const float* ba_q = (const float*)d_in[14];
  const float* wv   = (const float*)d_in[15];
  const float* bv   = (const float*)d_in[16];
  const float* ln_g = (const float*)d_in[17];
  const float* ln_b = (const float*)d_in[18];
  const float* wo   = (const float*)d_in[19];
  const float* bo   = (const float*)d_in[20];

  float* ws = (float*)d_ws;
  float* kr = ws;                          // N*K
  float* ki = kr + (size_t)N * K;
  float* qr = ki + (size_t)N * K;
  float* qi = qr + (size_t)N * K;
  float* V  = qi + (size_t)N * K;          // N*D
  float* TMt = V + (size_t)N * D;          // B*NC*256*192
  float* ret = TMt + (size_t)B * NC * 256 * 192;  // N*D
  float* LNred = ret + (size_t)N * D;      // N*32
  float* hk = LNred + (size_t)N * 32;      // N*D
  float* hq = hk + (size_t)N * D;          // N*D
  ushort* WT = (ushort*)(hq + (size_t)N * D);   // 655360 ushorts

  prep_kernel<<<80, 256, 0, stream>>>(w1_k, w1_q, wv, wo,
                                      w2_k, wa_k, w2_q, wa_q, WT);
  enc1_kernel<<<768, 256, 0, stream>>>(x, pos_k, pos_q, b1_k, b1_q, bv, WT,
                                       hk, hq, V);
  enc2_kernel<<<512, 256, 0, stream>>>(x, pos_k, pos_q, hk, hq,
                                       b2_k, ba_k, b2_q, ba_q, WT,
                                       kr, ki, qr, qi);
  tbuild_kernel<<<B * NC * 16, 256, 0, stream>>>(kr, ki, V, TMt);
  ret_kernel<<<B * NC * 16, 256, 0, stream>>>(qr, qi, kr, ki, TMt, ret, LNred);
  out2_kernel<<<512, 256, 0, stream>>>(ret, LNred, x, ln_g, ln_b, WT, bo,
                                       (float*)d_out);
}

// Round 19
// 142.068 us; speedup vs baseline: 1.2207x; 1.0060x over previous
//
#include <hip/hip_runtime.h>
#include <hip/hip_bf16.h>

typedef __attribute__((ext_vector_type(8))) short short8;
typedef __attribute__((ext_vector_type(4))) float float4v;

constexpr int B = 2, L = 1024, D = 256, K = 64;
constexpr int N = B * L;          // 2048 rows
constexpr int NC = L / 64;        // 16 chunks of 64 tokens

// WT arena (ushort units):
// big mats m in {w1_k, w1_q, wv, wo}: hi at m*131072, lo at +65536
// layer2 mats m in {w2_k, wa_k, w2_q, wa_q}: hi at WT2_OFF + m*32768, lo +16384
constexpr int WT2_OFF = 524288;

__device__ __forceinline__ ushort bf16_hi(float v) {
  return (ushort)(__float_as_uint(v) >> 16);
}
__device__ __forceinline__ float hi_f(float v) {
  return __uint_as_float(__float_as_uint(v) & 0xFFFF0000u);
}
__device__ __forceinline__ ushort bf16_rne(float v) {
  uint b = __float_as_uint(v);
  b += 0x7FFF + ((b >> 16) & 1);
  return (ushort)(b >> 16);
}

// ---------------------------------------------------------------------------
// K0: transpose + hi/lo split weights into WT arena (vector writes only).
__global__ __launch_bounds__(256) void prep_kernel(
    const float* __restrict__ w1_k, const float* __restrict__ w1_q,
    const float* __restrict__ wv, const float* __restrict__ wo,
    const float* __restrict__ w2_k, const float* __restrict__ wa_k,
    const float* __restrict__ w2_q, const float* __restrict__ wa_q,
    ushort* __restrict__ WT) {
  __shared__ float Lt[64][65];
  const int bi = blockIdx.x, tid = threadIdx.x;
  const float* src;
  int ncols, k0, n0;
  ushort* dhi;
  int losz;
  if (bi < 64) {
    const int m = bi >> 4, t = bi & 15;
    src = (m == 0) ? w1_k : (m == 1) ? w1_q : (m == 2) ? wv : wo;
    ncols = 256; k0 = (t >> 2) * 64; n0 = (t & 3) * 64;
    dhi = WT + m * 131072; losz = 65536;
  } else {
    const int m = (bi - 64) >> 2, kt = (bi - 64) & 3;
    src = (m == 0) ? w2_k : (m == 1) ? wa_k : (m == 2) ? w2_q : wa_q;
    ncols = 64; k0 = kt * 64; n0 = 0;
    dhi = WT + WT2_OFF + m * 32768; losz = 16384;
  }
  ushort* dlo = dhi + losz;
  for (int p = 0; p < 16; ++p) {
    const int kr = p * 4 + (tid >> 6), nc = tid & 63;
    Lt[kr][nc] = src[(k0 + kr) * ncols + n0 + nc];
  }
  __syncthreads();
  const int n = tid >> 2, kq = tid & 3;
  uint uh[8], ul[8];
  for (int i = 0; i < 8; ++i) {
    const float v0 = Lt[kq * 16 + 2 * i][n];
    const float v1 = Lt[kq * 16 + 2 * i + 1][n];
    uh[i] = (uint)bf16_hi(v0) | ((uint)bf16_hi(v1) << 16);
    ul[i] = (uint)bf16_rne(v0 - hi_f(v0)) | ((uint)bf16_rne(v1 - hi_f(v1)) << 16);
  }
  const int oidx = (n0 + n) * 256 + k0 + kq * 16;
  *(uint4*)&dhi[oidx] = make_uint4(uh[0], uh[1], uh[2], uh[3]);
  *(uint4*)&dhi[oidx + 8] = make_uint4(uh[4], uh[5], uh[6], uh[7]);
  *(uint4*)&dlo[oidx] = make_uint4(ul[0], ul[1], ul[2], ul[3]);
  *(uint4*)&dlo[oidx + 8] = make_uint4(ul[4], ul[5], ul[6], ul[7]);
}

// ---------------------------------------------------------------------------
// K1: layer-1 as 3 GEMMs via MFMA bf16x3. 32x64 tiles, 768 blocks (3/CU).
// Register prefetch of next k-tile overlapped with MFMA phase.
__global__ __launch_bounds__(256) void enc1_kernel(
    const float* __restrict__ x, const float* __restrict__ pos_k,
    const float* __restrict__ pos_q,
    const float* __restrict__ b1_k, const float* __restrict__ b1_q,
    const float* __restrict__ bv, const ushort* __restrict__ WT,
    float* __restrict__ hk, float* __restrict__ hq, float* __restrict__ V) {
  __shared__ __align__(16) ushort Ah[32][40], Al[32][40];
  __shared__ __align__(16) ushort Bh[64][40], Bl[64][40];
  const int tid = threadIdx.x;
  const int g = blockIdx.x / 256;
  const int rem = blockIdx.x % 256;
  const int row0 = (rem >> 2) * 32, nb = (rem & 3) * 64;
  const float* pos = (g == 0) ? pos_k : (g == 1) ? pos_q : nullptr;
  const ushort* Wh = WT + g * 131072;
  const ushort* Wl = Wh + 65536;
  const int w = tid >> 6, lane = tid & 63;
  const int m16 = lane & 15, quad = lane >> 4;

  const int sr = tid >> 3, skc = (tid & 7) * 4;
  const int srow = row0 + sr, sl = srow & (L - 1);
  const int sn = tid >> 2, schunk = tid & 3;

  float4 pxv;
  uint4 pbh, pbl;
  auto loadTile = [&](int k0) {
    float4 xv = *(const float4*)&x[srow * D + k0 + skc];
    if (pos) {
      const float4 pv = *(const float4*)&pos[sl * D + k0 + skc];
      xv.x += pv.x; xv.y += pv.y; xv.z += pv.z; xv.w += pv.w;
    }
    pxv = xv;
    const int ga = (nb + sn) * 256 + k0 + schunk * 8;
    pbh = *(const uint4*)&Wh[ga];
    pbl = *(const uint4*)&Wl[ga];
  };

  float4v acc[2] = {};
  loadTile(0);

  for (int k0 = 0; k0 < 256; k0 += 32) {
    __syncthreads();
    {
      ushort4 h4, l4;
      h4.x = bf16_hi(pxv.x); l4.x = bf16_rne(pxv.x - hi_f(pxv.x));
      h4.y = bf16_hi(pxv.y); l4.y = bf16_rne(pxv.y - hi_f(pxv.y));
      h4.z = bf16_hi(pxv.z); l4.z = bf16_rne(pxv.z - hi_f(pxv.z));
      h4.w = bf16_hi(pxv.w); l4.w = bf16_rne(pxv.w - hi_f(pxv.w));
      *(ushort4*)&Ah[sr][skc] = h4;
      *(ushort4*)&Al[sr][skc] = l4;
      *(uint4*)&Bh[sn][schunk * 8] = pbh;
      *(uint4*)&Bl[sn][schunk * 8] = pbl;
    }
    __syncthreads();
    if (k0 + 32 < 256) loadTile(k0 + 32);

    short8 afh[2], afl[2];
#pragma unroll
    for (int r = 0; r < 2; ++r) {
      afh[r] = *(const short8*)&Ah[r * 16 + m16][quad * 8];
      afl[r] = *(const short8*)&Al[r * 16 + m16][quad * 8];
    }
    const int col = w * 16 + m16;
    const short8 bfh = *(const short8*)&Bh[col][quad * 8];
    const short8 bfl = *(const short8*)&Bl[col][quad * 8];
#pragma unroll
    for (int r = 0; r < 2; ++r) {
      acc[r] = __builtin_amdgcn_mfma_f32_16x16x32_bf16(afh[r], bfh, acc[r], 0, 0, 0);
      acc[r] = __builtin_amdgcn_mfma_f32_16x16x32_bf16(afh[r], bfl, acc[r], 0, 0, 0);
      acc[r] = __builtin_amdgcn_mfma_f32_16x16x32_bf16(afl[r], bfh, acc[r], 0, 0, 0);
    }
  }

  float* outp = (g == 0) ? hk : (g == 1) ? hq : V;
  const float* bp = (g == 0) ? b1_k : (g == 1) ? b1_q : bv;
  const int colg = nb + w * 16 + m16;
  const float bias = bp[colg];
#pragma unroll
  for (int r = 0; r < 2; ++r)
#pragma unroll
    for (int j = 0; j < 4; ++j) {
      const int rowg = row0 + r * 16 + quad * 4 + j;
      float v = acc[r][j] + bias;
      if (g < 2) v = 0.5f * v * (1.0f + erff(v * 0.70710678f));
      outp[rowg * D + colg] = v;
    }
}

// ---------------------------------------------------------------------------
// K2: layer-2 (phase & amp GEMMs) + phasor epilogue.
// 512 blocks x 256 threads; double-buffered LDS, one barrier per k-iter.
__global__ __launch_bounds__(256) void enc2_kernel(
    const float* __restrict__ x, const float* __restrict__ pos_k,
    const float* __restrict__ pos_q, const float* __restrict__ hk,
    const float* __restrict__ hq,
    const float* __restrict__ b2_k, const float* __restrict__ ba_k,
    const float* __restrict__ b2_q, const float* __restrict__ ba_q,
    const ushort* __restrict__ WT,
    float* __restrict__ kr, float* __restrict__ ki,
    float* __restrict__ qr, float* __restrict__ qi) {
  __shared__ __align__(16) ushort Ahh[2][16][40], Ahl[2][16][40];
  __shared__ __align__(16) ushort Axh[2][16][40], Axl[2][16][40];
  __shared__ __align__(16) ushort B2h[2][32][40], B2l[2][32][40];
  __shared__ __align__(16) ushort Bah[2][32][40], Bal[2][32][40];
  __shared__ float phL[16][36], amL[16][36];
  const int tid = threadIdx.x;
  const int e = blockIdx.x >> 8;
  const int rem = blockIdx.x & 255;
  const int r0g = (rem >> 1) * 16;
  const int colbase = (rem & 1) * 32;
  const float* hsrc = e ? hq : hk;
  const float* pos = e ? pos_q : pos_k;
  const ushort* W2h = WT + WT2_OFF + (e ? 2 : 0) * 32768;
  const ushort* W2l = W2h + 16384;
  const ushort* Wah = WT + WT2_OFF + (e ? 3 : 1) * 32768;
  const ushort* Wal = Wah + 16384;
  const int w = tid >> 6, lane = tid & 63;
  const int m16 = lane & 15, quad = lane >> 4;
  const int mat = w & 1, ct = w >> 1;

  const int ahalf = tid >> 7;
  const int at = tid & 127;
  const int ar_ = at >> 3, akc = (at & 7) * 4;
  const int arow = r0g + ar_, al_ = arow & (L - 1);
  const int bsel = tid >> 6;
  const int bidx = tid & 63;
  const int bn = bidx >> 1, bch = (bidx & 1) * 2;
  const ushort* bs = (bsel == 0) ? W2h : (bsel == 1) ? W2l : (bsel == 2) ? Wah : Wal;

  float4 pav;
  uint4 pb0, pb1;
  auto loadTile = [&](int k0) {
    if (ahalf == 0) {
      pav = *(const float4*)&hsrc[arow * D + k0 + akc];
    } else {
      const float4 xv = *(const float4*)&x[arow * D + k0 + akc];
      const float4 pv = *(const float4*)&pos[al_ * D + k0 + akc];
      pav.x = xv.x + pv.x; pav.y = xv.y + pv.y;
      pav.z = xv.z + pv.z; pav.w = xv.w + pv.w;
    }
    const int ga = (colbase + bn) * 256 + k0 + bch * 8;
    pb0 = *(const uint4*)&bs[ga];
    pb1 = *(const uint4*)&bs[ga + 8];
  };
  auto storeTile = [&](int p) {
    ushort4 h4, l4;
    h4.x = bf16_hi(pav.x); l4.x = bf16_rne(pav.x - hi_f(pav.x));
    h4.y = bf16_hi(pav.y); l4.y = bf16_rne(pav.y - hi_f(pav.y));
    h4.z = bf16_hi(pav.z); l4.z = bf16_rne(pav.z - hi_f(pav.z));
    h4.w = bf16_hi(pav.w); l4.w = bf16_rne(pav.w - hi_f(pav.w));
    if (ahalf == 0) {
      *(ushort4*)&Ahh[p][ar_][akc] = h4;
      *(ushort4*)&Ahl[p][ar_][akc] = l4;
    } else {
      *(ushort4*)&Axh[p][ar_][akc] = h4;
      *(ushort4*)&Axl[p][ar_][akc] = l4;
    }
    ushort* bdst = (bsel == 0) ? &B2h[p][bn][bch * 8] : (bsel == 1) ? &B2l[p][bn][bch * 8]
                 : (bsel == 2) ? &Bah[p][bn][bch * 8] : &Bal[p][bn][bch * 8];
    *(uint4*)bdst = pb0;
    *(uint4*)(bdst + 8) = pb1;
  };

  float4v acc = {};
  loadTile(0);
  storeTile(0);
  int p = 0;

  for (int k0 = 0; k0 < 256; k0 += 32) {
    __syncthreads();
    const bool more = (k0 + 32 < 256);
    if (more) loadTile(k0 + 32);

    const short8 ah = mat ? *(const short8*)&Axh[p][m16][quad * 8]
                          : *(const short8*)&Ahh[p][m16][quad * 8];
    const short8 al = mat ? *(const short8*)&Axl[p][m16][quad * 8]
                          : *(const short8*)&Ahl[p][m16][quad * 8];
    const int col = ct * 16 + m16;
    const short8 bh = mat ? *(const short8*)&Bah[p][col][quad * 8]
                          : *(const short8*)&B2h[p][col][quad * 8];
    const short8 bl = mat ? *(const short8*)&Bal[p][col][quad * 8]
                          : *(const short8*)&B2l[p][col][quad * 8];
    acc = __builtin_amdgcn_mfma_f32_16x16x32_bf16(ah, bh, acc, 0, 0, 0);
    acc = __builtin_amdgcn_mfma_f32_16x16x32_bf16(ah, bl, acc, 0, 0, 0);
    acc = __builtin_amdgcn_mfma_f32_16x16x32_bf16(al, bh, acc, 0, 0, 0);

    if (more) storeTile(p ^ 1);
    p ^= 1;
  }

  {
    const int lcol = ct * 16 + m16;
    const int colk = colbase + lcol;
    if (mat == 0) {
      const float b2v = (e ? b2_q : b2_k)[colk];
#pragma unroll
      for (int j = 0; j < 4; ++j)
        phL[quad * 4 + j][lcol] = tanhf(acc[j] + b2v) * 3.14159265358979f;
    } else {
      const float bav = (e ? ba_q : ba_k)[colk];
#pragma unroll
      for (int j = 0; j < 4; ++j) {
        const float av = acc[j] + bav;
        amL[quad * 4 + j][lcol] = fmaxf(av, 0.0f) + log1pf(expf(-fabsf(av))) + 0.1f;
      }
    }
  }
  __syncthreads();
  {
    float* pr = e ? qr : kr;
    float* pim = e ? qi : ki;
#pragma unroll
    for (int pp = 0; pp < 2; ++pp) {
      const int idx = pp * 256 + tid;
      const int r = idx >> 5, lcol = idx & 31;
      const int row = r0g + r;
      const float a = amL[r][lcol], pph = phL[r][lcol];
      pr[row * K + colbase + lcol] = a * cosf(pph);
      pim[row * K + colbase + lcol] = a * sinf(pph);
    }
  }
}

// ---------------------------------------------------------------------------
// K3: per-chunk T + V^T into TMt[b][c][d][192] = [T_re(64)|T_im(64)|Vt(64)].
__global__ __launch_bounds__(256) void tbuild_kernel(
    const float* __restrict__ kr, const float* __restrict__ ki,
    const float* __restrict__ V, float* __restrict__ TMt) {
  const int id = blockIdx.x;
  const int dc = id & 15, c = (id >> 4) & 15, b = id >> 8;
  const int tid = threadIdx.x;
  const int n0 = b * L + c * 64;
  const int dl = tid & 15;
  const int kb = tid >> 4;

  __shared__ float krL[64][68], kiL[64][68];
  __shared__ float VL[64][20];
  __shared__ float Tl[16][204];
  for (int e = tid; e < 1024; e += 256) {
    const int t = e >> 4, k4 = (e & 15) * 4;
    *(float4*)&krL[t][k4] = *(const float4*)&kr[(n0 + t) * K + k4];
    *(float4*)&kiL[t][k4] = *(const float4*)&ki[(n0 + t) * K + k4];
  }
  {
    const int t = tid >> 2, f = (tid & 3) * 4;
    *(float4*)&VL[t][f] = *(const float4*)&V[(n0 + t) * D + dc * 16 + f];
  }
  __syncthreads();

  {
    const int t0 = (tid >> 4) * 4;
#pragma unroll
    for (int i = 0; i < 4; ++i) Tl[dl][128 + t0 + i] = VL[t0 + i][dl];
  }

  float ar[4] = {0.f, 0.f, 0.f, 0.f}, ai[4] = {0.f, 0.f, 0.f, 0.f};
#pragma unroll 4
  for (int t = 0; t < 64; ++t) {
    const float vt = VL[t][dl];
    const float4 k4r = *(const float4*)&krL[t][kb * 4];
    const float4 k4i = *(const float4*)&kiL[t][kb * 4];
    ar[0] += k4r.x * vt; ar[1] += k4r.y * vt; ar[2] += k4r.z * vt; ar[3] += k4r.w * vt;
    ai[0] += k4i.x * vt; ai[1] += k4i.y * vt; ai[2] += k4i.z * vt; ai[3] += k4i.w * vt;
  }

#pragma unroll
  for (int i = 0; i < 4; ++i) {
    Tl[dl][kb * 4 + i] = ar[i];
    Tl[dl][64 + kb * 4 + i] = ai[i];
  }
  __syncthreads();

  float* dst = &TMt[(((size_t)(b * 16 + c)) * 256 + dc * 16) * 192];
#pragma unroll
  for (int p = 0; p < 3; ++p) {
    const int e = p * 256 + tid;
    const int row = e / 48, f4 = e % 48;
    *(float4*)&dst[(size_t)row * 192 + f4 * 4] = *(const float4*)&Tl[row][f4 * 4];
  }
}

// ---------------------------------------------------------------------------
// K4: ret slice via MFMA, prefix folded in. 512 blocks (dc16) x 256 threads,
// 77 KB LDS -> 2 blocks/CU. S stored bf16-hi only; K region reused for B.
__global__ __launch_bounds__(256) void ret_kernel(
    const float* __restrict__ qr, const float* __restrict__ qi,
    const float* __restrict__ kr, const float* __restrict__ ki,
    const float* __restrict__ TMt, float* __restrict__ ret,
    float* __restrict__ LNred) {
  __shared__ __align__(16) ushort Qh[64][136], Ql[64][136];
  __shared__ __align__(16) ushort Sh[64][72];
  __shared__ __align__(16) char KB[34816];
  ushort* Kh = (ushort*)KB;
  ushort* Kl = Kh + 64 * 136;
  ushort* Bh = (ushort*)KB;
  ushort* Bl = Bh + 16 * 200;

  const int tid = threadIdx.x;
  const int dc = blockIdx.x & 15;
  const int c = (blockIdx.x >> 4) & 15;
  const int b = blockIdx.x >> 8;
  const int n0 = b * L + c * 64;
  const int cols0 = dc * 16;
  const int w = tid >> 6, lane = tid & 63;
  const int m16 = lane & 15, quad = lane >> 4;

  // Phase 0: stage Q, K (hi/lo)
#pragma unroll
  for (int j = 0; j < 8; ++j) {
    const int e = j * 256 + tid;
    const int row = e >> 5, c4 = e & 31;
    const int col0 = (c4 & 15) * 4;
    const int acol = (c4 < 16 ? 0 : 64) + col0;
    {
      const float* src = (c4 < 16) ? qr : qi;
      const float4 v = *(const float4*)&src[(n0 + row) * K + col0];
      ushort4 h4, l4;
      h4.x = bf16_hi(v.x); l4.x = bf16_rne(v.x - hi_f(v.x));
      h4.y = bf16_hi(v.y); l4.y = bf16_rne(v.y - hi_f(v.y));
      h4.z = bf16_hi(v.z); l4.z = bf16_rne(v.z - hi_f(v.z));
      h4.w = bf16_hi(v.w); l4.w = bf16_rne(v.w - hi_f(v.w));
      *(ushort4*)&Qh[row][acol] = h4;
      *(ushort4*)&Ql[row][acol] = l4;
    }
    {
      const float* src = (c4 < 16) ? kr : ki;
      const float4 v = *(const float4*)&src[(n0 + row) * K + col0];
      ushort4 h4, l4;
      h4.x = bf16_hi(v.x); l4.x = bf16_rne(v.x - hi_f(v.x));
      h4.y = bf16_hi(v.y); l4.y = bf16_rne(v.y - hi_f(v.y));
      h4.z = bf16_hi(v.z); l4.z = bf16_rne(v.z - hi_f(v.z));
      h4.w = bf16_hi(v.w); l4.w = bf16_rne(v.w - hi_f(v.w));
      *(ushort4*)&Kh[row * 136 + acol] = h4;
      *(ushort4*)&Kl[row * 136 + acol] = l4;
    }
  }

  // Prefix accumulation (registers)
  float4 mac0 = {}, mac1 = {};
  {
    const int prow = tid >> 4, in0 = (tid & 15) * 8;
    const float* base = &TMt[(size_t)(b * 16) * 49152 +
                             (size_t)(cols0 + prow) * 192 + in0];
    for (int cp = 0; cp < c; ++cp) {
      const float* p = base + (size_t)cp * 49152;
      const float4 v0 = *(const float4*)p;
      const float4 v1 = *(const float4*)(p + 4);
      mac0.x += v0.x; mac0.y += v0.y; mac0.z += v0.z; mac0.w += v0.w;
      mac1.x += v1.x; mac1.y += v1.y; mac1.z += v1.z; mac1.w += v1.w;
    }
  }
  __syncthreads();

  // Phase 1: S = Q.K^T, causal
  {
    float4v sc[4] = {};
#pragma unroll
    for (int kk = 0; kk < 128; kk += 32) {
      const short8 ah = *(const short8*)&Qh[w * 16 + m16][kk + quad * 8];
      const short8 al = *(const short8*)&Ql[w * 16 + m16][kk + quad * 8];
#pragma unroll
      for (int ct = 0; ct < 4; ++ct) {
        const short8 bh = *(const short8*)&Kh[(ct * 16 + m16) * 136 + kk + quad * 8];
        const short8 bl = *(const short8*)&Kl[(ct * 16 + m16) * 136 + kk + quad * 8];
        sc[ct] = __builtin_amdgcn_mfma_f32_16x16x32_bf16(ah, bh, sc[ct], 0, 0, 0);
        sc[ct] = __builtin_amdgcn_mfma_f32_16x16x32_bf16(ah, bl, sc[ct], 0, 0, 0);
        sc[ct] = __builtin_amdgcn_mfma_f32_16x16x32_bf16(al, bh, sc[ct], 0, 0, 0);
      }
    }
#pragma unroll
    for (int ct = 0; ct < 4; ++ct)
#pragma unroll
      for (int j = 0; j < 4; ++j) {
        const int row = w * 16 + quad * 4 + j;
        const int t = ct * 16 + m16;
        Sh[row][t] = (t <= row) ? bf16_hi(sc[ct][j]) : (ushort)0;
      }
  }
  __syncthreads();

  // Phase 2: stage B = [M_c | Vt_c] hi/lo into KB region
  {
    const int prow = tid >> 4, in0 = (tid & 15) * 8;
    ushort4 h4, l4;
    h4.x = bf16_hi(mac0.x); l4.x = bf16_rne(mac0.x - hi_f(mac0.x));
    h4.y = bf16_hi(mac0.y); l4.y = bf16_rne(mac0.y - hi_f(mac0.y));
    h4.z = bf16_hi(mac0.z); l4.z = bf16_rne(mac0.z - hi_f(mac0.z));
    h4.w = bf16_hi(mac0.w); l4.w = bf16_rne(mac0.w - hi_f(mac0.w));
    *(ushort4*)&Bh[prow * 200 + in0] = h4;
    *(ushort4*)&Bl[prow * 200 + in0] = l4;
    h4.x = bf16_hi(mac1.x); l4.x = bf16_rne(mac1.x - hi_f(mac1.x));
    h4.y = bf16_hi(mac1.y); l4.y = bf16_rne(mac1.y - hi_f(mac1.y));
    h4.z = bf16_hi(mac1.z); l4.z = bf16_rne(mac1.z - hi_f(mac1.z));
    h4.w = bf16_hi(mac1.w); l4.w = bf16_rne(mac1.w - hi_f(mac1.w));
    *(ushort4*)&Bh[prow * 200 + in0 + 4] = h4;
    *(ushort4*)&Bl[prow * 200 + in0 + 4] = l4;

    const int vrow = tid >> 4, vin = 128 + (tid & 15) * 4;
    const float4 v = *(const float4*)&TMt[(size_t)(b * 16 + c) * 49152 +
                                          (size_t)(cols0 + vrow) * 192 + vin];
    ushort4 vh, vl;
    vh.x = bf16_hi(v.x); vl.x = bf16_rne(v.x - hi_f(v.x));
    vh.y = bf16_hi(v.y); vl.y = bf16_rne(v.y - hi_f(v.y));
    vh.z = bf16_hi(v.z); vl.z = bf16_rne(v.z - hi_f(v.z));
    vh.w = bf16_hi(v.w); vl.w = bf16_rne(v.w - hi_f(v.w));
    *(ushort4*)&Bh[vrow * 200 + vin] = vh;
    *(ushort4*)&Bl[vrow * 200 + vin] = vl;
  }
  __syncthreads();

  // Phase 3: ret slice = [Q|S].[M;Vt]
  {
    float4v r2 = {};
#pragma unroll
    for (int kk = 0; kk < 4; ++kk) {
      const short8 ah = *(const short8*)&Qh[w * 16 + m16][kk * 32 + quad * 8];
      const short8 al = *(const short8*)&Ql[w * 16 + m16][kk * 32 + quad * 8];
      const short8 bh = *(const short8*)&Bh[m16 * 200 + kk * 32 + quad * 8];
      const short8 bl = *(const short8*)&Bl[m16 * 200 + kk * 32 + quad * 8];
      r2 = __builtin_amdgcn_mfma_f32_16x16x32_bf16(ah, bh, r2, 0, 0, 0);
      r2 = __builtin_amdgcn_mfma_f32_16x16x32_bf16(ah, bl, r2, 0, 0, 0);
      r2 = __builtin_amdgcn_mfma_f32_16x16x32_bf16(al, bh, r2, 0, 0, 0);
    }
#pragma unroll
    for (int s2 = 0; s2 < 2; ++s2) {
      const short8 ah = *(const short8*)&Sh[w * 16 + m16][s2 * 32 + quad * 8];
      const short8 bh = *(const short8*)&Bh[m16 * 200 + 128 + s2 * 32 + quad * 8];
      const short8 bl = *(const short8*)&Bl[m16 * 200 + 128 + s2 * 32 + quad * 8];
      r2 = __builtin_amdgcn_mfma_f32_16x16x32_bf16(ah, bh, r2, 0, 0, 0);
      r2 = __builtin_amdgcn_mfma_f32_16x16x32_bf16(ah, bl, r2, 0, 0, 0);
    }
#pragma unroll
    for (int j = 0; j < 4; ++j) {
      const int rowL = w * 16 + quad * 4 + j;
      const float nrm = rsqrtf((float)(c * 64 + rowL + 1) * 64.0f);
      const float v = r2[j] * nrm;
      ret[(size_t)(n0 + rowL) * D + cols0 + m16] = v;
      float sj = v, s2j = v * v;
      for (int off = 1; off < 16; off <<= 1) {
        sj += __shfl_xor(sj, off, 64);
        s2j += __shfl_xor(s2j, off, 64);
      }
      if (m16 == 0) {
        LNred[(size_t)(n0 + rowL) * 32 + dc * 2 + 0] = sj;
        LNred[(size_t)(n0 + rowL) * 32 + dc * 2 + 1] = s2j;
      }
    }
  }
}

// ---------------------------------------------------------------------------
// K5: out = x + LN(ret).wo + bo via MFMA bf16x3. 512 blocks x 256 threads,
// double-buffered LDS, one barrier per k-iter.
__global__ __launch_bounds__(256) void out2_kernel(
    const float* __restrict__ ret, const float* __restrict__ LNred,
    const float* __restrict__ x, const float* __restrict__ ln_g,
    const float* __restrict__ ln_b, const ushort* __restrict__ WT,
    const float* __restrict__ bo, float* __restrict__ out) {
  __shared__ __align__(16) ushort Ah[2][32][40], Al[2][32][40];
  __shared__ __align__(16) ushort Bh[2][32][40], Bl[2][32][40];
  __shared__ float mu_s[32], rs_s[32];
  const int tid = threadIdx.x;
  const int row0 = (blockIdx.x >> 3) * 32, nb = (blockIdx.x & 7) * 32;
  const ushort* Wh = WT + 3 * 131072;
  const ushort* Wl = Wh + 65536;
  const int w = tid >> 6, lane = tid & 63;
  const int m16 = lane & 15, quad = lane >> 4;
  const int rt = w & 1, cq = w >> 1;

  const int ar_ = tid >> 3, akc = (tid & 7) * 4;
  const int bplane = tid >> 7;
  const int bidx = tid & 127;
  const int bn = bidx >> 2, bchunk = bidx & 3;

  if (tid < 32) {
    const int row = row0 + tid;
    float s = 0.f, s2 = 0.f;
#pragma unroll
    for (int i = 0; i < 16; ++i) {
      s += LNred[(size_t)row * 32 + i * 2 + 0];
      s2 += LNred[(size_t)row * 32 + i * 2 + 1];
    }
    const float mu = s * (1.0f / 256.0f);
    mu_s[tid] = mu;
    rs_s[tid] = rsqrtf(s2 * (1.0f / 256.0f) - mu * mu + 1e-5f);
  }
  __syncthreads();   // mu_s/rs_s visible to all before first storeTile

  float4 prv, pg4, pb4;
  uint4 pbw;
  auto loadTile = [&](int k0) {
    prv = *(const float4*)&ret[(size_t)(row0 + ar_) * D + k0 + akc];
    pg4 = *(const float4*)&ln_g[k0 + akc];
    pb4 = *(const float4*)&ln_b[k0 + akc];
    const int ga = (nb + bn) * 256 + k0 + bchunk * 8;
    pbw = (bplane == 0) ? *(const uint4*)&Wh[ga] : *(const uint4*)&Wl[ga];
  };
  auto storeTile = [&](int p) {
    const float mu = mu_s[ar_], rs = rs_s[ar_];
    const float a0 = (prv.x - mu) * rs * pg4.x + pb4.x;
    const float a1 = (prv.y - mu) * rs * pg4.y + pb4.y;
    const float a2 = (prv.z - mu) * rs * pg4.z + pb4.z;
    const float a3 = (prv.w - mu) * rs * pg4.w + pb4.w;
    ushort4 h4, l4;
    h4.x = bf16_hi(a0); l4.x = bf16_rne(a0 - hi_f(a0));
    h4.y = bf16_hi(a1); l4.y = bf16_rne(a1 - hi_f(a1));
    h4.z = bf16_hi(a2); l4.z = bf16_rne(a2 - hi_f(a2));
    h4.w = bf16_hi(a3); l4.w = bf16_rne(a3 - hi_f(a3));
    *(ushort4*)&Ah[p][ar_][akc] = h4;
    *(ushort4*)&Al[p][ar_][akc] = l4;
    if (bplane == 0) *(uint4*)&Bh[p][bn][bchunk * 8] = pbw;
    else             *(uint4*)&Bl[p][bn][bchunk * 8] = pbw;
  };

  float4v acc = {};
  loadTile(0);
  storeTile(0);
  int p = 0;

  for (int k0 = 0; k0 < 256; k0 += 32) {
    __syncthreads();
    const bool more = (k0 + 32 < 256);
    if (more) loadTile(k0 + 32);

    const short8 afh = *(const short8*)&Ah[p][rt * 16 + m16][quad * 8];
    const short8 afl = *(const short8*)&Al[p][rt * 16 + m16][quad * 8];
    const int col = cq * 16 + m16;
    const short8 bfh = *(const short8*)&Bh[p][col][quad * 8];
    const short8 bfl = *(const short8*)&Bl[p][col][quad * 8];
    acc = __builtin_amdgcn_mfma_f32_16x16x32_bf16(afh, bfh, acc, 0, 0, 0);
    acc = __builtin_amdgcn_mfma_f32_16x16x32_bf16(afh, bfl, acc, 0, 0, 0);
    acc = __builtin_amdgcn_mfma_f32_16x16x32_bf16(afl, bfh, acc, 0, 0, 0);

    if (more) storeTile(p ^ 1);
    p ^= 1;
  }

  const int colg = nb + cq * 16 + m16;
  const float bias = bo[colg];
#pragma unroll
  for (int j = 0; j < 4; ++j) {
    const int rowg = row0 + rt * 16 + quad * 4 + j;
    out[rowg * D + colg] = x[rowg * D + colg] + acc[j] + bias;
  }
}

// ---------------------------------------------------------------------------
extern "C" void kernel_launch(void* const* d_in, const int* in_sizes, int n_in,
                              void* d_out, int out_size, void* d_ws, size_t ws_size,
                              hipStream_t stream) {
  (void)in_sizes; (void)n_in; (void)out_size; (void)ws_size;
  const float* x    = (const float*)d_in[0];
  const float* pos_k= (const float*)d_in[1];
  const float* w1_k = (const float*)d_in[2];
  const float* b1_k = (const float*)d_in[3];
  const float* w2_k = (const float*)d_in[4];
  const float* b2_k = (const float*)d_in[5];
  const float* wa_k = (const float*)d_in[6];
  const float* ba_k = (const float*)d_in[7];
  const float* pos_q= (const float*)d_in[8];
  const float* w1_q = (const float*)d_in[9];
  const float* b1_q = (const float*)d_in[10];
  const float* w2_q = (const float*)d_in[11];
  const float* b2_q = (const float*)d_in[12];
  const float* wa_q = (const float*)d_in[13];
  const float* ba_q = (const float*)d_in[14];
  const float* wv   = (const float*)d_in[15];
  const float* bv   = (const float*)d_in[16];
  const float* ln_g = (const float*)d_in[17];
  const float* ln_b = (const float*)d_in[18];
  const float* wo   = (const float*)d_in[19];
  const float* bo   = (const float*)d_in[20];

  float* ws = (float*)d_ws;
  float* kr = ws;                          // N*K
  float* ki = kr + (size_t)N * K;
  float* qr = ki + (size_t)N * K;
  float* qi = qr + (size_t)N * K;
  float* V  = qi + (size_t)N * K;          // N*D
  float* TMt = V + (size_t)N * D;          // B*NC*256*192
  float* ret = TMt + (size_t)B * NC * 256 * 192;  // N*D
  float* LNred = ret + (size_t)N * D;      // N*32
  float* hk = LNred + (size_t)N * 32;      // N*D
  float* hq = hk + (size_t)N * D;          // N*D
  ushort* WT = (ushort*)(hq + (size_t)N * D);   // 655360 ushorts

  prep_kernel<<<80, 256, 0, stream>>>(w1_k, w1_q, wv, wo,
                                      w2_k, wa_k, w2_q, wa_q, WT);
  enc1_kernel<<<768, 256, 0, stream>>>(x, pos_k, pos_q, b1_k, b1_q, bv, WT,
                                       hk, hq, V);
  enc2_kernel<<<512, 256, 0, stream>>>(x, pos_k, pos_q, hk, hq,
                                       b2_k, ba_k, b2_q, ba_q, WT,
                                       kr, ki, qr, qi);
  tbuild_kernel<<<B * NC * 16, 256, 0, stream>>>(kr, ki, V, TMt);
  ret_kernel<<<B * NC * 16, 256, 0, stream>>>(qr, qi, kr, ki, TMt, ret, LNred);
  out2_kernel<<<512, 256, 0, stream>>>(ret, LNred, x, ln_g, ln_b, WT, bo,
                                       (float*)d_out);
}

// Round 20
// 140.751 us; speedup vs baseline: 1.2321x; 1.0094x over previous
//
#include <hip/hip_runtime.h>
#include <hip/hip_bf16.h>

typedef __attribute__((ext_vector_type(8))) short short8;
typedef __attribute__((ext_vector_type(4))) float float4v;

constexpr int B = 2, L = 1024, D = 256, K = 64;
constexpr int N = B * L;          // 2048 rows
constexpr int NC = L / 64;        // 16 chunks of 64 tokens

// WT arena (ushort units):
// big mats m in {w1_k, w1_q, wv, wo}: hi at m*131072, lo at +65536
// layer2 mats m in {w2_k, wa_k, w2_q, wa_q}: hi at WT2_OFF + m*32768, lo +16384
constexpr int WT2_OFF = 524288;

__device__ __forceinline__ ushort bf16_hi(float v) {
  return (ushort)(__float_as_uint(v) >> 16);
}
__device__ __forceinline__ float hi_f(float v) {
  return __uint_as_float(__float_as_uint(v) & 0xFFFF0000u);
}
__device__ __forceinline__ ushort bf16_rne(float v) {
  uint b = __float_as_uint(v);
  b += 0x7FFF + ((b >> 16) & 1);
  return (ushort)(b >> 16);
}

// ---------------------------------------------------------------------------
// K0: transpose + hi/lo split weights into WT arena (vector writes only).
__global__ __launch_bounds__(256) void prep_kernel(
    const float* __restrict__ w1_k, const float* __restrict__ w1_q,
    const float* __restrict__ wv, const float* __restrict__ wo,
    const float* __restrict__ w2_k, const float* __restrict__ wa_k,
    const float* __restrict__ w2_q, const float* __restrict__ wa_q,
    ushort* __restrict__ WT) {
  __shared__ float Lt[64][65];
  const int bi = blockIdx.x, tid = threadIdx.x;
  const float* src;
  int ncols, k0, n0;
  ushort* dhi;
  int losz;
  if (bi < 64) {
    const int m = bi >> 4, t = bi & 15;
    src = (m == 0) ? w1_k : (m == 1) ? w1_q : (m == 2) ? wv : wo;
    ncols = 256; k0 = (t >> 2) * 64; n0 = (t & 3) * 64;
    dhi = WT + m * 131072; losz = 65536;
  } else {
    const int m = (bi - 64) >> 2, kt = (bi - 64) & 3;
    src = (m == 0) ? w2_k : (m == 1) ? wa_k : (m == 2) ? w2_q : wa_q;
    ncols = 64; k0 = kt * 64; n0 = 0;
    dhi = WT + WT2_OFF + m * 32768; losz = 16384;
  }
  ushort* dlo = dhi + losz;
  for (int p = 0; p < 16; ++p) {
    const int kr = p * 4 + (tid >> 6), nc = tid & 63;
    Lt[kr][nc] = src[(k0 + kr) * ncols + n0 + nc];
  }
  __syncthreads();
  const int n = tid >> 2, kq = tid & 3;
  uint uh[8], ul[8];
  for (int i = 0; i < 8; ++i) {
    const float v0 = Lt[kq * 16 + 2 * i][n];
    const float v1 = Lt[kq * 16 + 2 * i + 1][n];
    uh[i] = (uint)bf16_hi(v0) | ((uint)bf16_hi(v1) << 16);
    ul[i] = (uint)bf16_rne(v0 - hi_f(v0)) | ((uint)bf16_rne(v1 - hi_f(v1)) << 16);
  }
  const int oidx = (n0 + n) * 256 + k0 + kq * 16;
  *(uint4*)&dhi[oidx] = make_uint4(uh[0], uh[1], uh[2], uh[3]);
  *(uint4*)&dhi[oidx + 8] = make_uint4(uh[4], uh[5], uh[6], uh[7]);
  *(uint4*)&dlo[oidx] = make_uint4(ul[0], ul[1], ul[2], ul[3]);
  *(uint4*)&dlo[oidx + 8] = make_uint4(ul[4], ul[5], ul[6], ul[7]);
}

// ---------------------------------------------------------------------------
// K1: layer-1 as 3 GEMMs via MFMA bf16x3. 32x64 tiles, 768 blocks (3/CU).
// Double-buffered LDS: one barrier per k-iter, prefetch under MFMA.
__global__ __launch_bounds__(256) void enc1_kernel(
    const float* __restrict__ x, const float* __restrict__ pos_k,
    const float* __restrict__ pos_q,
    const float* __restrict__ b1_k, const float* __restrict__ b1_q,
    const float* __restrict__ bv, const ushort* __restrict__ WT,
    float* __restrict__ hk, float* __restrict__ hq, float* __restrict__ V) {
  __shared__ __align__(16) ushort Ah[2][32][40], Al[2][32][40];
  __shared__ __align__(16) ushort Bh[2][64][40], Bl[2][64][40];
  const int tid = threadIdx.x;
  const int g = blockIdx.x / 256;
  const int rem = blockIdx.x % 256;
  const int row0 = (rem >> 2) * 32, nb = (rem & 3) * 64;
  const float* pos = (g == 0) ? pos_k : (g == 1) ? pos_q : nullptr;
  const ushort* Wh = WT + g * 131072;
  const ushort* Wl = Wh + 65536;
  const int w = tid >> 6, lane = tid & 63;
  const int m16 = lane & 15, quad = lane >> 4;

  const int sr = tid >> 3, skc = (tid & 7) * 4;
  const int srow = row0 + sr, sl = srow & (L - 1);
  const int sn = tid >> 2, schunk = tid & 3;

  float4 pxv;
  uint4 pbh, pbl;
  auto loadTile = [&](int k0) {
    float4 xv = *(const float4*)&x[srow * D + k0 + skc];
    if (pos) {
      const float4 pv = *(const float4*)&pos[sl * D + k0 + skc];
      xv.x += pv.x; xv.y += pv.y; xv.z += pv.z; xv.w += pv.w;
    }
    pxv = xv;
    const int ga = (nb + sn) * 256 + k0 + schunk * 8;
    pbh = *(const uint4*)&Wh[ga];
    pbl = *(const uint4*)&Wl[ga];
  };
  auto storeTile = [&](int p) {
    ushort4 h4, l4;
    h4.x = bf16_hi(pxv.x); l4.x = bf16_rne(pxv.x - hi_f(pxv.x));
    h4.y = bf16_hi(pxv.y); l4.y = bf16_rne(pxv.y - hi_f(pxv.y));
    h4.z = bf16_hi(pxv.z); l4.z = bf16_rne(pxv.z - hi_f(pxv.z));
    h4.w = bf16_hi(pxv.w); l4.w = bf16_rne(pxv.w - hi_f(pxv.w));
    *(ushort4*)&Ah[p][sr][skc] = h4;
    *(ushort4*)&Al[p][sr][skc] = l4;
    *(uint4*)&Bh[p][sn][schunk * 8] = pbh;
    *(uint4*)&Bl[p][sn][schunk * 8] = pbl;
  };

  float4v acc[2] = {};
  loadTile(0);
  storeTile(0);
  int p = 0;

  for (int k0 = 0; k0 < 256; k0 += 32) {
    __syncthreads();
    const bool more = (k0 + 32 < 256);
    if (more) loadTile(k0 + 32);

    short8 afh[2], afl[2];
#pragma unroll
    for (int r = 0; r < 2; ++r) {
      afh[r] = *(const short8*)&Ah[p][r * 16 + m16][quad * 8];
      afl[r] = *(const short8*)&Al[p][r * 16 + m16][quad * 8];
    }
    const int col = w * 16 + m16;
    const short8 bfh = *(const short8*)&Bh[p][col][quad * 8];
    const short8 bfl = *(const short8*)&Bl[p][col][quad * 8];
#pragma unroll
    for (int r = 0; r < 2; ++r) {
      acc[r] = __builtin_amdgcn_mfma_f32_16x16x32_bf16(afh[r], bfh, acc[r], 0, 0, 0);
      acc[r] = __builtin_amdgcn_mfma_f32_16x16x32_bf16(afh[r], bfl, acc[r], 0, 0, 0);
      acc[r] = __builtin_amdgcn_mfma_f32_16x16x32_bf16(afl[r], bfh, acc[r], 0, 0, 0);
    }

    if (more) storeTile(p ^ 1);
    p ^= 1;
  }

  float* outp = (g == 0) ? hk : (g == 1) ? hq : V;
  const float* bp = (g == 0) ? b1_k : (g == 1) ? b1_q : bv;
  const int colg = nb + w * 16 + m16;
  const float bias = bp[colg];
#pragma unroll
  for (int r = 0; r < 2; ++r)
#pragma unroll
    for (int j = 0; j < 4; ++j) {
      const int rowg = row0 + r * 16 + quad * 4 + j;
      float v = acc[r][j] + bias;
      if (g < 2) v = 0.5f * v * (1.0f + erff(v * 0.70710678f));
      outp[rowg * D + colg] = v;
    }
}

// ---------------------------------------------------------------------------
// K2: layer-2 (phase & amp GEMMs) + phasor epilogue.
// 512 blocks x 256 threads; double-buffered LDS, one barrier per k-iter.
__global__ __launch_bounds__(256) void enc2_kernel(
    const float* __restrict__ x, const float* __restrict__ pos_k,
    const float* __restrict__ pos_q, const float* __restrict__ hk,
    const float* __restrict__ hq,
    const float* __restrict__ b2_k, const float* __restrict__ ba_k,
    const float* __restrict__ b2_q, const float* __restrict__ ba_q,
    const ushort* __restrict__ WT,
    float* __restrict__ kr, float* __restrict__ ki,
    float* __restrict__ qr, float* __restrict__ qi) {
  __shared__ __align__(16) ushort Ahh[2][16][40], Ahl[2][16][40];
  __shared__ __align__(16) ushort Axh[2][16][40], Axl[2][16][40];
  __shared__ __align__(16) ushort B2h[2][32][40], B2l[2][32][40];
  __shared__ __align__(16) ushort Bah[2][32][40], Bal[2][32][40];
  __shared__ float phL[16][36], amL[16][36];
  const int tid = threadIdx.x;
  const int e = blockIdx.x >> 8;
  const int rem = blockIdx.x & 255;
  const int r0g = (rem >> 1) * 16;
  const int colbase = (rem & 1) * 32;
  const float* hsrc = e ? hq : hk;
  const float* pos = e ? pos_q : pos_k;
  const ushort* W2h = WT + WT2_OFF + (e ? 2 : 0) * 32768;
  const ushort* W2l = W2h + 16384;
  const ushort* Wah = WT + WT2_OFF + (e ? 3 : 1) * 32768;
  const ushort* Wal = Wah + 16384;
  const int w = tid >> 6, lane = tid & 63;
  const int m16 = lane & 15, quad = lane >> 4;
  const int mat = w & 1, ct = w >> 1;

  const int ahalf = tid >> 7;
  const int at = tid & 127;
  const int ar_ = at >> 3, akc = (at & 7) * 4;
  const int arow = r0g + ar_, al_ = arow & (L - 1);
  const int bsel = tid >> 6;
  const int bidx = tid & 63;
  const int bn = bidx >> 1, bch = (bidx & 1) * 2;
  const ushort* bs = (bsel == 0) ? W2h : (bsel == 1) ? W2l : (bsel == 2) ? Wah : Wal;

  float4 pav;
  uint4 pb0, pb1;
  auto loadTile = [&](int k0) {
    if (ahalf == 0) {
      pav = *(const float4*)&hsrc[arow * D + k0 + akc];
    } else {
      const float4 xv = *(const float4*)&x[arow * D + k0 + akc];
      const float4 pv = *(const float4*)&pos[al_ * D + k0 + akc];
      pav.x = xv.x + pv.x; pav.y = xv.y + pv.y;
      pav.z = xv.z + pv.z; pav.w = xv.w + pv.w;
    }
    const int ga = (colbase + bn) * 256 + k0 + bch * 8;
    pb0 = *(const uint4*)&bs[ga];
    pb1 = *(const uint4*)&bs[ga + 8];
  };
  auto storeTile = [&](int p) {
    ushort4 h4, l4;
    h4.x = bf16_hi(pav.x); l4.x = bf16_rne(pav.x - hi_f(pav.x));
    h4.y = bf16_hi(pav.y); l4.y = bf16_rne(pav.y - hi_f(pav.y));
    h4.z = bf16_hi(pav.z); l4.z = bf16_rne(pav.z - hi_f(pav.z));
    h4.w = bf16_hi(pav.w); l4.w = bf16_rne(pav.w - hi_f(pav.w));
    if (ahalf == 0) {
      *(ushort4*)&Ahh[p][ar_][akc] = h4;
      *(ushort4*)&Ahl[p][ar_][akc] = l4;
    } else {
      *(ushort4*)&Axh[p][ar_][akc] = h4;
      *(ushort4*)&Axl[p][ar_][akc] = l4;
    }
    ushort* bdst = (bsel == 0) ? &B2h[p][bn][bch * 8] : (bsel == 1) ? &B2l[p][bn][bch * 8]
                 : (bsel == 2) ? &Bah[p][bn][bch * 8] : &Bal[p][bn][bch * 8];
    *(uint4*)bdst = pb0;
    *(uint4*)(bdst + 8) = pb1;
  };

  float4v acc = {};
  loadTile(0);
  storeTile(0);
  int p = 0;

  for (int k0 = 0; k0 < 256; k0 += 32) {
    __syncthreads();
    const bool more = (k0 + 32 < 256);
    if (more) loadTile(k0 + 32);

    const short8 ah = mat ? *(const short8*)&Axh[p][m16][quad * 8]
                          : *(const short8*)&Ahh[p][m16][quad * 8];
    const short8 al = mat ? *(const short8*)&Axl[p][m16][quad * 8]
                          : *(const short8*)&Ahl[p][m16][quad * 8];
    const int col = ct * 16 + m16;
    const short8 bh = mat ? *(const short8*)&Bah[p][col][quad * 8]
                          : *(const short8*)&B2h[p][col][quad * 8];
    const short8 bl = mat ? *(const short8*)&Bal[p][col][quad * 8]
                          : *(const short8*)&B2l[p][col][quad * 8];
    acc = __builtin_amdgcn_mfma_f32_16x16x32_bf16(ah, bh, acc, 0, 0, 0);
    acc = __builtin_amdgcn_mfma_f32_16x16x32_bf16(ah, bl, acc, 0, 0, 0);
    acc = __builtin_amdgcn_mfma_f32_16x16x32_bf16(al, bh, acc, 0, 0, 0);

    if (more) storeTile(p ^ 1);
    p ^= 1;
  }

  {
    const int lcol = ct * 16 + m16;
    const int colk = colbase + lcol;
    if (mat == 0) {
      const float b2v = (e ? b2_q : b2_k)[colk];
#pragma unroll
      for (int j = 0; j < 4; ++j)
        phL[quad * 4 + j][lcol] = tanhf(acc[j] + b2v) * 3.14159265358979f;
    } else {
      const float bav = (e ? ba_q : ba_k)[colk];
#pragma unroll
      for (int j = 0; j < 4; ++j) {
        const float av = acc[j] + bav;
        amL[quad * 4 + j][lcol] = fmaxf(av, 0.0f) + log1pf(expf(-fabsf(av))) + 0.1f;
      }
    }
  }
  __syncthreads();
  {
    float* pr = e ? qr : kr;
    float* pim = e ? qi : ki;
#pragma unroll
    for (int pp = 0; pp < 2; ++pp) {
      const int idx = pp * 256 + tid;
      const int r = idx >> 5, lcol = idx & 31;
      const int row = r0g + r;
      const float a = amL[r][lcol], pph = phL[r][lcol];
      pr[row * K + colbase + lcol] = a * cosf(pph);
      pim[row * K + colbase + lcol] = a * sinf(pph);
    }
  }
}

// ---------------------------------------------------------------------------
// K3: per-chunk T + V^T into TMt[b][c][d][192] = [T_re(64)|T_im(64)|Vt(64)].
__global__ __launch_bounds__(256) void tbuild_kernel(
    const float* __restrict__ kr, const float* __restrict__ ki,
    const float* __restrict__ V, float* __restrict__ TMt) {
  const int id = blockIdx.x;
  const int dc = id & 15, c = (id >> 4) & 15, b = id >> 8;
  const int tid = threadIdx.x;
  const int n0 = b * L + c * 64;
  const int dl = tid & 15;
  const int kb = tid >> 4;

  __shared__ float krL[64][68], kiL[64][68];
  __shared__ float VL[64][20];
  __shared__ float Tl[16][204];
  for (int e = tid; e < 1024; e += 256) {
    const int t = e >> 4, k4 = (e & 15) * 4;
    *(float4*)&krL[t][k4] = *(const float4*)&kr[(n0 + t) * K + k4];
    *(float4*)&kiL[t][k4] = *(const float4*)&ki[(n0 + t) * K + k4];
  }
  {
    const int t = tid >> 2, f = (tid & 3) * 4;
    *(float4*)&VL[t][f] = *(const float4*)&V[(n0 + t) * D + dc * 16 + f];
  }
  __syncthreads();

  {
    const int t0 = (tid >> 4) * 4;
#pragma unroll
    for (int i = 0; i < 4; ++i) Tl[dl][128 + t0 + i] = VL[t0 + i][dl];
  }

  float ar[4] = {0.f, 0.f, 0.f, 0.f}, ai[4] = {0.f, 0.f, 0.f, 0.f};
#pragma unroll 4
  for (int t = 0; t < 64; ++t) {
    const float vt = VL[t][dl];
    const float4 k4r = *(const float4*)&krL[t][kb * 4];
    const float4 k4i = *(const float4*)&kiL[t][kb * 4];
    ar[0] += k4r.x * vt; ar[1] += k4r.y * vt; ar[2] += k4r.z * vt; ar[3] += k4r.w * vt;
    ai[0] += k4i.x * vt; ai[1] += k4i.y * vt; ai[2] += k4i.z * vt; ai[3] += k4i.w * vt;
  }

#pragma unroll
  for (int i = 0; i < 4; ++i) {
    Tl[dl][kb * 4 + i] = ar[i];
    Tl[dl][64 + kb * 4 + i] = ai[i];
  }
  __syncthreads();

  float* dst = &TMt[(((size_t)(b * 16 + c)) * 256 + dc * 16) * 192];
#pragma unroll
  for (int p = 0; p < 3; ++p) {
    const int e = p * 256 + tid;
    const int row = e / 48, f4 = e % 48;
    *(float4*)&dst[(size_t)row * 192 + f4 * 4] = *(const float4*)&Tl[row][f4 * 4];
  }
}

// ---------------------------------------------------------------------------
// K4: ret slice via MFMA, prefix folded in. 512 blocks (dc16) x 256 threads,
// 77 KB LDS -> 2 blocks/CU. S stored bf16-hi only; K region reused for B.
__global__ __launch_bounds__(256) void ret_kernel(
    const float* __restrict__ qr, const float* __restrict__ qi,
    const float* __restrict__ kr, const float* __restrict__ ki,
    const float* __restrict__ TMt, float* __restrict__ ret,
    float* __restrict__ LNred) {
  __shared__ __align__(16) ushort Qh[64][136], Ql[64][136];
  __shared__ __align__(16) ushort Sh[64][72];
  __shared__ __align__(16) char KB[34816];
  ushort* Kh = (ushort*)KB;
  ushort* Kl = Kh + 64 * 136;
  ushort* Bh = (ushort*)KB;
  ushort* Bl = Bh + 16 * 200;

  const int tid = threadIdx.x;
  const int dc = blockIdx.x & 15;
  const int c = (blockIdx.x >> 4) & 15;
  const int b = blockIdx.x >> 8;
  const int n0 = b * L + c * 64;
  const int cols0 = dc * 16;
  const int w = tid >> 6, lane = tid & 63;
  const int m16 = lane & 15, quad = lane >> 4;

  // Phase 0: stage Q, K (hi/lo)
#pragma unroll
  for (int j = 0; j < 8; ++j) {
    const int e = j * 256 + tid;
    const int row = e >> 5, c4 = e & 31;
    const int col0 = (c4 & 15) * 4;
    const int acol = (c4 < 16 ? 0 : 64) + col0;
    {
      const float* src = (c4 < 16) ? qr : qi;
      const float4 v = *(const float4*)&src[(n0 + row) * K + col0];
      ushort4 h4, l4;
      h4.x = bf16_hi(v.x); l4.x = bf16_rne(v.x - hi_f(v.x));
      h4.y = bf16_hi(v.y); l4.y = bf16_rne(v.y - hi_f(v.y));
      h4.z = bf16_hi(v.z); l4.z = bf16_rne(v.z - hi_f(v.z));
      h4.w = bf16_hi(v.w); l4.w = bf16_rne(v.w - hi_f(v.w));
      *(ushort4*)&Qh[row][acol] = h4;
      *(ushort4*)&Ql[row][acol] = l4;
    }
    {
      const float* src = (c4 < 16) ? kr : ki;
      const float4 v = *(const float4*)&src[(n0 + row) * K + col0];
      ushort4 h4, l4;
      h4.x = bf16_hi(v.x); l4.x = bf16_rne(v.x - hi_f(v.x));
      h4.y = bf16_hi(v.y); l4.y = bf16_rne(v.y - hi_f(v.y));
      h4.z = bf16_hi(v.z); l4.z = bf16_rne(v.z - hi_f(v.z));
      h4.w = bf16_hi(v.w); l4.w = bf16_rne(v.w - hi_f(v.w));
      *(ushort4*)&Kh[row * 136 + acol] = h4;
      *(ushort4*)&Kl[row * 136 + acol] = l4;
    }
  }

  // Prefix accumulation (registers)
  float4 mac0 = {}, mac1 = {};
  {
    const int prow = tid >> 4, in0 = (tid & 15) * 8;
    const float* base = &TMt[(size_t)(b * 16) * 49152 +
                             (size_t)(cols0 + prow) * 192 + in0];
    for (int cp = 0; cp < c; ++cp) {
      const float* p = base + (size_t)cp * 49152;
      const float4 v0 = *(const float4*)p;
      const float4 v1 = *(const float4*)(p + 4);
      mac0.x += v0.x; mac0.y += v0.y; mac0.z += v0.z; mac0.w += v0.w;
      mac1.x += v1.x; mac1.y += v1.y; mac1.z += v1.z; mac1.w += v1.w;
    }
  }
  __syncthreads();

  // Phase 1: S = Q.K^T, causal
  {
    float4v sc[4] = {};
#pragma unroll
    for (int kk = 0; kk < 128; kk += 32) {
      const short8 ah = *(const short8*)&Qh[w * 16 + m16][kk + quad * 8];
      const short8 al = *(const short8*)&Ql[w * 16 + m16][kk + quad * 8];
#pragma unroll
      for (int ct = 0; ct < 4; ++ct) {
        const short8 bh = *(const short8*)&Kh[(ct * 16 + m16) * 136 + kk + quad * 8];
        const short8 bl = *(const short8*)&Kl[(ct * 16 + m16) * 136 + kk + quad * 8];
        sc[ct] = __builtin_amdgcn_mfma_f32_16x16x32_bf16(ah, bh, sc[ct], 0, 0, 0);
        sc[ct] = __builtin_amdgcn_mfma_f32_16x16x32_bf16(ah, bl, sc[ct], 0, 0, 0);
        sc[ct] = __builtin_amdgcn_mfma_f32_16x16x32_bf16(al, bh, sc[ct], 0, 0, 0);
      }
    }
#pragma unroll
    for (int ct = 0; ct < 4; ++ct)
#pragma unroll
      for (int j = 0; j < 4; ++j) {
        const int row = w * 16 + quad * 4 + j;
        const int t = ct * 16 + m16;
        Sh[row][t] = (t <= row) ? bf16_hi(sc[ct][j]) : (ushort)0;
      }
  }
  __syncthreads();

  // Phase 2: stage B = [M_c | Vt_c] hi/lo into KB region
  {
    const int prow = tid >> 4, in0 = (tid & 15) * 8;
    ushort4 h4, l4;
    h4.x = bf16_hi(mac0.x); l4.x = bf16_rne(mac0.x - hi_f(mac0.x));
    h4.y = bf16_hi(mac0.y); l4.y = bf16_rne(mac0.y - hi_f(mac0.y));
    h4.z = bf16_hi(mac0.z); l4.z = bf16_rne(mac0.z - hi_f(mac0.z));
    h4.w = bf16_hi(mac0.w); l4.w = bf16_rne(mac0.w - hi_f(mac0.w));
    *(ushort4*)&Bh[prow * 200 + in0] = h4;
    *(ushort4*)&Bl[prow * 200 + in0] = l4;
    h4.x = bf16_hi(mac1.x); l4.x = bf16_rne(mac1.x - hi_f(mac1.x));
    h4.y = bf16_hi(mac1.y); l4.y = bf16_rne(mac1.y - hi_f(mac1.y));
    h4.z = bf16_hi(mac1.z); l4.z = bf16_rne(mac1.z - hi_f(mac1.z));
    h4.w = bf16_hi(mac1.w); l4.w = bf16_rne(mac1.w - hi_f(mac1.w));
    *(ushort4*)&Bh[prow * 200 + in0 + 4] = h4;
    *(ushort4*)&Bl[prow * 200 + in0 + 4] = l4;

    const int vrow = tid >> 4, vin = 128 + (tid & 15) * 4;
    const float4 v = *(const float4*)&TMt[(size_t)(b * 16 + c) * 49152 +
                                          (size_t)(cols0 + vrow) * 192 + vin];
    ushort4 vh, vl;
    vh.x = bf16_hi(v.x); vl.x = bf16_rne(v.x - hi_f(v.x));
    vh.y = bf16_hi(v.y); vl.y = bf16_rne(v.y - hi_f(v.y));
    vh.z = bf16_hi(v.z); vl.z = bf16_rne(v.z - hi_f(v.z));
    vh.w = bf16_hi(v.w); vl.w = bf16_rne(v.w - hi_f(v.w));
    *(ushort4*)&Bh[vrow * 200 + vin] = vh;
    *(ushort4*)&Bl[vrow * 200 + vin] = vl;
  }
  __syncthreads();

  // Phase 3: ret slice = [Q|S].[M;Vt]
  {
    float4v r2 = {};
#pragma unroll
    for (int kk = 0; kk < 4; ++kk) {
      const short8 ah = *(const short8*)&Qh[w * 16 + m16][kk * 32 + quad * 8];
      const short8 al = *(const short8*)&Ql[w * 16 + m16][kk * 32 + quad * 8];
      const short8 bh = *(const short8*)&Bh[m16 * 200 + kk * 32 + quad * 8];
      const short8 bl = *(const short8*)&Bl[m16 * 200 + kk * 32 + quad * 8];
      r2 = __builtin_amdgcn_mfma_f32_16x16x32_bf16(ah, bh, r2, 0, 0, 0);
      r2 = __builtin_amdgcn_mfma_f32_16x16x32_bf16(ah, bl, r2, 0, 0, 0);
      r2 = __builtin_amdgcn_mfma_f32_16x16x32_bf16(al, bh, r2, 0, 0, 0);
    }
#pragma unroll
    for (int s2 = 0; s2 < 2; ++s2) {
      const short8 ah = *(const short8*)&Sh[w * 16 + m16][s2 * 32 + quad * 8];
      const short8 bh = *(const short8*)&Bh[m16 * 200 + 128 + s2 * 32 + quad * 8];
      const short8 bl = *(const short8*)&Bl[m16 * 200 + 128 + s2 * 32 + quad * 8];
      r2 = __builtin_amdgcn_mfma_f32_16x16x32_bf16(ah, bh, r2, 0, 0, 0);
      r2 = __builtin_amdgcn_mfma_f32_16x16x32_bf16(ah, bl, r2, 0, 0, 0);
    }
#pragma unroll
    for (int j = 0; j < 4; ++j) {
      const int rowL = w * 16 + quad * 4 + j;
      const float nrm = rsqrtf((float)(c * 64 + rowL + 1) * 64.0f);
      const float v = r2[j] * nrm;
      ret[(size_t)(n0 + rowL) * D + cols0 + m16] = v;
      float sj = v, s2j = v * v;
      for (int off = 1; off < 16; off <<= 1) {
        sj += __shfl_xor(sj, off, 64);
        s2j += __shfl_xor(s2j, off, 64);
      }
      if (m16 == 0) {
        LNred[(size_t)(n0 + rowL) * 32 + dc * 2 + 0] = sj;
        LNred[(size_t)(n0 + rowL) * 32 + dc * 2 + 1] = s2j;
      }
    }
  }
}

// ---------------------------------------------------------------------------
// K5: out = x + LN(ret).wo + bo via MFMA bf16x3. 512 blocks x 256 threads,
// double-buffered LDS, one barrier per k-iter.
__global__ __launch_bounds__(256) void out2_kernel(
    const float* __restrict__ ret, const float* __restrict__ LNred,
    const float* __restrict__ x, const float* __restrict__ ln_g,
    const float* __restrict__ ln_b, const ushort* __restrict__ WT,
    const float* __restrict__ bo, float* __restrict__ out) {
  __shared__ __align__(16) ushort Ah[2][32][40], Al[2][32][40];
  __shared__ __align__(16) ushort Bh[2][32][40], Bl[2][32][40];
  __shared__ float mu_s[32], rs_s[32];
  const int tid = threadIdx.x;
  const int row0 = (blockIdx.x >> 3) * 32, nb = (blockIdx.x & 7) * 32;
  const ushort* Wh = WT + 3 * 131072;
  const ushort* Wl = Wh + 65536;
  const int w = tid >> 6, lane = tid & 63;
  const int m16 = lane & 15, quad = lane >> 4;
  const int rt = w & 1, cq = w >> 1;

  const int ar_ = tid >> 3, akc = (tid & 7) * 4;
  const int bplane = tid >> 7;
  const int bidx = tid & 127;
  const int bn = bidx >> 2, bchunk = bidx & 3;

  if (tid < 32) {
    const int row = row0 + tid;
    float s = 0.f, s2 = 0.f;
#pragma unroll
    for (int i = 0; i < 16; ++i) {
      s += LNred[(size_t)row * 32 + i * 2 + 0];
      s2 += LNred[(size_t)row * 32 + i * 2 + 1];
    }
    const float mu = s * (1.0f / 256.0f);
    mu_s[tid] = mu;
    rs_s[tid] = rsqrtf(s2 * (1.0f / 256.0f) - mu * mu + 1e-5f);
  }
  __syncthreads();   // mu_s/rs_s visible to all before first storeTile

  float4 prv, pg4, pb4;
  uint4 pbw;
  auto loadTile = [&](int k0) {
    prv = *(const float4*)&ret[(size_t)(row0 + ar_) * D + k0 + akc];
    pg4 = *(const float4*)&ln_g[k0 + akc];
    pb4 = *(const float4*)&ln_b[k0 + akc];
    const int ga = (nb + bn) * 256 + k0 + bchunk * 8;
    pbw = (bplane == 0) ? *(const uint4*)&Wh[ga] : *(const uint4*)&Wl[ga];
  };
  auto storeTile = [&](int p) {
    const float mu = mu_s[ar_], rs = rs_s[ar_];
    const float a0 = (prv.x - mu) * rs * pg4.x + pb4.x;
    const float a1 = (prv.y - mu) * rs * pg4.y + pb4.y;
    const float a2 = (prv.z - mu) * rs * pg4.z + pb4.z;
    const float a3 = (prv.w - mu) * rs * pg4.w + pb4.w;
    ushort4 h4, l4;
    h4.x = bf16_hi(a0); l4.x = bf16_rne(a0 - hi_f(a0));
    h4.y = bf16_hi(a1); l4.y = bf16_rne(a1 - hi_f(a1));
    h4.z = bf16_hi(a2); l4.z = bf16_rne(a2 - hi_f(a2));
    h4.w = bf16_hi(a3); l4.w = bf16_rne(a3 - hi_f(a3));
    *(ushort4*)&Ah[p][ar_][akc] = h4;
    *(ushort4*)&Al[p][ar_][akc] = l4;
    if (bplane == 0) *(uint4*)&Bh[p][bn][bchunk * 8] = pbw;
    else             *(uint4*)&Bl[p][bn][bchunk * 8] = pbw;
  };

  float4v acc = {};
  loadTile(0);
  storeTile(0);
  int p = 0;

  for (int k0 = 0; k0 < 256; k0 += 32) {
    __syncthreads();
    const bool more = (k0 + 32 < 256);
    if (more) loadTile(k0 + 32);

    const short8 afh = *(const short8*)&Ah[p][rt * 16 + m16][quad * 8];
    const short8 afl = *(const short8*)&Al[p][rt * 16 + m16][quad * 8];
    const int col = cq * 16 + m16;
    const short8 bfh = *(const short8*)&Bh[p][col][quad * 8];
    const short8 bfl = *(const short8*)&Bl[p][col][quad * 8];
    acc = __builtin_amdgcn_mfma_f32_16x16x32_bf16(afh, bfh, acc, 0, 0, 0);
    acc = __builtin_amdgcn_mfma_f32_16x16x32_bf16(afh, bfl, acc, 0, 0, 0);
    acc = __builtin_amdgcn_mfma_f32_16x16x32_bf16(afl, bfh, acc, 0, 0, 0);

    if (more) storeTile(p ^ 1);
    p ^= 1;
  }

  const int colg = nb + cq * 16 + m16;
  const float bias = bo[colg];
#pragma unroll
  for (int j = 0; j < 4; ++j) {
    const int rowg = row0 + rt * 16 + quad * 4 + j;
    out[rowg * D + colg] = x[rowg * D + colg] + acc[j] + bias;
  }
}

// ---------------------------------------------------------------------------
extern "C" void kernel_launch(void* const* d_in, const int* in_sizes, int n_in,
                              void* d_out, int out_size, void* d_ws, size_t ws_size,
                              hipStream_t stream) {
  (void)in_sizes; (void)n_in; (void)out_size; (void)ws_size;
  const float* x    = (const float*)d_in[0];
  const float* pos_k= (const float*)d_in[1];
  const float* w1_k = (const float*)d_in[2];
  const float* b1_k = (const float*)d_in[3];
  const float* w2_k = (const float*)d_in[4];
  const float* b2_k = (const float*)d_in[5];
  const float* wa_k = (const float*)d_in[6];
  const float* ba_k = (const float*)d_in[7];
  const float* pos_q= (const float*)d_in[8];
  const float* w1_q = (const float*)d_in[9];
  const float* b1_q = (const float*)d_in[10];
  const float* w2_q = (const float*)d_in[11];
  const float* b2_q = (const float*)d_in[12];
  const float* wa_q = (const float*)d_in[13];
  const float* ba_q = (const float*)d_in[14];
  const float* wv   = (const float*)d_in[15];
  const float* bv   = (const float*)d_in[16];
  const float* ln_g = (const float*)d_in[17];
  const float* ln_b = (const float*)d_in[18];
  const float* wo   = (const float*)d_in[19];
  const float* bo   = (const float*)d_in[20];

  float* ws = (float*)d_ws;
  float* kr = ws;                          // N*K
  float* ki = kr + (size_t)N * K;
  float* qr = ki + (size_t)N * K;
  float* qi = qr + (size_t)N * K;
  float* V  = qi + (size_t)N * K;          // N*D
  float* TMt = V + (size_t)N * D;          // B*NC*256*192
  float* ret = TMt + (size_t)B * NC * 256 * 192;  // N*D
  float* LNred = ret + (size_t)N * D;      // N*32
  float* hk = LNred + (size_t)N * 32;      // N*D
  float* hq = hk + (size_t)N * D;          // N*D
  ushort* WT = (ushort*)(hq + (size_t)N * D);   // 655360 ushorts

  prep_kernel<<<80, 256, 0, stream>>>(w1_k, w1_q, wv, wo,
                                      w2_k, wa_k, w2_q, wa_q, WT);
  enc1_kernel<<<768, 256, 0, stream>>>(x, pos_k, pos_q, b1_k, b1_q, bv, WT,
                                       hk, hq, V);
  enc2_kernel<<<512, 256, 0, stream>>>(x, pos_k, pos_q, hk, hq,
                                       b2_k, ba_k, b2_q, ba_q, WT,
                                       kr, ki, qr, qi);
  tbuild_kernel<<<B * NC * 16, 256, 0, stream>>>(kr, ki, V, TMt);
  ret_kernel<<<B * NC * 16, 256, 0, stream>>>(qr, qi, kr, ki, TMt, ret, LNred);
  out2_kernel<<<512, 256, 0, stream>>>(ret, LNred, x, ln_g, ln_b, WT, bo,
                                       (float*)d_out);
}